// Round 1
// baseline (11047.478 us; speedup 1.0000x reference)
//
#include <hip/hip_runtime.h>
#include <hip/hip_bf16.h>

#define BB 4
#define GG_ 30
#define DD 320
#define LL 4
#define NHH 8
#define DKK 40
#define SS 900
#define BS 3600
#define FFD 1280

__device__ __forceinline__ float gelu_f(float x) {
    return 0.5f * x * (1.0f + erff(x * 0.70710678118654752f));
}

// ---------------- embed: one-hot gather + bias + pe ----------------
__global__ void embed_kernel(const int* __restrict__ grid, const float* __restrict__ pe,
                             const float* __restrict__ ew, const float* __restrict__ eb,
                             float* __restrict__ x) {
    int idx = blockIdx.x * 256 + threadIdx.x;   // < 1,152,000
    int m = idx / DD, d = idx % DD;
    int gv = grid[m];
    x[idx] = ew[gv * DD + d] + eb[d] + pe[(m % SS) * DD + d];
}

// ---------------- generic tiled fp32 GEMM ----------------
// C[m, n] = act(A[m,:]@W[:,n] + bias[n]) * alpha + (res ? res[m*ldc+n] : 0)
__global__ __launch_bounds__(256) void gemm_kernel(
    const float* __restrict__ A, int lda, const float* __restrict__ W,
    const float* __restrict__ bias, const float* __restrict__ res, float alpha,
    float* __restrict__ C, int ldc, int M, int N, int K, int act) {
    __shared__ float As[16][65];
    __shared__ float Ws[16][65];
    const int tid = threadIdx.x;
    const int m0 = blockIdx.y * 64, n0 = blockIdx.x * 64;
    const int tx = tid & 15, ty = tid >> 4;
    float acc[4][4] = {};
    const int kkA = tid & 15, mloc0 = tid >> 4;
    const int nloc = tid & 63, kk0 = tid >> 6;
    for (int k0 = 0; k0 < K; k0 += 16) {
        const int kA = k0 + kkA;
#pragma unroll
        for (int i = 0; i < 4; ++i) {
            int mloc = mloc0 + i * 16, m = m0 + mloc;
            As[kkA][mloc] = (m < M && kA < K) ? A[m * lda + kA] : 0.f;
        }
#pragma unroll
        for (int i = 0; i < 4; ++i) {
            int kk = kk0 + i * 4, k = k0 + kk, n = n0 + nloc;
            Ws[kk][nloc] = (k < K && n < N) ? W[k * N + n] : 0.f;
        }
        __syncthreads();
#pragma unroll
        for (int kk = 0; kk < 16; ++kk) {
            float a[4], b[4];
#pragma unroll
            for (int i = 0; i < 4; ++i) a[i] = As[kk][ty * 4 + i];
#pragma unroll
            for (int j = 0; j < 4; ++j) b[j] = Ws[kk][tx * 4 + j];
#pragma unroll
            for (int i = 0; i < 4; ++i)
#pragma unroll
                for (int j = 0; j < 4; ++j) acc[i][j] = fmaf(a[i], b[j], acc[i][j]);
        }
        __syncthreads();
    }
#pragma unroll
    for (int i = 0; i < 4; ++i) {
        int m = m0 + ty * 4 + i;
        if (m >= M) continue;
#pragma unroll
        for (int j = 0; j < 4; ++j) {
            int n = n0 + tx * 4 + j;
            if (n >= N) continue;
            float v = acc[i][j] + (bias ? bias[n] : 0.f);
            if (act == 1) v = gelu_f(v);
            else if (act == 2) v = fmaxf(v, 0.f);
            v *= alpha;
            if (res) v += res[m * ldc + n];
            C[m * ldc + n] = v;
        }
    }
}

// ---------------- conv as gather-GEMM (im2col on the fly) ----------------
template <int KS>
__global__ __launch_bounds__(256) void conv_kernel(
    const float* __restrict__ X, const float* __restrict__ W,
    const float* __restrict__ bias, float* __restrict__ C, int ldc) {
    const int Kc = KS * KS * DD;
    __shared__ float As[16][65];
    __shared__ float Ws[16][65];
    const int tid = threadIdx.x;
    const int m0 = blockIdx.y * 64, n0 = blockIdx.x * 64;
    const int tx = tid & 15, ty = tid >> 4;
    float acc[4][4] = {};
    const int kkA = tid & 15, mloc0 = tid >> 4;
    const int nloc = tid & 63, kk0 = tid >> 6;
    for (int k0 = 0; k0 < Kc; k0 += 16) {
        const int kA = k0 + kkA;
        const int kh = kA / (KS * DD);
        const int rr = kA % (KS * DD);
        const int kw = rr / DD;
        const int ci = rr % DD;
#pragma unroll
        for (int i = 0; i < 4; ++i) {
            int mloc = mloc0 + i * 16, m = m0 + mloc;
            float v = 0.f;
            if (m < BS) {
                int b = m / SS, hw = m % SS, hh = hw / GG_, wp = hw % GG_;
                int ih = hh + kh - KS / 2, iw = wp + kw - KS / 2;
                if (ih >= 0 && ih < GG_ && iw >= 0 && iw < GG_)
                    v = X[(b * SS + ih * GG_ + iw) * DD + ci];
            }
            As[kkA][mloc] = v;
        }
#pragma unroll
        for (int i = 0; i < 4; ++i) {
            int kk = kk0 + i * 4;
            Ws[kk][nloc] = W[(k0 + kk) * DD + n0 + nloc];
        }
        __syncthreads();
#pragma unroll
        for (int kk = 0; kk < 16; ++kk) {
            float a[4], b[4];
#pragma unroll
            for (int i = 0; i < 4; ++i) a[i] = As[kk][ty * 4 + i];
#pragma unroll
            for (int j = 0; j < 4; ++j) b[j] = Ws[kk][tx * 4 + j];
#pragma unroll
            for (int i = 0; i < 4; ++i)
#pragma unroll
                for (int j = 0; j < 4; ++j) acc[i][j] = fmaf(a[i], b[j], acc[i][j]);
        }
        __syncthreads();
    }
#pragma unroll
    for (int i = 0; i < 4; ++i) {
        int m = m0 + ty * 4 + i;
        if (m >= BS) continue;
#pragma unroll
        for (int j = 0; j < 4; ++j) {
            int n = n0 + tx * 4 + j;
            C[m * ldc + n] = fmaxf(acc[i][j] + bias[n], 0.f);
        }
    }
}

// ---------------- fused attention: one block per (b,h,row) ----------------
__global__ __launch_bounds__(256) void attn_kernel(
    const float* __restrict__ Q, const float* __restrict__ Kv, const float* __restrict__ V,
    const float* __restrict__ de, const float* __restrict__ dre,
    const int* __restrict__ dist_idx, const int* __restrict__ dir_idx,
    float* __restrict__ AO) {
    const int sq = blockIdx.x, h = blockIdx.y, b = blockIdx.z;
    const int tid = threadIdx.x;
    __shared__ float sc[SS];
    __shared__ float red[256];
    __shared__ float qs[DKK];
    __shared__ float part[240];
    __shared__ float s_max, s_inv;
    const int base = b * SS;
    if (tid < DKK) qs[tid] = Q[(base + sq) * DD + h * DKK + tid];
    __syncthreads();
    const float scale = 0.15811388300841898f;  // 1/sqrt(40)
    float lmax = -1e30f;
    for (int t = tid; t < SS; t += 256) {
        const float* kr = Kv + (base + t) * DD + h * DKK;
        float s = 0.f;
#pragma unroll
        for (int d = 0; d < DKK; ++d) s = fmaf(qs[d], kr[d], s);
        s = s * scale + de[dist_idx[sq * SS + t] * NHH + h] + dre[dir_idx[sq * SS + t] * NHH + h];
        sc[t] = s;
        lmax = fmaxf(lmax, s);
    }
    red[tid] = lmax;
    __syncthreads();
    for (int s = 128; s > 0; s >>= 1) {
        if (tid < s) red[tid] = fmaxf(red[tid], red[tid + s]);
        __syncthreads();
    }
    if (tid == 0) s_max = red[0];
    __syncthreads();
    const float mx = s_max;
    float lsum = 0.f;
    for (int t = tid; t < SS; t += 256) {
        float e = expf(sc[t] - mx);
        sc[t] = e;
        lsum += e;
    }
    red[tid] = lsum;
    __syncthreads();
    for (int s = 128; s > 0; s >>= 1) {
        if (tid < s) red[tid] += red[tid + s];
        __syncthreads();
    }
    if (tid == 0) s_inv = 1.f / red[0];
    __syncthreads();
    if (tid < 240) {
        const int d = tid % DKK, ch = tid / DKK;
        float acc = 0.f;
        const int t0 = ch * 150;
        for (int t = t0; t < t0 + 150; ++t)
            acc = fmaf(sc[t], V[(base + t) * DD + h * DKK + d], acc);
        part[tid] = acc;
    }
    __syncthreads();
    if (tid < DKK) {
        float s = 0.f;
#pragma unroll
        for (int c = 0; c < 6; ++c) s += part[c * DKK + tid];
        AO[(base + sq) * DD + h * DKK + tid] = s * s_inv;
    }
}

// ---------------- row LayerNorm, optional additive residual ----------------
__global__ __launch_bounds__(320) void ln_kernel(const float* __restrict__ a,
                                                 const float* __restrict__ add,
                                                 const float* __restrict__ g,
                                                 const float* __restrict__ bta,
                                                 float* __restrict__ out) {
    const int row = blockIdx.x, i = threadIdx.x;
    __shared__ float red[320];
    __shared__ float s_m, s_v;
    float v = a[row * DD + i];
    if (add) v += add[row * DD + i];
    red[i] = v;
    __syncthreads();
    if (i < 64) red[i] += red[i + 256];
    __syncthreads();
    for (int s = 128; s > 0; s >>= 1) {
        if (i < s) red[i] += red[i + s];
        __syncthreads();
    }
    if (i == 0) s_m = red[0] * (1.0f / DD);
    __syncthreads();
    const float d = v - s_m;
    red[i] = d * d;
    __syncthreads();
    if (i < 64) red[i] += red[i + 256];
    __syncthreads();
    for (int s = 128; s > 0; s >>= 1) {
        if (i < s) red[i] += red[i + s];
        __syncthreads();
    }
    if (i == 0) s_v = red[0] * (1.0f / DD);
    __syncthreads();
    out[row * DD + i] = d * rsqrtf(s_v + 1e-5f) * g[i] + bta[i];
}

// ---------------- global mean over S ----------------
__global__ __launch_bounds__(320) void mean_kernel(const float* __restrict__ xs, float* __restrict__ g) {
    const int b = blockIdx.x, d = threadIdx.x;
    float s = 0.f;
    for (int t = 0; t < SS; ++t) s += xs[(b * SS + t) * DD + d];
    g[b * DD + d] = s * (1.0f / SS);
}

// ---------------- transform params (17 tiny heads + softmax/tanh) ----------------
__global__ __launch_bounds__(64) void tp_kernel(const float* __restrict__ g,
                                                const float* __restrict__ wrot, const float* __restrict__ brot,
                                                const float* __restrict__ wrefl, const float* __restrict__ brefl,
                                                const float* __restrict__ wtr, const float* __restrict__ btr,
                                                const float* __restrict__ wsc, const float* __restrict__ bsc,
                                                float* __restrict__ tp) {
    const int b = blockIdx.x, tid = threadIdx.x;
    __shared__ float gs[DD];
    __shared__ float raw[17];
    for (int j = tid; j < DD; j += 64) gs[j] = g[b * DD + j];
    __syncthreads();
    if (tid < 17) {
        float s;
        if (tid < 4) {
            s = brot[tid];
            for (int d = 0; d < DD; ++d) s = fmaf(gs[d], wrot[d * 4 + tid], s);
        } else if (tid < 12) {
            int j = tid - 4;
            s = brefl[j];
            for (int d = 0; d < DD; ++d) s = fmaf(gs[d], wrefl[d * 8 + j], s);
        } else if (tid < 14) {
            int j = tid - 12;
            s = btr[j];
            for (int d = 0; d < DD; ++d) s = fmaf(gs[d], wtr[d * 2 + j], s);
        } else {
            int j = tid - 14;
            s = bsc[j];
            for (int d = 0; d < DD; ++d) s = fmaf(gs[d], wsc[d * 3 + j], s);
        }
        raw[tid] = s;
    }
    __syncthreads();
    if (tid == 0) {
        float mx = -1e30f;
        for (int j = 0; j < 4; ++j) mx = fmaxf(mx, raw[j]);
        float sm = 0.f, e[4];
        for (int j = 0; j < 4; ++j) { e[j] = expf(raw[j] - mx); sm += e[j]; }
        for (int j = 0; j < 4; ++j) tp[b * 17 + j] = e[j] / sm;
    } else if (tid == 1) {
        float mx = -1e30f;
        for (int j = 4; j < 12; ++j) mx = fmaxf(mx, raw[j]);
        float sm = 0.f, e[8];
        for (int j = 0; j < 8; ++j) { e[j] = expf(raw[4 + j] - mx); sm += e[j]; }
        for (int j = 0; j < 8; ++j) tp[b * 17 + 4 + j] = e[j] / sm;
    } else if (tid == 2) {
        tp[b * 17 + 12] = tanhf(raw[12]);
        tp[b * 17 + 13] = tanhf(raw[13]);
    } else if (tid == 3) {
        float mx = -1e30f;
        for (int j = 14; j < 17; ++j) mx = fmaxf(mx, raw[j]);
        float sm = 0.f, e[3];
        for (int j = 0; j < 3; ++j) { e[j] = expf(raw[14 + j] - mx); sm += e[j]; }
        for (int j = 0; j < 3; ++j) tp[b * 17 + 14 + j] = e[j] / sm;
    }
}

// ---------------- concat xs with broadcast tp -> ti [BS, 337] ----------------
__global__ void concat_kernel(const float* __restrict__ xs, const float* __restrict__ tp,
                              float* __restrict__ ti) {
    int idx = blockIdx.x * 256 + threadIdx.x;
    if (idx >= BS * 337) return;
    int m = idx / 337, j = idx % 337;
    ti[idx] = (j < DD) ? xs[m * DD + j] : tp[(m / SS) * 17 + (j - DD)];
}

static inline void launch_gemm(hipStream_t s, const float* A, int lda, const float* W,
                               const float* bias, const float* res, float alpha, float* C,
                               int ldc, int M, int N, int K, int act) {
    dim3 g((N + 63) / 64, (M + 63) / 64);
    gemm_kernel<<<g, 256, 0, s>>>(A, lda, W, bias, res, alpha, C, ldc, M, N, K, act);
}

extern "C" void kernel_launch(void* const* d_in, const int* in_sizes, int n_in,
                              void* d_out, int out_size, void* d_ws, size_t ws_size,
                              hipStream_t stream) {
    (void)in_sizes; (void)n_in; (void)out_size; (void)ws_size;
    const int* in_grid = (const int*)d_in[0];
    const float* pe = (const float*)d_in[1];
    const float* iew = (const float*)d_in[2];
    const float* ieb = (const float*)d_in[3];
    const float* wq = (const float*)d_in[4], *bq = (const float*)d_in[5];
    const float* wk = (const float*)d_in[6], *bk = (const float*)d_in[7];
    const float* wv = (const float*)d_in[8], *bv = (const float*)d_in[9];
    const float* wo = (const float*)d_in[10], *bo = (const float*)d_in[11];
    const float* lnag = (const float*)d_in[12], *lnab = (const float*)d_in[13];
    const float* dist_emb = (const float*)d_in[14], *dir_emb = (const float*)d_in[15];
    const float* wrot = (const float*)d_in[16], *brot = (const float*)d_in[17];
    const float* wrefl = (const float*)d_in[18], *brefl = (const float*)d_in[19];
    const float* wtr = (const float*)d_in[20], *btr = (const float*)d_in[21];
    const float* wsc = (const float*)d_in[22], *bsc = (const float*)d_in[23];
    const float* tnw1 = (const float*)d_in[24], *tnb1 = (const float*)d_in[25];
    const float* tnw2 = (const float*)d_in[26], *tnb2 = (const float*)d_in[27];
    const float* tnw3 = (const float*)d_in[28], *tnb3 = (const float*)d_in[29];
    const float* ffw1 = (const float*)d_in[30], *ffb1 = (const float*)d_in[31];
    const float* ffw2 = (const float*)d_in[32], *ffb2 = (const float*)d_in[33];
    const float* ln2g = (const float*)d_in[34], *ln2b = (const float*)d_in[35];
    const float* ck1 = (const float*)d_in[36], *cb1 = (const float*)d_in[37];
    const float* ck3 = (const float*)d_in[38], *cb3 = (const float*)d_in[39];
    const float* ck5 = (const float*)d_in[40], *cb5 = (const float*)d_in[41];
    const float* ck7 = (const float*)d_in[42], *cb7 = (const float*)d_in[43];
    const float* fusw = (const float*)d_in[44], *fusb = (const float*)d_in[45];
    const float* opw1 = (const float*)d_in[46], *opb1 = (const float*)d_in[47];
    const float* opw2 = (const float*)d_in[48], *opb2 = (const float*)d_in[49];
    const float* opw3 = (const float*)d_in[50], *opb3 = (const float*)d_in[51];
    const int* dist_idx = (const int*)d_in[52];
    const int* dir_idx = (const int*)d_in[53];
    float* out = (float*)d_out;

    // workspace arena (floats)
    float* ws = (float*)d_ws;
    float* XS = ws;                       // 1,152,000
    float* R1 = ws + 1152000;             // 4,800,000
    float* Qb = R1;                       // 1,152,000
    float* Kb = R1 + 1152000;
    float* Vb = R1 + 2304000;
    float* AO = R1 + 3456000;
    float* TI = R1;                       // 1,213,200
    float* T1 = R1 + 1216000;             // 2,304,000
    float* T2 = R1 + 3520000;             // 1,152,000
    float* F1 = R1;                       // 4,608,000
    float* FEATS = R1;                    // 4,608,000
    float* R2 = ws + 5952000;             // 1,152,000
    float* Gm = ws + 7104000;             // 1,280
    float* TP = Gm + 1280;                // 68
    float* H1 = ws;                       // reuse XS after convs (576,000)
    float* H2 = ws + 600000;              // 288,000

    embed_kernel<<<4500, 256, 0, stream>>>(in_grid, pe, iew, ieb, XS);

    for (int l = 0; l < LL; ++l) {
        const int wO = l * DD * DD, bO = l * DD;
        launch_gemm(stream, XS, DD, wq + wO, bq + bO, nullptr, 1.f, Qb, DD, BS, DD, DD, 0);
        launch_gemm(stream, XS, DD, wk + wO, bk + bO, nullptr, 1.f, Kb, DD, BS, DD, DD, 0);
        launch_gemm(stream, XS, DD, wv + wO, bv + bO, nullptr, 1.f, Vb, DD, BS, DD, DD, 0);
        attn_kernel<<<dim3(SS, NHH, BB), 256, 0, stream>>>(
            Qb, Kb, Vb, dist_emb + l * 60 * NHH, dir_emb + l * 8 * NHH, dist_idx, dir_idx, AO);
        launch_gemm(stream, AO, DD, wo + wO, bo + bO, XS, 1.f, R2, DD, BS, DD, DD, 0);
        ln_kernel<<<BS, 320, 0, stream>>>(R2, nullptr, lnag + bO, lnab + bO, XS);
        mean_kernel<<<BB, 320, 0, stream>>>(XS, Gm);
        tp_kernel<<<BB, 64, 0, stream>>>(Gm, wrot + l * 1280, brot + l * 4,
                                         wrefl + l * 2560, brefl + l * 8,
                                         wtr + l * 640, btr + l * 2,
                                         wsc + l * 960, bsc + l * 3, TP);
        concat_kernel<<<(BS * 337 + 255) / 256, 256, 0, stream>>>(XS, TP, TI);
        launch_gemm(stream, TI, 337, tnw1 + l * 337 * 640, tnb1 + l * 640, nullptr, 1.f,
                    T1, 640, BS, 640, 337, 1);
        launch_gemm(stream, T1, 640, tnw2 + l * 640 * DD, tnb2 + bO, nullptr, 1.f,
                    T2, DD, BS, DD, 640, 1);
        launch_gemm(stream, T2, DD, tnw3 + wO, tnb3 + bO, XS, 0.3f, XS, DD, BS, DD, DD, 0);
        launch_gemm(stream, XS, DD, ffw1 + l * DD * FFD, ffb1 + l * FFD, nullptr, 1.f,
                    F1, FFD, BS, FFD, DD, 1);
        launch_gemm(stream, F1, FFD, ffw2 + l * FFD * DD, ffb2 + bO, nullptr, 1.f,
                    R2, DD, BS, DD, FFD, 0);
        ln_kernel<<<BS, 320, 0, stream>>>(R2, XS, ln2g + bO, ln2b + bO, XS);
    }

    // multiscale convs -> FEATS concat [BS, 1280]
    conv_kernel<1><<<dim3(5, 57), 256, 0, stream>>>(XS, ck1, cb1, FEATS + 0, 1280);
    conv_kernel<3><<<dim3(5, 57), 256, 0, stream>>>(XS, ck3, cb3, FEATS + 320, 1280);
    conv_kernel<5><<<dim3(5, 57), 256, 0, stream>>>(XS, ck5, cb5, FEATS + 640, 1280);
    conv_kernel<7><<<dim3(5, 57), 256, 0, stream>>>(XS, ck7, cb7, FEATS + 960, 1280);
    launch_gemm(stream, FEATS, 1280, fusw, fusb, nullptr, 1.f, R2, DD, BS, DD, 1280, 0);
    // output head
    launch_gemm(stream, R2, DD, opw1, opb1, nullptr, 1.f, H1, 160, BS, 160, DD, 1);
    launch_gemm(stream, H1, 160, opw2, opb2, nullptr, 1.f, H2, 80, BS, 80, 160, 1);
    launch_gemm(stream, H2, 80, opw3, opb3, nullptr, 1.f, out, 10, BS, 10, 80, 0);
}

// Round 2
// 6085.506 us; speedup vs baseline: 1.8154x; 1.8154x over previous
//
#include <hip/hip_runtime.h>
#include <hip/hip_bf16.h>

#define BB 4
#define GG_ 30
#define DD 320
#define LL 4
#define NHH 8
#define DKK 40
#define SS 900
#define BS 3600
#define FFD 1280
#define LDK 72   // BK(64) + 8 pad, in bf16 elems -> 144B row stride, 16B aligned

typedef __attribute__((ext_vector_type(8))) short short8;
typedef __attribute__((ext_vector_type(4))) float f32x4;

__device__ __forceinline__ float gelu_f(float x) {
    return 0.5f * x * (1.0f + erff(x * 0.70710678118654752f));
}

// ---------------- weight convert fp32[K,N] -> bf16 transposed [N,Kpad] ----------------
__global__ __launch_bounds__(256) void convt_kernel(const float* __restrict__ src,
                                                    __hip_bfloat16* __restrict__ dst,
                                                    int K, int N, int Kpad,
                                                    int srcStride, int dstStride) {
    __shared__ float t[32][33];
    const int mat = blockIdx.z;
    const float* s = src + (size_t)mat * srcStride;
    __hip_bfloat16* d = dst + (size_t)mat * dstStride;
    const int kb = blockIdx.x * 32, nb = blockIdx.y * 32;
    const int tx = threadIdx.x, ty = threadIdx.y;   // (32, 8)
#pragma unroll
    for (int i = 0; i < 4; ++i) {
        int k = kb + ty + i * 8, n = nb + tx;
        t[ty + i * 8][tx] = (k < K && n < N) ? s[(size_t)k * N + n] : 0.f;
    }
    __syncthreads();
#pragma unroll
    for (int i = 0; i < 4; ++i) {
        int n = nb + ty + i * 8, k = kb + tx;
        if (n < N && k < Kpad) d[(size_t)n * Kpad + k] = __float2bfloat16(t[tx][ty + i * 8]);
    }
}

// ---------------- embed: one-hot gather + bias + pe (fp32 + bf16 mirror) ----------------
__global__ void embed_kernel(const int* __restrict__ grid, const float* __restrict__ pe,
                             const float* __restrict__ ew, const float* __restrict__ eb,
                             float* __restrict__ x, __hip_bfloat16* __restrict__ xb) {
    int idx = blockIdx.x * 256 + threadIdx.x;   // < 1,152,000
    int m = idx / DD, d = idx % DD;
    int gv = grid[m];
    float v = ew[gv * DD + d] + eb[d] + pe[(m % SS) * DD + d];
    x[idx] = v;
    xb[idx] = __float2bfloat16(v);
}

// ---------------- MFMA bf16 GEMM: C = act(A@Wt^T + bias)*alpha + res ----------------
// A: bf16 [M, lda] row-major. Wt: bf16 [N, ldw] (ldw = Kpad, k-contiguous rows).
// BM=128 BN=64 BK=64, 256 threads = 4 waves (2x2), wave tile 64x32 = 4x2 frags of 16x16.
__global__ __launch_bounds__(256) void mgemm_kernel(
    const __hip_bfloat16* __restrict__ A, int lda,
    const __hip_bfloat16* __restrict__ Wt, int ldw,
    const float* __restrict__ bias, const float* __restrict__ res, int ldr,
    float alpha, float* __restrict__ Cf, __hip_bfloat16* __restrict__ Cb, int ldc,
    int M, int N, int K, int act) {
    __shared__ short As[128 * LDK];
    __shared__ short Bs[64 * LDK];
    const int tid = threadIdx.x;
    const int m0 = blockIdx.y * 128, n0 = blockIdx.x * 64;
    const int lane = tid & 63;
    const int w = tid >> 6, wm = w >> 1, wn = w & 1;
    const int rbase = tid >> 3, q8 = (tid & 7) * 8;
    f32x4 acc[4][2];
    const f32x4 fz = {0.f, 0.f, 0.f, 0.f};
#pragma unroll
    for (int mi = 0; mi < 4; ++mi)
#pragma unroll
        for (int ni = 0; ni < 2; ++ni) acc[mi][ni] = fz;
    const short8 zz = {0, 0, 0, 0, 0, 0, 0, 0};
    for (int k0 = 0; k0 < K; k0 += 64) {
#pragma unroll
        for (int c = 0; c < 4; ++c) {
            int r = c * 32 + rbase, m = m0 + r;
            short8 v = zz;
            if (m < M) v = *(const short8*)((const short*)A + (size_t)m * lda + k0 + q8);
            *(short8*)(As + r * LDK + q8) = v;
        }
#pragma unroll
        for (int c = 0; c < 2; ++c) {
            int r = c * 32 + rbase, n = n0 + r;
            short8 v = zz;
            if (n < N) v = *(const short8*)((const short*)Wt + (size_t)n * ldw + k0 + q8);
            *(short8*)(Bs + r * LDK + q8) = v;
        }
        __syncthreads();
#pragma unroll
        for (int ks = 0; ks < 64; ks += 32) {
            const int kb = ks + (lane >> 4) * 8;
            short8 af[4], bf[2];
#pragma unroll
            for (int mi = 0; mi < 4; ++mi)
                af[mi] = *(const short8*)(As + (wm * 64 + mi * 16 + (lane & 15)) * LDK + kb);
#pragma unroll
            for (int ni = 0; ni < 2; ++ni)
                bf[ni] = *(const short8*)(Bs + (wn * 32 + ni * 16 + (lane & 15)) * LDK + kb);
#pragma unroll
            for (int mi = 0; mi < 4; ++mi)
#pragma unroll
                for (int ni = 0; ni < 2; ++ni)
                    acc[mi][ni] = __builtin_amdgcn_mfma_f32_16x16x32_bf16(af[mi], bf[ni], acc[mi][ni], 0, 0, 0);
        }
        __syncthreads();
    }
    const int col0 = n0 + wn * 32 + (lane & 15);
    const int rloc = (lane >> 4) * 4;
#pragma unroll
    for (int mi = 0; mi < 4; ++mi) {
#pragma unroll
        for (int ni = 0; ni < 2; ++ni) {
            int col = col0 + ni * 16;
            if (col >= N) continue;
            float bv = bias ? bias[col] : 0.f;
#pragma unroll
            for (int r = 0; r < 4; ++r) {
                int row = m0 + wm * 64 + mi * 16 + rloc + r;
                if (row >= M) continue;
                float v = acc[mi][ni][r] + bv;
                if (act == 1) v = gelu_f(v);
                else if (act == 2) v = fmaxf(v, 0.f);
                v *= alpha;
                if (res) v += res[(size_t)row * ldr + col];
                if (Cf) Cf[(size_t)row * ldc + col] = v;
                if (Cb) Cb[(size_t)row * ldc + col] = __float2bfloat16(v);
            }
        }
    }
}

// ---------------- MFMA conv (im2col gather from padded bf16 image) ----------------
// P: [B][36][36][320] bf16 zero-padded. Out: relu(conv + bias) -> bf16, ldc stride.
template <int KS>
__global__ __launch_bounds__(256) void mconv_kernel(
    const __hip_bfloat16* __restrict__ P, const __hip_bfloat16* __restrict__ Wt,
    const float* __restrict__ bias, __hip_bfloat16* __restrict__ Cb, int ldc) {
    const int K = KS * KS * DD;
    const int OFF = 3 - KS / 2;
    __shared__ short As[128 * LDK];
    __shared__ short Bs[64 * LDK];
    const int tid = threadIdx.x;
    const int m0 = blockIdx.y * 128, n0 = blockIdx.x * 64;
    const int lane = tid & 63;
    const int w = tid >> 6, wm = w >> 1, wn = w & 1;
    const int rbase = tid >> 3, q8 = (tid & 7) * 8;
    f32x4 acc[4][2];
    const f32x4 fz = {0.f, 0.f, 0.f, 0.f};
#pragma unroll
    for (int mi = 0; mi < 4; ++mi)
#pragma unroll
        for (int ni = 0; ni < 2; ++ni) acc[mi][ni] = fz;
    const short8 zz = {0, 0, 0, 0, 0, 0, 0, 0};
    for (int k0 = 0; k0 < K; k0 += 64) {
#pragma unroll
        for (int c = 0; c < 4; ++c) {
            int r = c * 32 + rbase, m = m0 + r;
            int k = k0 + q8;
            int ci = k % DD, t = k / DD;
            int kw = t % KS, kh = t / KS;
            short8 v = zz;
            if (m < BS) {
                int b = m / SS, hw = m % SS, oh = hw / GG_, ow = hw % GG_;
                int ih = oh + kh + OFF, iw = ow + kw + OFF;
                v = *(const short8*)((const short*)P + (((b * 36 + ih) * 36 + iw) * DD + ci));
            }
            *(short8*)(As + r * LDK + q8) = v;
        }
#pragma unroll
        for (int c = 0; c < 2; ++c) {
            int r = c * 32 + rbase, n = n0 + r;
            short8 v = *(const short8*)((const short*)Wt + (size_t)n * K + k0 + q8);
            *(short8*)(Bs + r * LDK + q8) = v;
        }
        __syncthreads();
#pragma unroll
        for (int ks = 0; ks < 64; ks += 32) {
            const int kb = ks + (lane >> 4) * 8;
            short8 af[4], bf[2];
#pragma unroll
            for (int mi = 0; mi < 4; ++mi)
                af[mi] = *(const short8*)(As + (wm * 64 + mi * 16 + (lane & 15)) * LDK + kb);
#pragma unroll
            for (int ni = 0; ni < 2; ++ni)
                bf[ni] = *(const short8*)(Bs + (wn * 32 + ni * 16 + (lane & 15)) * LDK + kb);
#pragma unroll
            for (int mi = 0; mi < 4; ++mi)
#pragma unroll
                for (int ni = 0; ni < 2; ++ni)
                    acc[mi][ni] = __builtin_amdgcn_mfma_f32_16x16x32_bf16(af[mi], bf[ni], acc[mi][ni], 0, 0, 0);
        }
        __syncthreads();
    }
    const int col0 = n0 + wn * 32 + (lane & 15);
    const int rloc = (lane >> 4) * 4;
#pragma unroll
    for (int mi = 0; mi < 4; ++mi) {
#pragma unroll
        for (int ni = 0; ni < 2; ++ni) {
            int col = col0 + ni * 16;
            float bv = bias[col];
#pragma unroll
            for (int r = 0; r < 4; ++r) {
                int row = m0 + wm * 64 + mi * 16 + rloc + r;
                if (row >= BS) continue;
                float v = fmaxf(acc[mi][ni][r] + bv, 0.f);
                Cb[(size_t)row * ldc + col] = __float2bfloat16(v);
            }
        }
    }
}

// ---------------- pad bf16 image for convs ----------------
__global__ void pad_kernel(const __hip_bfloat16* __restrict__ xb, __hip_bfloat16* __restrict__ p) {
    int idx = blockIdx.x * 256 + threadIdx.x;   // 4*36*36*320
    if (idx >= BB * 36 * 36 * DD) return;
    int c = idx % DD, t = idx / DD;
    int wp = t % 36, t2 = t / 36, hp = t2 % 36, b = t2 / 36;
    __hip_bfloat16 v = __float2bfloat16(0.f);
    if (hp >= 3 && hp < 33 && wp >= 3 && wp < 33)
        v = xb[((b * SS + (hp - 3) * GG_ + (wp - 3))) * DD + c];
    p[idx] = v;
}

// ---------------- legacy fp32 GEMM (tiny op heads) ----------------
__global__ __launch_bounds__(256) void gemm_kernel(
    const float* __restrict__ A, int lda, const float* __restrict__ W,
    const float* __restrict__ bias, float* __restrict__ C, int ldc,
    int M, int N, int K, int act) {
    __shared__ float As[16][65];
    __shared__ float Ws[16][65];
    const int tid = threadIdx.x;
    const int m0 = blockIdx.y * 64, n0 = blockIdx.x * 64;
    const int tx = tid & 15, ty = tid >> 4;
    float acc[4][4] = {};
    const int kkA = tid & 15, mloc0 = tid >> 4;
    const int nloc = tid & 63, kk0 = tid >> 6;
    for (int k0 = 0; k0 < K; k0 += 16) {
        const int kA = k0 + kkA;
#pragma unroll
        for (int i = 0; i < 4; ++i) {
            int mloc = mloc0 + i * 16, m = m0 + mloc;
            As[kkA][mloc] = (m < M && kA < K) ? A[m * lda + kA] : 0.f;
        }
#pragma unroll
        for (int i = 0; i < 4; ++i) {
            int kk = kk0 + i * 4, k = k0 + kk, n = n0 + nloc;
            Ws[kk][nloc] = (k < K && n < N) ? W[k * N + n] : 0.f;
        }
        __syncthreads();
#pragma unroll
        for (int kk = 0; kk < 16; ++kk) {
            float a[4], b[4];
#pragma unroll
            for (int i = 0; i < 4; ++i) a[i] = As[kk][ty * 4 + i];
#pragma unroll
            for (int j = 0; j < 4; ++j) b[j] = Ws[kk][tx * 4 + j];
#pragma unroll
            for (int i = 0; i < 4; ++i)
#pragma unroll
                for (int j = 0; j < 4; ++j) acc[i][j] = fmaf(a[i], b[j], acc[i][j]);
        }
        __syncthreads();
    }
#pragma unroll
    for (int i = 0; i < 4; ++i) {
        int m = m0 + ty * 4 + i;
        if (m >= M) continue;
#pragma unroll
        for (int j = 0; j < 4; ++j) {
            int n = n0 + tx * 4 + j;
            if (n >= N) continue;
            float v = acc[i][j] + bias[n];
            if (act == 1) v = gelu_f(v);
            C[m * ldc + n] = v;
        }
    }
}

// ---------------- fused attention (fp32 compute, bf16 out) ----------------
__global__ __launch_bounds__(256) void attn_kernel(
    const float* __restrict__ Q, const float* __restrict__ Kv, const float* __restrict__ V,
    const float* __restrict__ de, const float* __restrict__ dre,
    const int* __restrict__ dist_idx, const int* __restrict__ dir_idx,
    __hip_bfloat16* __restrict__ AO) {
    const int sq = blockIdx.x, h = blockIdx.y, b = blockIdx.z;
    const int tid = threadIdx.x;
    __shared__ float sc[SS];
    __shared__ float red[256];
    __shared__ float qs[DKK];
    __shared__ float part[240];
    __shared__ float s_max, s_inv;
    const int base = b * SS;
    if (tid < DKK) qs[tid] = Q[(base + sq) * DD + h * DKK + tid];
    __syncthreads();
    const float scale = 0.15811388300841898f;  // 1/sqrt(40)
    float lmax = -1e30f;
    for (int t = tid; t < SS; t += 256) {
        const float* kr = Kv + (base + t) * DD + h * DKK;
        float s = 0.f;
#pragma unroll
        for (int d = 0; d < DKK; ++d) s = fmaf(qs[d], kr[d], s);
        s = s * scale + de[dist_idx[sq * SS + t] * NHH + h] + dre[dir_idx[sq * SS + t] * NHH + h];
        sc[t] = s;
        lmax = fmaxf(lmax, s);
    }
    red[tid] = lmax;
    __syncthreads();
    for (int s = 128; s > 0; s >>= 1) {
        if (tid < s) red[tid] = fmaxf(red[tid], red[tid + s]);
        __syncthreads();
    }
    if (tid == 0) s_max = red[0];
    __syncthreads();
    const float mx = s_max;
    float lsum = 0.f;
    for (int t = tid; t < SS; t += 256) {
        float e = expf(sc[t] - mx);
        sc[t] = e;
        lsum += e;
    }
    red[tid] = lsum;
    __syncthreads();
    for (int s = 128; s > 0; s >>= 1) {
        if (tid < s) red[tid] += red[tid + s];
        __syncthreads();
    }
    if (tid == 0) s_inv = 1.f / red[0];
    __syncthreads();
    if (tid < 240) {
        const int d = tid % DKK, ch = tid / DKK;
        float acc = 0.f;
        const int t0 = ch * 150;
        for (int t = t0; t < t0 + 150; ++t)
            acc = fmaf(sc[t], V[(base + t) * DD + h * DKK + d], acc);
        part[tid] = acc;
    }
    __syncthreads();
    if (tid < DKK) {
        float s = 0.f;
#pragma unroll
        for (int c = 0; c < 6; ++c) s += part[c * DKK + tid];
        AO[(base + sq) * DD + h * DKK + tid] = __float2bfloat16(s * s_inv);
    }
}

// ---------------- row LayerNorm, optional residual, dual out ----------------
__global__ __launch_bounds__(320) void ln_kernel(const float* __restrict__ a,
                                                 const float* __restrict__ add,
                                                 const float* __restrict__ g,
                                                 const float* __restrict__ bta,
                                                 float* __restrict__ out,
                                                 __hip_bfloat16* __restrict__ outb) {
    const int row = blockIdx.x, i = threadIdx.x;
    __shared__ float red[320];
    __shared__ float s_m, s_v;
    float v = a[row * DD + i];
    if (add) v += add[row * DD + i];
    red[i] = v;
    __syncthreads();
    if (i < 64) red[i] += red[i + 256];
    __syncthreads();
    for (int s = 128; s > 0; s >>= 1) {
        if (i < s) red[i] += red[i + s];
        __syncthreads();
    }
    if (i == 0) s_m = red[0] * (1.0f / DD);
    __syncthreads();
    const float d = v - s_m;
    red[i] = d * d;
    __syncthreads();
    if (i < 64) red[i] += red[i + 256];
    __syncthreads();
    for (int s = 128; s > 0; s >>= 1) {
        if (i < s) red[i] += red[i + s];
        __syncthreads();
    }
    if (i == 0) s_v = red[0] * (1.0f / DD);
    __syncthreads();
    float o = d * rsqrtf(s_v + 1e-5f) * g[i] + bta[i];
    out[row * DD + i] = o;
    outb[row * DD + i] = __float2bfloat16(o);
}

// ---------------- global mean over S (20 blocks) ----------------
__global__ __launch_bounds__(256) void mean_kernel(const float* __restrict__ xs, float* __restrict__ g) {
    const int b = blockIdx.y, d = blockIdx.x * 64 + (threadIdx.x & 63);
    const int rg = threadIdx.x >> 6;
    float s = 0.f;
    for (int t = rg; t < SS; t += 4) s += xs[((size_t)b * SS + t) * DD + d];
    __shared__ float red[256];
    red[threadIdx.x] = s;
    __syncthreads();
    if (threadIdx.x < 128) red[threadIdx.x] += red[threadIdx.x + 128];
    __syncthreads();
    if (threadIdx.x < 64) g[b * DD + d] = (red[threadIdx.x] + red[threadIdx.x + 64]) * (1.0f / SS);
}

// ---------------- transform params ----------------
__global__ __launch_bounds__(64) void tp_kernel(const float* __restrict__ g,
                                                const float* __restrict__ wrot, const float* __restrict__ brot,
                                                const float* __restrict__ wrefl, const float* __restrict__ brefl,
                                                const float* __restrict__ wtr, const float* __restrict__ btr,
                                                const float* __restrict__ wsc, const float* __restrict__ bsc,
                                                float* __restrict__ tp) {
    const int b = blockIdx.x, tid = threadIdx.x;
    __shared__ float gs[DD];
    __shared__ float raw[17];
    for (int j = tid; j < DD; j += 64) gs[j] = g[b * DD + j];
    __syncthreads();
    if (tid < 17) {
        float s;
        if (tid < 4) {
            s = brot[tid];
            for (int d = 0; d < DD; ++d) s = fmaf(gs[d], wrot[d * 4 + tid], s);
        } else if (tid < 12) {
            int j = tid - 4;
            s = brefl[j];
            for (int d = 0; d < DD; ++d) s = fmaf(gs[d], wrefl[d * 8 + j], s);
        } else if (tid < 14) {
            int j = tid - 12;
            s = btr[j];
            for (int d = 0; d < DD; ++d) s = fmaf(gs[d], wtr[d * 2 + j], s);
        } else {
            int j = tid - 14;
            s = bsc[j];
            for (int d = 0; d < DD; ++d) s = fmaf(gs[d], wsc[d * 3 + j], s);
        }
        raw[tid] = s;
    }
    __syncthreads();
    if (tid == 0) {
        float mx = -1e30f;
        for (int j = 0; j < 4; ++j) mx = fmaxf(mx, raw[j]);
        float sm = 0.f, e[4];
        for (int j = 0; j < 4; ++j) { e[j] = expf(raw[j] - mx); sm += e[j]; }
        for (int j = 0; j < 4; ++j) tp[b * 17 + j] = e[j] / sm;
    } else if (tid == 1) {
        float mx = -1e30f;
        for (int j = 4; j < 12; ++j) mx = fmaxf(mx, raw[j]);
        float sm = 0.f, e[8];
        for (int j = 0; j < 8; ++j) { e[j] = expf(raw[4 + j] - mx); sm += e[j]; }
        for (int j = 0; j < 8; ++j) tp[b * 17 + 4 + j] = e[j] / sm;
    } else if (tid == 2) {
        tp[b * 17 + 12] = tanhf(raw[12]);
        tp[b * 17 + 13] = tanhf(raw[13]);
    } else if (tid == 3) {
        float mx = -1e30f;
        for (int j = 14; j < 17; ++j) mx = fmaxf(mx, raw[j]);
        float sm = 0.f, e[3];
        for (int j = 0; j < 3; ++j) { e[j] = expf(raw[14 + j] - mx); sm += e[j]; }
        for (int j = 0; j < 3; ++j) tp[b * 17 + 14 + j] = e[j] / sm;
    }
}

// ---------------- concat xs(bf16) + tp -> TIbf [3600, 384] (zero pad) ----------------
__global__ void concat_kernel(const __hip_bfloat16* __restrict__ xb, const float* __restrict__ tp,
                              __hip_bfloat16* __restrict__ ti) {
    int idx = blockIdx.x * 256 + threadIdx.x;
    if (idx >= BS * 384) return;
    int m = idx / 384, j = idx % 384;
    __hip_bfloat16 v;
    if (j < DD) v = xb[m * DD + j];
    else if (j < 337) v = __float2bfloat16(tp[(m / SS) * 17 + (j - DD)]);
    else v = __float2bfloat16(0.f);
    ti[idx] = v;
}

static inline void launch_mgemm(hipStream_t s, const __hip_bfloat16* A, int lda,
                                const __hip_bfloat16* Wt, int ldw, const float* bias,
                                const float* res, int ldr, float alpha, float* Cf,
                                __hip_bfloat16* Cb, int ldc, int M, int N, int K, int act) {
    dim3 g((N + 63) / 64, (M + 127) / 128);
    mgemm_kernel<<<g, 256, 0, s>>>(A, lda, Wt, ldw, bias, res, ldr, alpha, Cf, Cb, ldc, M, N, K, act);
}

extern "C" void kernel_launch(void* const* d_in, const int* in_sizes, int n_in,
                              void* d_out, int out_size, void* d_ws, size_t ws_size,
                              hipStream_t stream) {
    (void)in_sizes; (void)n_in; (void)out_size; (void)ws_size;
    const int* in_grid = (const int*)d_in[0];
    const float* pe = (const float*)d_in[1];
    const float* iew = (const float*)d_in[2];
    const float* ieb = (const float*)d_in[3];
    const float* wq = (const float*)d_in[4], *bq = (const float*)d_in[5];
    const float* wk = (const float*)d_in[6], *bk = (const float*)d_in[7];
    const float* wv = (const float*)d_in[8], *bv = (const float*)d_in[9];
    const float* wo = (const float*)d_in[10], *bo = (const float*)d_in[11];
    const float* lnag = (const float*)d_in[12], *lnab = (const float*)d_in[13];
    const float* dist_emb = (const float*)d_in[14], *dir_emb = (const float*)d_in[15];
    const float* wrot = (const float*)d_in[16], *brot = (const float*)d_in[17];
    const float* wrefl = (const float*)d_in[18], *brefl = (const float*)d_in[19];
    const float* wtr = (const float*)d_in[20], *btr = (const float*)d_in[21];
    const float* wsc = (const float*)d_in[22], *bsc = (const float*)d_in[23];
    const float* tnw1 = (const float*)d_in[24], *tnb1 = (const float*)d_in[25];
    const float* tnw2 = (const float*)d_in[26], *tnb2 = (const float*)d_in[27];
    const float* tnw3 = (const float*)d_in[28], *tnb3 = (const float*)d_in[29];
    const float* ffw1 = (const float*)d_in[30], *ffb1 = (const float*)d_in[31];
    const float* ffw2 = (const float*)d_in[32], *ffb2 = (const float*)d_in[33];
    const float* ln2g = (const float*)d_in[34], *ln2b = (const float*)d_in[35];
    const float* ck1 = (const float*)d_in[36], *cb1 = (const float*)d_in[37];
    const float* ck3 = (const float*)d_in[38], *cb3 = (const float*)d_in[39];
    const float* ck5 = (const float*)d_in[40], *cb5 = (const float*)d_in[41];
    const float* ck7 = (const float*)d_in[42], *cb7 = (const float*)d_in[43];
    const float* fusw = (const float*)d_in[44], *fusb = (const float*)d_in[45];
    const float* opw1 = (const float*)d_in[46], *opb1 = (const float*)d_in[47];
    const float* opw2 = (const float*)d_in[48], *opb2 = (const float*)d_in[49];
    const float* opw3 = (const float*)d_in[50], *opb3 = (const float*)d_in[51];
    const int* dist_idx = (const int*)d_in[52];
    const int* dir_idx = (const int*)d_in[53];
    float* out = (float*)d_out;

    // ---- workspace arena (byte offsets) ----
    char* base = (char*)d_ws;
    typedef __hip_bfloat16 bf;
    bf* WQT = (bf*)(base + 0);
    bf* WKT = (bf*)(base + 819200);
    bf* WVT = (bf*)(base + 1638400);
    bf* WOT = (bf*)(base + 2457600);
    bf* TN1T = (bf*)(base + 3276800);     // 4 x 640 x 384
    bf* TN2T = (bf*)(base + 5242880);     // 4 x 320 x 640
    bf* TN3T = (bf*)(base + 6881280);
    bf* FF1T = (bf*)(base + 7700480);     // 4 x 1280 x 320
    bf* FF2T = (bf*)(base + 10977280);    // 4 x 320 x 1280
    bf* CK1T = (bf*)(base + 14254080);
    bf* CK3T = (bf*)(base + 14458880);
    bf* CK5T = (bf*)(base + 16302080);
    bf* CK7T = (bf*)(base + 21422080);
    bf* FUST = (bf*)(base + 31457280);
    bf* OP1T = (bf*)(base + 32276480);
    float* XS = (float*)(base + 32378880);
    bf* XSbf = (bf*)(base + 36986880);
    float* Qb = (float*)(base + 39290880);
    float* Kb = (float*)(base + 43898880);
    float* Vb = (float*)(base + 48506880);
    float* R2 = (float*)(base + 53114880);
    float* Gm = (float*)(base + 57722880);
    float* TP = (float*)(base + 57728000);
    char* BIG = base + 57728512;
    bf* AObf = (bf*)(BIG + 0);
    bf* TIbf = (bf*)(BIG + 0);            // after AObf dead
    bf* T1bf = (bf*)(BIG + 2764800);
    bf* T2bf = (bf*)(BIG + 7372800);
    bf* F1bf = (bf*)(BIG + 0);
    bf* PADbf = (bf*)(BIG + 0);
    bf* FEATSbf = (bf*)(BIG + 3317760);
    float* H1 = (float*)(BIG + 0);
    float* H2 = (float*)(BIG + 2304000);
    bf* R2bf = XSbf;                      // XSbf dead after pad_kernel

    dim3 cb(32, 8);
    // ---- weight convert+transpose (per call) ----
    convt_kernel<<<dim3(10, 10, 4), cb, 0, stream>>>(wq, WQT, 320, 320, 320, 102400, 102400);
    convt_kernel<<<dim3(10, 10, 4), cb, 0, stream>>>(wk, WKT, 320, 320, 320, 102400, 102400);
    convt_kernel<<<dim3(10, 10, 4), cb, 0, stream>>>(wv, WVT, 320, 320, 320, 102400, 102400);
    convt_kernel<<<dim3(10, 10, 4), cb, 0, stream>>>(wo, WOT, 320, 320, 320, 102400, 102400);
    convt_kernel<<<dim3(12, 20, 4), cb, 0, stream>>>(tnw1, TN1T, 337, 640, 384, 215680, 245760);
    convt_kernel<<<dim3(20, 10, 4), cb, 0, stream>>>(tnw2, TN2T, 640, 320, 640, 204800, 204800);
    convt_kernel<<<dim3(10, 10, 4), cb, 0, stream>>>(tnw3, TN3T, 320, 320, 320, 102400, 102400);
    convt_kernel<<<dim3(10, 40, 4), cb, 0, stream>>>(ffw1, FF1T, 320, 1280, 320, 409600, 409600);
    convt_kernel<<<dim3(40, 10, 4), cb, 0, stream>>>(ffw2, FF2T, 1280, 320, 1280, 409600, 409600);
    convt_kernel<<<dim3(10, 10, 1), cb, 0, stream>>>(ck1, CK1T, 320, 320, 320, 0, 0);
    convt_kernel<<<dim3(90, 10, 1), cb, 0, stream>>>(ck3, CK3T, 2880, 320, 2880, 0, 0);
    convt_kernel<<<dim3(250, 10, 1), cb, 0, stream>>>(ck5, CK5T, 8000, 320, 8000, 0, 0);
    convt_kernel<<<dim3(490, 10, 1), cb, 0, stream>>>(ck7, CK7T, 15680, 320, 15680, 0, 0);
    convt_kernel<<<dim3(40, 10, 1), cb, 0, stream>>>(fusw, FUST, 1280, 320, 1280, 0, 0);
    convt_kernel<<<dim3(10, 5, 1), cb, 0, stream>>>(opw1, OP1T, 320, 160, 320, 0, 0);

    embed_kernel<<<4500, 256, 0, stream>>>(in_grid, pe, iew, ieb, XS, XSbf);

    for (int l = 0; l < LL; ++l) {
        const int wO = l * DD * DD, bO = l * DD;
        launch_mgemm(stream, XSbf, DD, WQT + wO, DD, bq + bO, nullptr, 0, 1.f, Qb, nullptr, DD, BS, DD, DD, 0);
        launch_mgemm(stream, XSbf, DD, WKT + wO, DD, bk + bO, nullptr, 0, 1.f, Kb, nullptr, DD, BS, DD, DD, 0);
        launch_mgemm(stream, XSbf, DD, WVT + wO, DD, bv + bO, nullptr, 0, 1.f, Vb, nullptr, DD, BS, DD, DD, 0);
        attn_kernel<<<dim3(SS, NHH, BB), 256, 0, stream>>>(
            Qb, Kb, Vb, dist_emb + l * 60 * NHH, dir_emb + l * 8 * NHH, dist_idx, dir_idx, AObf);
        launch_mgemm(stream, AObf, DD, WOT + wO, DD, bo + bO, XS, DD, 1.f, R2, nullptr, DD, BS, DD, DD, 0);
        ln_kernel<<<BS, 320, 0, stream>>>(R2, nullptr, lnag + bO, lnab + bO, XS, XSbf);
        mean_kernel<<<dim3(5, BB), 256, 0, stream>>>(XS, Gm);
        tp_kernel<<<BB, 64, 0, stream>>>(Gm, wrot + l * 1280, brot + l * 4,
                                         wrefl + l * 2560, brefl + l * 8,
                                         wtr + l * 640, btr + l * 2,
                                         wsc + l * 960, bsc + l * 3, TP);
        concat_kernel<<<(BS * 384 + 255) / 256, 256, 0, stream>>>(XSbf, TP, TIbf);
        launch_mgemm(stream, TIbf, 384, TN1T + l * 245760, 384, tnb1 + l * 640, nullptr, 0, 1.f,
                     nullptr, T1bf, 640, BS, 640, 384, 1);
        launch_mgemm(stream, T1bf, 640, TN2T + l * 204800, 640, tnb2 + bO, nullptr, 0, 1.f,
                     nullptr, T2bf, DD, BS, DD, 640, 1);
        launch_mgemm(stream, T2bf, DD, TN3T + wO, DD, tnb3 + bO, XS, DD, 0.3f,
                     XS, XSbf, DD, BS, DD, DD, 0);
        launch_mgemm(stream, XSbf, DD, FF1T + l * 409600, DD, ffb1 + l * FFD, nullptr, 0, 1.f,
                     nullptr, F1bf, FFD, BS, FFD, DD, 1);
        launch_mgemm(stream, F1bf, FFD, FF2T + l * 409600, FFD, ffb2 + bO, nullptr, 0, 1.f,
                     R2, nullptr, DD, BS, DD, FFD, 0);
        ln_kernel<<<BS, 320, 0, stream>>>(R2, XS, ln2g + bO, ln2b + bO, XS, XSbf);
    }

    // ---- multiscale convs -> FEATSbf [3600, 1280] ----
    pad_kernel<<<(BB * 36 * 36 * DD + 255) / 256, 256, 0, stream>>>(XSbf, PADbf);
    launch_mgemm(stream, XSbf, DD, CK1T, DD, cb1, nullptr, 0, 1.f, nullptr, FEATSbf + 0, 1280, BS, DD, DD, 2);
    mconv_kernel<3><<<dim3(5, 29), 256, 0, stream>>>(PADbf, CK3T, cb3, FEATSbf + 320, 1280);
    mconv_kernel<5><<<dim3(5, 29), 256, 0, stream>>>(PADbf, CK5T, cb5, FEATSbf + 640, 1280);
    mconv_kernel<7><<<dim3(5, 29), 256, 0, stream>>>(PADbf, CK7T, cb7, FEATSbf + 960, 1280);
    launch_mgemm(stream, FEATSbf, 1280, FUST, 1280, fusb, nullptr, 0, 1.f, nullptr, R2bf, DD, BS, DD, 1280, 0);
    // ---- output head ----
    launch_mgemm(stream, R2bf, DD, OP1T, DD, opb1, nullptr, 0, 1.f, H1, nullptr, 160, BS, 160, DD, 1);
    gemm_kernel<<<dim3(2, 57), 256, 0, stream>>>(H1, 160, opw2, opb2, H2, 80, BS, 80, 160, 1);
    gemm_kernel<<<dim3(1, 57), 256, 0, stream>>>(H2, 80, opw3, opb3, out, 10, BS, 10, 80, 0);
}

// Round 3
// 2555.430 us; speedup vs baseline: 4.3231x; 2.3814x over previous
//
#include <hip/hip_runtime.h>
#include <hip/hip_bf16.h>

#define BB 4
#define GG_ 30
#define DD 320
#define LL 4
#define NHH 8
#define DKK 40
#define SS 900
#define BS 3600
#define FFD 1280
#define LDK 72   // BK(64) + 8 pad, in bf16 elems -> 144B row stride, 16B aligned

typedef __attribute__((ext_vector_type(8))) short short8;
typedef __attribute__((ext_vector_type(4))) short short4v;
typedef __attribute__((ext_vector_type(4))) float f32x4;

__device__ __forceinline__ float gelu_f(float x) {
    return 0.5f * x * (1.0f + erff(x * 0.70710678118654752f));
}

// ---------------- weight convert fp32[K,N] -> bf16 transposed [N,Kpad] ----------------
__global__ __launch_bounds__(256) void convt_kernel(const float* __restrict__ src,
                                                    __hip_bfloat16* __restrict__ dst,
                                                    int K, int N, int Kpad,
                                                    int srcStride, int dstStride) {
    __shared__ float t[32][33];
    const int mat = blockIdx.z;
    const float* s = src + (size_t)mat * srcStride;
    __hip_bfloat16* d = dst + (size_t)mat * dstStride;
    const int kb = blockIdx.x * 32, nb = blockIdx.y * 32;
    const int tx = threadIdx.x, ty = threadIdx.y;   // (32, 8)
#pragma unroll
    for (int i = 0; i < 4; ++i) {
        int k = kb + ty + i * 8, n = nb + tx;
        t[ty + i * 8][tx] = (k < K && n < N) ? s[(size_t)k * N + n] : 0.f;
    }
    __syncthreads();
#pragma unroll
    for (int i = 0; i < 4; ++i) {
        int n = nb + ty + i * 8, k = kb + tx;
        if (n < N && k < Kpad) d[(size_t)n * Kpad + k] = __float2bfloat16(t[tx][ty + i * 8]);
    }
}

// ---------------- embed ----------------
__global__ void embed_kernel(const int* __restrict__ grid, const float* __restrict__ pe,
                             const float* __restrict__ ew, const float* __restrict__ eb,
                             float* __restrict__ x, __hip_bfloat16* __restrict__ xb) {
    int idx = blockIdx.x * 256 + threadIdx.x;   // < 1,152,000
    int m = idx / DD, d = idx % DD;
    int gv = grid[m];
    float v = ew[gv * DD + d] + eb[d] + pe[(m % SS) * DD + d];
    x[idx] = v;
    xb[idx] = __float2bfloat16(v);
}

// ---------------- MFMA bf16 GEMM ----------------
__global__ __launch_bounds__(256) void mgemm_kernel(
    const __hip_bfloat16* __restrict__ A, int lda,
    const __hip_bfloat16* __restrict__ Wt, int ldw,
    const float* __restrict__ bias, const float* __restrict__ res, int ldr,
    float alpha, float* __restrict__ Cf, __hip_bfloat16* __restrict__ Cb, int ldc,
    int M, int N, int K, int act) {
    __shared__ short As[128 * LDK];
    __shared__ short Bs[64 * LDK];
    const int tid = threadIdx.x;
    const int m0 = blockIdx.y * 128, n0 = blockIdx.x * 64;
    const int lane = tid & 63;
    const int w = tid >> 6, wm = w >> 1, wn = w & 1;
    const int rbase = tid >> 3, q8 = (tid & 7) * 8;
    f32x4 acc[4][2];
    const f32x4 fz = {0.f, 0.f, 0.f, 0.f};
#pragma unroll
    for (int mi = 0; mi < 4; ++mi)
#pragma unroll
        for (int ni = 0; ni < 2; ++ni) acc[mi][ni] = fz;
    const short8 zz = {0, 0, 0, 0, 0, 0, 0, 0};
    for (int k0 = 0; k0 < K; k0 += 64) {
#pragma unroll
        for (int c = 0; c < 4; ++c) {
            int r = c * 32 + rbase, m = m0 + r;
            short8 v = zz;
            if (m < M) v = *(const short8*)((const short*)A + (size_t)m * lda + k0 + q8);
            *(short8*)(As + r * LDK + q8) = v;
        }
#pragma unroll
        for (int c = 0; c < 2; ++c) {
            int r = c * 32 + rbase, n = n0 + r;
            short8 v = zz;
            if (n < N) v = *(const short8*)((const short*)Wt + (size_t)n * ldw + k0 + q8);
            *(short8*)(Bs + r * LDK + q8) = v;
        }
        __syncthreads();
#pragma unroll
        for (int ks = 0; ks < 64; ks += 32) {
            const int kb = ks + (lane >> 4) * 8;
            short8 af[4], bf[2];
#pragma unroll
            for (int mi = 0; mi < 4; ++mi)
                af[mi] = *(const short8*)(As + (wm * 64 + mi * 16 + (lane & 15)) * LDK + kb);
#pragma unroll
            for (int ni = 0; ni < 2; ++ni)
                bf[ni] = *(const short8*)(Bs + (wn * 32 + ni * 16 + (lane & 15)) * LDK + kb);
#pragma unroll
            for (int mi = 0; mi < 4; ++mi)
#pragma unroll
                for (int ni = 0; ni < 2; ++ni)
                    acc[mi][ni] = __builtin_amdgcn_mfma_f32_16x16x32_bf16(af[mi], bf[ni], acc[mi][ni], 0, 0, 0);
        }
        __syncthreads();
    }
    const int col0 = n0 + wn * 32 + (lane & 15);
    const int rloc = (lane >> 4) * 4;
#pragma unroll
    for (int mi = 0; mi < 4; ++mi) {
#pragma unroll
        for (int ni = 0; ni < 2; ++ni) {
            int col = col0 + ni * 16;
            if (col >= N) continue;
            float bv = bias ? bias[col] : 0.f;
#pragma unroll
            for (int r = 0; r < 4; ++r) {
                int row = m0 + wm * 64 + mi * 16 + rloc + r;
                if (row >= M) continue;
                float v = acc[mi][ni][r] + bv;
                if (act == 1) v = gelu_f(v);
                else if (act == 2) v = fmaxf(v, 0.f);
                v *= alpha;
                if (res) v += res[(size_t)row * ldr + col];
                if (Cf) Cf[(size_t)row * ldc + col] = v;
                if (Cb) Cb[(size_t)row * ldc + col] = __float2bfloat16(v);
            }
        }
    }
}

// ---------------- MFMA conv (im2col gather from padded bf16 image) ----------------
template <int KS>
__global__ __launch_bounds__(256) void mconv_kernel(
    const __hip_bfloat16* __restrict__ P, const __hip_bfloat16* __restrict__ Wt,
    const float* __restrict__ bias, __hip_bfloat16* __restrict__ Cb, int ldc) {
    const int K = KS * KS * DD;
    const int OFF = 3 - KS / 2;
    __shared__ short As[128 * LDK];
    __shared__ short Bs[64 * LDK];
    const int tid = threadIdx.x;
    const int m0 = blockIdx.y * 128, n0 = blockIdx.x * 64;
    const int lane = tid & 63;
    const int w = tid >> 6, wm = w >> 1, wn = w & 1;
    const int rbase = tid >> 3, q8 = (tid & 7) * 8;
    f32x4 acc[4][2];
    const f32x4 fz = {0.f, 0.f, 0.f, 0.f};
#pragma unroll
    for (int mi = 0; mi < 4; ++mi)
#pragma unroll
        for (int ni = 0; ni < 2; ++ni) acc[mi][ni] = fz;
    const short8 zz = {0, 0, 0, 0, 0, 0, 0, 0};
    for (int k0 = 0; k0 < K; k0 += 64) {
#pragma unroll
        for (int c = 0; c < 4; ++c) {
            int r = c * 32 + rbase, m = m0 + r;
            int k = k0 + q8;
            int ci = k % DD, t = k / DD;
            int kw = t % KS, kh = t / KS;
            short8 v = zz;
            if (m < BS) {
                int b = m / SS, hw = m % SS, oh = hw / GG_, ow = hw % GG_;
                int ih = oh + kh + OFF, iw = ow + kw + OFF;
                v = *(const short8*)((const short*)P + (((b * 36 + ih) * 36 + iw) * DD + ci));
            }
            *(short8*)(As + r * LDK + q8) = v;
        }
#pragma unroll
        for (int c = 0; c < 2; ++c) {
            int r = c * 32 + rbase, n = n0 + r;
            short8 v = *(const short8*)((const short*)Wt + (size_t)n * K + k0 + q8);
            *(short8*)(Bs + r * LDK + q8) = v;
        }
        __syncthreads();
#pragma unroll
        for (int ks = 0; ks < 64; ks += 32) {
            const int kb = ks + (lane >> 4) * 8;
            short8 af[4], bf[2];
#pragma unroll
            for (int mi = 0; mi < 4; ++mi)
                af[mi] = *(const short8*)(As + (wm * 64 + mi * 16 + (lane & 15)) * LDK + kb);
#pragma unroll
            for (int ni = 0; ni < 2; ++ni)
                bf[ni] = *(const short8*)(Bs + (wn * 32 + ni * 16 + (lane & 15)) * LDK + kb);
#pragma unroll
            for (int mi = 0; mi < 4; ++mi)
#pragma unroll
                for (int ni = 0; ni < 2; ++ni)
                    acc[mi][ni] = __builtin_amdgcn_mfma_f32_16x16x32_bf16(af[mi], bf[ni], acc[mi][ni], 0, 0, 0);
        }
        __syncthreads();
    }
    const int col0 = n0 + wn * 32 + (lane & 15);
    const int rloc = (lane >> 4) * 4;
#pragma unroll
    for (int mi = 0; mi < 4; ++mi) {
#pragma unroll
        for (int ni = 0; ni < 2; ++ni) {
            int col = col0 + ni * 16;
            float bv = bias[col];
#pragma unroll
            for (int r = 0; r < 4; ++r) {
                int row = m0 + wm * 64 + mi * 16 + rloc + r;
                if (row >= BS) continue;
                float v = fmaxf(acc[mi][ni][r] + bv, 0.f);
                Cb[(size_t)row * ldc + col] = __float2bfloat16(v);
            }
        }
    }
}

// ---------------- pad bf16 image for convs ----------------
__global__ void pad_kernel(const __hip_bfloat16* __restrict__ xb, __hip_bfloat16* __restrict__ p) {
    int idx = blockIdx.x * 256 + threadIdx.x;   // 4*36*36*320
    if (idx >= BB * 36 * 36 * DD) return;
    int c = idx % DD, t = idx / DD;
    int wp = t % 36, t2 = t / 36, hp = t2 % 36, b = t2 / 36;
    __hip_bfloat16 v = __float2bfloat16(0.f);
    if (hp >= 3 && hp < 33 && wp >= 3 && wp < 33)
        v = xb[((b * SS + (hp - 3) * GG_ + (wp - 3))) * DD + c];
    p[idx] = v;
}

// ---------------- legacy fp32 GEMM (tiny op heads) ----------------
__global__ __launch_bounds__(256) void gemm_kernel(
    const float* __restrict__ A, int lda, const float* __restrict__ W,
    const float* __restrict__ bias, float* __restrict__ C, int ldc,
    int M, int N, int K, int act) {
    __shared__ float As[16][65];
    __shared__ float Ws[16][65];
    const int tid = threadIdx.x;
    const int m0 = blockIdx.y * 64, n0 = blockIdx.x * 64;
    const int tx = tid & 15, ty = tid >> 4;
    float acc[4][4] = {};
    const int kkA = tid & 15, mloc0 = tid >> 4;
    const int nloc = tid & 63, kk0 = tid >> 6;
    for (int k0 = 0; k0 < K; k0 += 16) {
        const int kA = k0 + kkA;
#pragma unroll
        for (int i = 0; i < 4; ++i) {
            int mloc = mloc0 + i * 16, m = m0 + mloc;
            As[kkA][mloc] = (m < M && kA < K) ? A[m * lda + kA] : 0.f;
        }
#pragma unroll
        for (int i = 0; i < 4; ++i) {
            int kk = kk0 + i * 4, k = k0 + kk, n = n0 + nloc;
            Ws[kk][nloc] = (k < K && n < N) ? W[k * N + n] : 0.f;
        }
        __syncthreads();
#pragma unroll
        for (int kk = 0; kk < 16; ++kk) {
            float a[4], b[4];
#pragma unroll
            for (int i = 0; i < 4; ++i) a[i] = As[kk][ty * 4 + i];
#pragma unroll
            for (int j = 0; j < 4; ++j) b[j] = Ws[kk][tx * 4 + j];
#pragma unroll
            for (int i = 0; i < 4; ++i)
#pragma unroll
                for (int j = 0; j < 4; ++j) acc[i][j] = fmaf(a[i], b[j], acc[i][j]);
        }
        __syncthreads();
    }
#pragma unroll
    for (int i = 0; i < 4; ++i) {
        int m = m0 + ty * 4 + i;
        if (m >= M) continue;
#pragma unroll
        for (int j = 0; j < 4; ++j) {
            int n = n0 + tx * 4 + j;
            if (n >= N) continue;
            float v = acc[i][j] + bias[n];
            if (act == 1) v = gelu_f(v);
            C[m * ldc + n] = v;
        }
    }
}

// ---------------- geometric bias table: [NH][900][960] bf16 ----------------
__global__ __launch_bounds__(256) void bias_kernel(const float* __restrict__ de,
                                                   const float* __restrict__ dre,
                                                   const int* __restrict__ dist,
                                                   const int* __restrict__ dirn,
                                                   __hip_bfloat16* __restrict__ out) {
    const int h = blockIdx.y;
    int idx = blockIdx.x * 256 + threadIdx.x;      // 900*960 = 864000
    int sq = idx / 960, t = idx - sq * 960;
    float v = 0.f;
    if (t < SS) v = de[dist[sq * SS + t] * NHH + h] + dre[dirn[sq * SS + t] * NHH + h];
    out[((size_t)h * SS + sq) * 960 + t] = __float2bfloat16(v);
}

// ---------------- V transpose: Vbf[BS][320] -> VT[b][h][48][960] ----------------
__global__ __launch_bounds__(256) void vt_kernel(const __hip_bfloat16* __restrict__ V,
                                                 __hip_bfloat16* __restrict__ VT) {
    int idx = blockIdx.x * 256 + threadIdx.x;      // 4*8*48*960 = 1474560
    int t = idx % 960;
    int d = (idx / 960) % 48;
    int h = (idx / (960 * 48)) % NHH;
    int b = idx / (960 * 48 * NHH);
    __hip_bfloat16 v = __float2bfloat16(0.f);
    if (t < SS && d < DKK) v = V[((size_t)b * SS + t) * DD + h * DKK + d];
    VT[idx] = v;
}

// ---------------- MFMA flash attention ----------------
// grid: (15 q-tiles, NH, B). 256 thr = 4 waves; wave w owns q rows [w*16, w*16+16).
#define LQ 56
#define LK 56
#define LV 72
#define LP 72
__global__ __launch_bounds__(256) void mattn_kernel(
    const __hip_bfloat16* __restrict__ Qg, const __hip_bfloat16* __restrict__ Kg,
    const __hip_bfloat16* __restrict__ VTg, const __hip_bfloat16* __restrict__ BIASg,
    __hip_bfloat16* __restrict__ AO) {
    const int qt = blockIdx.x, h = blockIdx.y, b = blockIdx.z;
    const int tid = threadIdx.x, lane = tid & 63, w = tid >> 6;
    const int lhi = lane >> 4, llo = lane & 15;
    __shared__ short Qs[64 * LQ];
    __shared__ short Ks[64 * LK];
    __shared__ short Vs[48 * LV];
    __shared__ short Ps[4][16 * LP];
    short* Ps_w = Ps[w];
    const int q0 = qt * 64;
    const short4v z4 = {0, 0, 0, 0};
    const f32x4 fz = {0.f, 0.f, 0.f, 0.f};
    const float scale = 0.15811388300841898f;  // 1/sqrt(40)

    // stage Q tile (64 x 56, zero pad d>=40 / q>=900)
    for (int task = tid; task < 64 * 14; task += 256) {
        int r = task / 14, d0 = (task - r * 14) * 4;
        int q = q0 + r;
        short4v v = z4;
        if (q < SS && d0 < DKK)
            v = *(const short4v*)((const short*)Qg + ((size_t)b * SS + q) * DD + h * DKK + d0);
        *(short4v*)(Qs + r * LQ + d0) = v;
    }
    __syncthreads();
    short8 qa[2];
#pragma unroll
    for (int ks = 0; ks < 2; ++ks)
        qa[ks] = *(const short8*)(Qs + (w * 16 + llo) * LQ + ks * 32 + lhi * 8);

    float mrow[4] = {-1e30f, -1e30f, -1e30f, -1e30f};
    float lrow[4] = {0.f, 0.f, 0.f, 0.f};
    f32x4 o[3] = {fz, fz, fz};
    const int qrow = q0 + w * 16 + lhi * 4;

    for (int t = 0; t < 15; ++t) {
        const int kv0 = t * 64;
        // stage K tile (64 x 56)
        for (int task = tid; task < 64 * 14; task += 256) {
            int r = task / 14, d0 = (task - r * 14) * 4;
            int kv = kv0 + r;
            short4v v = z4;
            if (kv < SS && d0 < DKK)
                v = *(const short4v*)((const short*)Kg + ((size_t)b * SS + kv) * DD + h * DKK + d0);
            *(short4v*)(Ks + r * LK + d0) = v;
        }
        // stage VT tile (48 x 64)
        for (int task = tid; task < 48 * 16; task += 256) {
            int r = task / 16, c4 = (task - r * 16) * 4;
            short4v v = *(const short4v*)((const short*)VTg +
                         (((size_t)b * NHH + h) * 48 + r) * 960 + kv0 + c4);
            *(short4v*)(Vs + r * LV + c4) = v;
        }
        __syncthreads();
        // QK^T
        f32x4 s[4] = {fz, fz, fz, fz};
#pragma unroll
        for (int ks = 0; ks < 2; ++ks) {
#pragma unroll
            for (int ni = 0; ni < 4; ++ni) {
                short8 kb = *(const short8*)(Ks + (ni * 16 + llo) * LK + ks * 32 + lhi * 8);
                s[ni] = __builtin_amdgcn_mfma_f32_16x16x32_bf16(qa[ks], kb, s[ni], 0, 0, 0);
            }
        }
        // scale + bias + mask
#pragma unroll
        for (int ni = 0; ni < 4; ++ni) {
            int col = kv0 + ni * 16 + llo;
#pragma unroll
            for (int r = 0; r < 4; ++r) {
                int qc = qrow + r; if (qc > SS - 1) qc = SS - 1;
                float v = s[ni][r] * scale +
                          __bfloat162float(BIASg[((size_t)h * SS + qc) * 960 + col]);
                s[ni][r] = (col < SS) ? v : -1e30f;
            }
        }
        // online softmax
        float rmax[4], psum[4], corr[4];
#pragma unroll
        for (int r = 0; r < 4; ++r)
            rmax[r] = fmaxf(fmaxf(s[0][r], s[1][r]), fmaxf(s[2][r], s[3][r]));
#pragma unroll
        for (int off = 1; off < 16; off <<= 1)
#pragma unroll
            for (int r = 0; r < 4; ++r)
                rmax[r] = fmaxf(rmax[r], __shfl_xor(rmax[r], off));
#pragma unroll
        for (int r = 0; r < 4; ++r) {
            float mnew = fmaxf(mrow[r], rmax[r]);
            corr[r] = expf(mrow[r] - mnew);
            mrow[r] = mnew;
            float ps = 0.f;
#pragma unroll
            for (int ni = 0; ni < 4; ++ni) {
                float p = expf(s[ni][r] - mnew);
                s[ni][r] = p;
                ps += p;
            }
            psum[r] = ps;
        }
#pragma unroll
        for (int off = 1; off < 16; off <<= 1)
#pragma unroll
            for (int r = 0; r < 4; ++r) psum[r] += __shfl_xor(psum[r], off);
#pragma unroll
        for (int r = 0; r < 4; ++r) lrow[r] = lrow[r] * corr[r] + psum[r];
#pragma unroll
        for (int nj = 0; nj < 3; ++nj)
#pragma unroll
            for (int r = 0; r < 4; ++r) o[nj][r] *= corr[r];
        // P -> LDS (bf16), C-layout -> A-frag layout
#pragma unroll
        for (int ni = 0; ni < 4; ++ni)
#pragma unroll
            for (int r = 0; r < 4; ++r)
                ((__hip_bfloat16*)Ps_w)[(lhi * 4 + r) * LP + ni * 16 + llo] =
                    __float2bfloat16(s[ni][r]);
        // PV
#pragma unroll
        for (int ks = 0; ks < 2; ++ks) {
            short8 pa = *(const short8*)(Ps_w + llo * LP + ks * 32 + lhi * 8);
#pragma unroll
            for (int nj = 0; nj < 3; ++nj) {
                short8 vb = *(const short8*)(Vs + (nj * 16 + llo) * LV + ks * 32 + lhi * 8);
                o[nj] = __builtin_amdgcn_mfma_f32_16x16x32_bf16(pa, vb, o[nj], 0, 0, 0);
            }
        }
        __syncthreads();
    }
    // write O / l
#pragma unroll
    for (int nj = 0; nj < 3; ++nj) {
        int d = nj * 16 + llo;
        if (d >= DKK) continue;
#pragma unroll
        for (int r = 0; r < 4; ++r) {
            int q = qrow + r;
            if (q < SS)
                AO[((size_t)b * SS + q) * DD + h * DKK + d] = __float2bfloat16(o[nj][r] / lrow[r]);
        }
    }
}

// ---------------- row LayerNorm ----------------
__global__ __launch_bounds__(320) void ln_kernel(const float* __restrict__ a,
                                                 const float* __restrict__ add,
                                                 const float* __restrict__ g,
                                                 const float* __restrict__ bta,
                                                 float* __restrict__ out,
                                                 __hip_bfloat16* __restrict__ outb) {
    const int row = blockIdx.x, i = threadIdx.x;
    __shared__ float red[320];
    __shared__ float s_m, s_v;
    float v = a[row * DD + i];
    if (add) v += add[row * DD + i];
    red[i] = v;
    __syncthreads();
    if (i < 64) red[i] += red[i + 256];
    __syncthreads();
    for (int s = 128; s > 0; s >>= 1) {
        if (i < s) red[i] += red[i + s];
        __syncthreads();
    }
    if (i == 0) s_m = red[0] * (1.0f / DD);
    __syncthreads();
    const float d = v - s_m;
    red[i] = d * d;
    __syncthreads();
    if (i < 64) red[i] += red[i + 256];
    __syncthreads();
    for (int s = 128; s > 0; s >>= 1) {
        if (i < s) red[i] += red[i + s];
        __syncthreads();
    }
    if (i == 0) s_v = red[0] * (1.0f / DD);
    __syncthreads();
    float o = d * rsqrtf(s_v + 1e-5f) * g[i] + bta[i];
    out[row * DD + i] = o;
    outb[row * DD + i] = __float2bfloat16(o);
}

// ---------------- global mean over S ----------------
__global__ __launch_bounds__(256) void mean_kernel(const float* __restrict__ xs, float* __restrict__ g) {
    const int b = blockIdx.y, d = blockIdx.x * 64 + (threadIdx.x & 63);
    const int rg = threadIdx.x >> 6;
    float s = 0.f;
    for (int t = rg; t < SS; t += 4) s += xs[((size_t)b * SS + t) * DD + d];
    __shared__ float red[256];
    red[threadIdx.x] = s;
    __syncthreads();
    if (threadIdx.x < 128) red[threadIdx.x] += red[threadIdx.x + 128];
    __syncthreads();
    if (threadIdx.x < 64) g[b * DD + d] = (red[threadIdx.x] + red[threadIdx.x + 64]) * (1.0f / SS);
}

// ---------------- transform params ----------------
__global__ __launch_bounds__(64) void tp_kernel(const float* __restrict__ g,
                                                const float* __restrict__ wrot, const float* __restrict__ brot,
                                                const float* __restrict__ wrefl, const float* __restrict__ brefl,
                                                const float* __restrict__ wtr, const float* __restrict__ btr,
                                                const float* __restrict__ wsc, const float* __restrict__ bsc,
                                                float* __restrict__ tp) {
    const int b = blockIdx.x, tid = threadIdx.x;
    __shared__ float gs[DD];
    __shared__ float raw[17];
    for (int j = tid; j < DD; j += 64) gs[j] = g[b * DD + j];
    __syncthreads();
    if (tid < 17) {
        float s;
        if (tid < 4) {
            s = brot[tid];
            for (int d = 0; d < DD; ++d) s = fmaf(gs[d], wrot[d * 4 + tid], s);
        } else if (tid < 12) {
            int j = tid - 4;
            s = brefl[j];
            for (int d = 0; d < DD; ++d) s = fmaf(gs[d], wrefl[d * 8 + j], s);
        } else if (tid < 14) {
            int j = tid - 12;
            s = btr[j];
            for (int d = 0; d < DD; ++d) s = fmaf(gs[d], wtr[d * 2 + j], s);
        } else {
            int j = tid - 14;
            s = bsc[j];
            for (int d = 0; d < DD; ++d) s = fmaf(gs[d], wsc[d * 3 + j], s);
        }
        raw[tid] = s;
    }
    __syncthreads();
    if (tid == 0) {
        float mx = -1e30f;
        for (int j = 0; j < 4; ++j) mx = fmaxf(mx, raw[j]);
        float sm = 0.f, e[4];
        for (int j = 0; j < 4; ++j) { e[j] = expf(raw[j] - mx); sm += e[j]; }
        for (int j = 0; j < 4; ++j) tp[b * 17 + j] = e[j] / sm;
    } else if (tid == 1) {
        float mx = -1e30f;
        for (int j = 4; j < 12; ++j) mx = fmaxf(mx, raw[j]);
        float sm = 0.f, e[8];
        for (int j = 0; j < 8; ++j) { e[j] = expf(raw[4 + j] - mx); sm += e[j]; }
        for (int j = 0; j < 8; ++j) tp[b * 17 + 4 + j] = e[j] / sm;
    } else if (tid == 2) {
        tp[b * 17 + 12] = tanhf(raw[12]);
        tp[b * 17 + 13] = tanhf(raw[13]);
    } else if (tid == 3) {
        float mx = -1e30f;
        for (int j = 14; j < 17; ++j) mx = fmaxf(mx, raw[j]);
        float sm = 0.f, e[3];
        for (int j = 0; j < 3; ++j) { e[j] = expf(raw[14 + j] - mx); sm += e[j]; }
        for (int j = 0; j < 3; ++j) tp[b * 17 + 14 + j] = e[j] / sm;
    }
}

// ---------------- concat xs(bf16) + tp -> TIbf [3600, 384] ----------------
__global__ void concat_kernel(const __hip_bfloat16* __restrict__ xb, const float* __restrict__ tp,
                              __hip_bfloat16* __restrict__ ti) {
    int idx = blockIdx.x * 256 + threadIdx.x;
    if (idx >= BS * 384) return;
    int m = idx / 384, j = idx % 384;
    __hip_bfloat16 v;
    if (j < DD) v = xb[m * DD + j];
    else if (j < 337) v = __float2bfloat16(tp[(m / SS) * 17 + (j - DD)]);
    else v = __float2bfloat16(0.f);
    ti[idx] = v;
}

static inline void launch_mgemm(hipStream_t s, const __hip_bfloat16* A, int lda,
                                const __hip_bfloat16* Wt, int ldw, const float* bias,
                                const float* res, int ldr, float alpha, float* Cf,
                                __hip_bfloat16* Cb, int ldc, int M, int N, int K, int act) {
    dim3 g((N + 63) / 64, (M + 127) / 128);
    mgemm_kernel<<<g, 256, 0, s>>>(A, lda, Wt, ldw, bias, res, ldr, alpha, Cf, Cb, ldc, M, N, K, act);
}

extern "C" void kernel_launch(void* const* d_in, const int* in_sizes, int n_in,
                              void* d_out, int out_size, void* d_ws, size_t ws_size,
                              hipStream_t stream) {
    (void)in_sizes; (void)n_in; (void)out_size; (void)ws_size;
    const int* in_grid = (const int*)d_in[0];
    const float* pe = (const float*)d_in[1];
    const float* iew = (const float*)d_in[2];
    const float* ieb = (const float*)d_in[3];
    const float* wq = (const float*)d_in[4], *bq = (const float*)d_in[5];
    const float* wk = (const float*)d_in[6], *bk = (const float*)d_in[7];
    const float* wv = (const float*)d_in[8], *bv = (const float*)d_in[9];
    const float* wo = (const float*)d_in[10], *bo = (const float*)d_in[11];
    const float* lnag = (const float*)d_in[12], *lnab = (const float*)d_in[13];
    const float* dist_emb = (const float*)d_in[14], *dir_emb = (const float*)d_in[15];
    const float* wrot = (const float*)d_in[16], *brot = (const float*)d_in[17];
    const float* wrefl = (const float*)d_in[18], *brefl = (const float*)d_in[19];
    const float* wtr = (const float*)d_in[20], *btr = (const float*)d_in[21];
    const float* wsc = (const float*)d_in[22], *bsc = (const float*)d_in[23];
    const float* tnw1 = (const float*)d_in[24], *tnb1 = (const float*)d_in[25];
    const float* tnw2 = (const float*)d_in[26], *tnb2 = (const float*)d_in[27];
    const float* tnw3 = (const float*)d_in[28], *tnb3 = (const float*)d_in[29];
    const float* ffw1 = (const float*)d_in[30], *ffb1 = (const float*)d_in[31];
    const float* ffw2 = (const float*)d_in[32], *ffb2 = (const float*)d_in[33];
    const float* ln2g = (const float*)d_in[34], *ln2b = (const float*)d_in[35];
    const float* ck1 = (const float*)d_in[36], *cb1 = (const float*)d_in[37];
    const float* ck3 = (const float*)d_in[38], *cb3 = (const float*)d_in[39];
    const float* ck5 = (const float*)d_in[40], *cb5 = (const float*)d_in[41];
    const float* ck7 = (const float*)d_in[42], *cb7 = (const float*)d_in[43];
    const float* fusw = (const float*)d_in[44], *fusb = (const float*)d_in[45];
    const float* opw1 = (const float*)d_in[46], *opb1 = (const float*)d_in[47];
    const float* opw2 = (const float*)d_in[48], *opb2 = (const float*)d_in[49];
    const float* opw3 = (const float*)d_in[50], *opb3 = (const float*)d_in[51];
    const int* dist_idx = (const int*)d_in[52];
    const int* dir_idx = (const int*)d_in[53];
    float* out = (float*)d_out;

    // ---- workspace arena (byte offsets) ----
    char* base = (char*)d_ws;
    typedef __hip_bfloat16 bf;
    bf* WQT = (bf*)(base + 0);
    bf* WKT = (bf*)(base + 819200);
    bf* WVT = (bf*)(base + 1638400);
    bf* WOT = (bf*)(base + 2457600);
    bf* TN1T = (bf*)(base + 3276800);
    bf* TN2T = (bf*)(base + 5242880);
    bf* TN3T = (bf*)(base + 6881280);
    bf* FF1T = (bf*)(base + 7700480);
    bf* FF2T = (bf*)(base + 10977280);
    bf* CK1T = (bf*)(base + 14254080);
    bf* CK3T = (bf*)(base + 14458880);
    bf* CK5T = (bf*)(base + 16302080);
    bf* CK7T = (bf*)(base + 21422080);
    bf* FUST = (bf*)(base + 31457280);
    bf* OP1T = (bf*)(base + 32276480);
    float* XS = (float*)(base + 32378880);
    bf* XSbf = (bf*)(base + 36986880);
    bf* Qbf = (bf*)(base + 39290880);
    bf* Kbf = (bf*)(base + 41594880);
    bf* Vbf = (bf*)(base + 43898880);
    bf* VT = (bf*)(base + 46202880);      // 4*8*48*960*2 = 2,949,120 -> ends 49,152,000
    float* R2 = (float*)(base + 53114880);
    float* Gm = (float*)(base + 57722880);
    float* TP = (float*)(base + 57728000);
    char* BIG = base + 57728512;
    bf* AObf = (bf*)(BIG + 0);
    bf* BIAS = (bf*)(BIG + 2764800);      // 8*900*960*2 = 13,824,000 (dead after attn)
    bf* TIbf = (bf*)(BIG + 0);
    bf* T1bf = (bf*)(BIG + 2764800);
    bf* T2bf = (bf*)(BIG + 7372800);
    bf* F1bf = (bf*)(BIG + 0);
    bf* PADbf = (bf*)(BIG + 0);
    bf* FEATSbf = (bf*)(BIG + 3317760);
    float* H1 = (float*)(BIG + 0);
    float* H2 = (float*)(BIG + 2304000);
    bf* R2bf = XSbf;

    dim3 cb(32, 8);
    convt_kernel<<<dim3(10, 10, 4), cb, 0, stream>>>(wq, WQT, 320, 320, 320, 102400, 102400);
    convt_kernel<<<dim3(10, 10, 4), cb, 0, stream>>>(wk, WKT, 320, 320, 320, 102400, 102400);
    convt_kernel<<<dim3(10, 10, 4), cb, 0, stream>>>(wv, WVT, 320, 320, 320, 102400, 102400);
    convt_kernel<<<dim3(10, 10, 4), cb, 0, stream>>>(wo, WOT, 320, 320, 320, 102400, 102400);
    convt_kernel<<<dim3(12, 20, 4), cb, 0, stream>>>(tnw1, TN1T, 337, 640, 384, 215680, 245760);
    convt_kernel<<<dim3(20, 10, 4), cb, 0, stream>>>(tnw2, TN2T, 640, 320, 640, 204800, 204800);
    convt_kernel<<<dim3(10, 10, 4), cb, 0, stream>>>(tnw3, TN3T, 320, 320, 320, 102400, 102400);
    convt_kernel<<<dim3(10, 40, 4), cb, 0, stream>>>(ffw1, FF1T, 320, 1280, 320, 409600, 409600);
    convt_kernel<<<dim3(40, 10, 4), cb, 0, stream>>>(ffw2, FF2T, 1280, 320, 1280, 409600, 409600);
    convt_kernel<<<dim3(10, 10, 1), cb, 0, stream>>>(ck1, CK1T, 320, 320, 320, 0, 0);
    convt_kernel<<<dim3(90, 10, 1), cb, 0, stream>>>(ck3, CK3T, 2880, 320, 2880, 0, 0);
    convt_kernel<<<dim3(250, 10, 1), cb, 0, stream>>>(ck5, CK5T, 8000, 320, 8000, 0, 0);
    convt_kernel<<<dim3(490, 10, 1), cb, 0, stream>>>(ck7, CK7T, 15680, 320, 15680, 0, 0);
    convt_kernel<<<dim3(40, 10, 1), cb, 0, stream>>>(fusw, FUST, 1280, 320, 1280, 0, 0);
    convt_kernel<<<dim3(10, 5, 1), cb, 0, stream>>>(opw1, OP1T, 320, 160, 320, 0, 0);

    embed_kernel<<<4500, 256, 0, stream>>>(in_grid, pe, iew, ieb, XS, XSbf);

    for (int l = 0; l < LL; ++l) {
        const int wO = l * DD * DD, bO = l * DD;
        launch_mgemm(stream, XSbf, DD, WQT + wO, DD, bq + bO, nullptr, 0, 1.f, nullptr, Qbf, DD, BS, DD, DD, 0);
        launch_mgemm(stream, XSbf, DD, WKT + wO, DD, bk + bO, nullptr, 0, 1.f, nullptr, Kbf, DD, BS, DD, DD, 0);
        launch_mgemm(stream, XSbf, DD, WVT + wO, DD, bv + bO, nullptr, 0, 1.f, nullptr, Vbf, DD, BS, DD, DD, 0);
        vt_kernel<<<5760, 256, 0, stream>>>(Vbf, VT);
        bias_kernel<<<dim3(3375, NHH), 256, 0, stream>>>(dist_emb + l * 60 * NHH, dir_emb + l * 8 * NHH,
                                                         dist_idx, dir_idx, BIAS);
        mattn_kernel<<<dim3(15, NHH, BB), 256, 0, stream>>>(Qbf, Kbf, VT, BIAS, AObf);
        launch_mgemm(stream, AObf, DD, WOT + wO, DD, bo + bO, XS, DD, 1.f, R2, nullptr, DD, BS, DD, DD, 0);
        ln_kernel<<<BS, 320, 0, stream>>>(R2, nullptr, lnag + bO, lnab + bO, XS, XSbf);
        mean_kernel<<<dim3(5, BB), 256, 0, stream>>>(XS, Gm);
        tp_kernel<<<BB, 64, 0, stream>>>(Gm, wrot + l * 1280, brot + l * 4,
                                         wrefl + l * 2560, brefl + l * 8,
                                         wtr + l * 640, btr + l * 2,
                                         wsc + l * 960, bsc + l * 3, TP);
        concat_kernel<<<(BS * 384 + 255) / 256, 256, 0, stream>>>(XSbf, TP, TIbf);
        launch_mgemm(stream, TIbf, 384, TN1T + l * 245760, 384, tnb1 + l * 640, nullptr, 0, 1.f,
                     nullptr, T1bf, 640, BS, 640, 384, 1);
        launch_mgemm(stream, T1bf, 640, TN2T + l * 204800, 640, tnb2 + bO, nullptr, 0, 1.f,
                     nullptr, T2bf, DD, BS, DD, 640, 1);
        launch_mgemm(stream, T2bf, DD, TN3T + wO, DD, tnb3 + bO, XS, DD, 0.3f,
                     XS, XSbf, DD, BS, DD, DD, 0);
        launch_mgemm(stream, XSbf, DD, FF1T + l * 409600, DD, ffb1 + l * FFD, nullptr, 0, 1.f,
                     nullptr, F1bf, FFD, BS, FFD, DD, 1);
        launch_mgemm(stream, F1bf, FFD, FF2T + l * 409600, FFD, ffb2 + bO, nullptr, 0, 1.f,
                     R2, nullptr, DD, BS, DD, FFD, 0);
        ln_kernel<<<BS, 320, 0, stream>>>(R2, XS, ln2g + bO, ln2b + bO, XS, XSbf);
    }

    // ---- multiscale convs ----
    pad_kernel<<<(BB * 36 * 36 * DD + 255) / 256, 256, 0, stream>>>(XSbf, PADbf);
    launch_mgemm(stream, XSbf, DD, CK1T, DD, cb1, nullptr, 0, 1.f, nullptr, FEATSbf + 0, 1280, BS, DD, DD, 2);
    mconv_kernel<3><<<dim3(5, 29), 256, 0, stream>>>(PADbf, CK3T, cb3, FEATSbf + 320, 1280);
    mconv_kernel<5><<<dim3(5, 29), 256, 0, stream>>>(PADbf, CK5T, cb5, FEATSbf + 640, 1280);
    mconv_kernel<7><<<dim3(5, 29), 256, 0, stream>>>(PADbf, CK7T, cb7, FEATSbf + 960, 1280);
    launch_mgemm(stream, FEATSbf, 1280, FUST, 1280, fusb, nullptr, 0, 1.f, nullptr, R2bf, DD, BS, DD, 1280, 0);
    // ---- output head ----
    launch_mgemm(stream, R2bf, DD, OP1T, DD, opb1, nullptr, 0, 1.f, H1, nullptr, 160, BS, 160, DD, 1);
    gemm_kernel<<<dim3(2, 57), 256, 0, stream>>>(H1, 160, opw2, opb2, H2, 80, BS, 80, 160, 1);
    gemm_kernel<<<dim3(1, 57), 256, 0, stream>>>(H2, 80, opw3, opb3, out, 10, BS, 10, 80, 0);
}

// Round 6
// 2252.790 us; speedup vs baseline: 4.9039x; 1.1343x over previous
//
#include <hip/hip_runtime.h>
#include <hip/hip_bf16.h>

#define BB 4
#define GG_ 30
#define DD 320
#define LL 4
#define NHH 8
#define DKK 40
#define SS 900
#define BS 3600
#define FFD 1280
#define LDK 72   // BK(64) + 8 pad, in bf16 elems -> 144B row stride, 16B aligned

typedef __attribute__((ext_vector_type(8))) short short8;
typedef __attribute__((ext_vector_type(4))) short short4v;
typedef __attribute__((ext_vector_type(4))) float f32x4;

__device__ __forceinline__ float gelu_f(float x) {
    return 0.5f * x * (1.0f + erff(x * 0.70710678118654752f));
}

// ---------------- weight convert fp32[K,N] -> bf16 transposed [N,Kpad] ----------------
__global__ __launch_bounds__(256) void convt_kernel(const float* __restrict__ src,
                                                    __hip_bfloat16* __restrict__ dst,
                                                    int K, int N, int Kpad,
                                                    int srcStride, int dstStride) {
    __shared__ float t[32][33];
    const int mat = blockIdx.z;
    const float* s = src + (size_t)mat * srcStride;
    __hip_bfloat16* d = dst + (size_t)mat * dstStride;
    const int kb = blockIdx.x * 32, nb = blockIdx.y * 32;
    const int tx = threadIdx.x, ty = threadIdx.y;   // (32, 8)
#pragma unroll
    for (int i = 0; i < 4; ++i) {
        int k = kb + ty + i * 8, n = nb + tx;
        t[ty + i * 8][tx] = (k < K && n < N) ? s[(size_t)k * N + n] : 0.f;
    }
    __syncthreads();
#pragma unroll
    for (int i = 0; i < 4; ++i) {
        int n = nb + ty + i * 8, k = kb + tx;
        if (n < N && k < Kpad) d[(size_t)n * Kpad + k] = __float2bfloat16(t[tx][ty + i * 8]);
    }
}

// ---------------- embed ----------------
__global__ void embed_kernel(const int* __restrict__ grid, const float* __restrict__ pe,
                             const float* __restrict__ ew, const float* __restrict__ eb,
                             float* __restrict__ x, __hip_bfloat16* __restrict__ xb) {
    int idx = blockIdx.x * 256 + threadIdx.x;   // < 1,152,000
    int m = idx / DD, d = idx % DD;
    int gv = grid[m];
    float v = ew[gv * DD + d] + eb[d] + pe[(m % SS) * DD + d];
    x[idx] = v;
    xb[idx] = __float2bfloat16(v);
}

// ---------------- MFMA bf16 GEMM (round-3 proven 128x64 body) ----------------
__global__ __launch_bounds__(256) void mgemm_kernel(
    const __hip_bfloat16* __restrict__ A, int lda,
    const __hip_bfloat16* __restrict__ Wt, int ldw,
    const float* __restrict__ bias, const float* __restrict__ res, int ldr,
    float alpha, float* __restrict__ Cf, __hip_bfloat16* __restrict__ Cb, int ldc,
    int M, int N, int K, int act) {
    __shared__ short As[128 * LDK];
    __shared__ short Bs[64 * LDK];
    const int tid = threadIdx.x;
    const int m0 = blockIdx.y * 128, n0 = blockIdx.x * 64;
    const int lane = tid & 63;
    const int w = tid >> 6, wm = w >> 1, wn = w & 1;
    const int rbase = tid >> 3, q8 = (tid & 7) * 8;
    f32x4 acc[4][2];
    const f32x4 fz = {0.f, 0.f, 0.f, 0.f};
#pragma unroll
    for (int mi = 0; mi < 4; ++mi)
#pragma unroll
        for (int ni = 0; ni < 2; ++ni) acc[mi][ni] = fz;
    const short8 zz = {0, 0, 0, 0, 0, 0, 0, 0};
    for (int k0 = 0; k0 < K; k0 += 64) {
#pragma unroll
        for (int c = 0; c < 4; ++c) {
            int r = c * 32 + rbase, m = m0 + r;
            short8 v = zz;
            if (m < M) v = *(const short8*)((const short*)A + (size_t)m * lda + k0 + q8);
            *(short8*)(As + r * LDK + q8) = v;
        }
#pragma unroll
        for (int c = 0; c < 2; ++c) {
            int r = c * 32 + rbase, n = n0 + r;
            short8 v = zz;
            if (n < N) v = *(const short8*)((const short*)Wt + (size_t)n * ldw + k0 + q8);
            *(short8*)(Bs + r * LDK + q8) = v;
        }
        __syncthreads();
#pragma unroll
        for (int ks = 0; ks < 64; ks += 32) {
            const int kb = ks + (lane >> 4) * 8;
            short8 af[4], bf[2];
#pragma unroll
            for (int mi = 0; mi < 4; ++mi)
                af[mi] = *(const short8*)(As + (wm * 64 + mi * 16 + (lane & 15)) * LDK + kb);
#pragma unroll
            for (int ni = 0; ni < 2; ++ni)
                bf[ni] = *(const short8*)(Bs + (wn * 32 + ni * 16 + (lane & 15)) * LDK + kb);
#pragma unroll
            for (int mi = 0; mi < 4; ++mi)
#pragma unroll
                for (int ni = 0; ni < 2; ++ni)
                    acc[mi][ni] = __builtin_amdgcn_mfma_f32_16x16x32_bf16(af[mi], bf[ni], acc[mi][ni], 0, 0, 0);
        }
        __syncthreads();
    }
    const int col0 = n0 + wn * 32 + (lane & 15);
    const int rloc = (lane >> 4) * 4;
#pragma unroll
    for (int mi = 0; mi < 4; ++mi) {
#pragma unroll
        for (int ni = 0; ni < 2; ++ni) {
            int col = col0 + ni * 16;
            if (col >= N) continue;
            float bv = bias ? bias[col] : 0.f;
#pragma unroll
            for (int r = 0; r < 4; ++r) {
                int row = m0 + wm * 64 + mi * 16 + rloc + r;
                if (row >= M) continue;
                float v = acc[mi][ni][r] + bv;
                if (act == 1) v = gelu_f(v);
                else if (act == 2) v = fmaxf(v, 0.f);
                v *= alpha;
                if (res) v += res[(size_t)row * ldr + col];
                if (Cf) Cf[(size_t)row * ldc + col] = v;
                if (Cb) Cb[(size_t)row * ldc + col] = __float2bfloat16(v);
            }
        }
    }
}

// ---------------- MFMA conv (round-3 proven 128x64 body + kh-split via blockIdx.z) ----------------
// split z handles kh in [2z, min(2z+2, KS)); writes fp32 partial to part[z].
template <int KS>
__global__ __launch_bounds__(256) void mconv_kernel(
    const __hip_bfloat16* __restrict__ P, const __hip_bfloat16* __restrict__ Wt,
    float* __restrict__ part) {
    const int K = KS * KS * DD;
    const int OFF = 3 - KS / 2;
    const int kh0 = blockIdx.z * 2;
    const int nkh = (KS - kh0 < 2) ? (KS - kh0) : 2;
    const int Ksub = nkh * KS * DD;          // divisible by 64 for KS in {3,5,7}
    const int wbase = kh0 * KS * DD;
    float* __restrict__ Cp = part + (size_t)blockIdx.z * BS * DD;
    __shared__ short As[128 * LDK];
    __shared__ short Bs[64 * LDK];
    const int tid = threadIdx.x;
    const int m0 = blockIdx.y * 128, n0 = blockIdx.x * 64;
    const int lane = tid & 63;
    const int w = tid >> 6, wm = w >> 1, wn = w & 1;
    const int rbase = tid >> 3, q8 = (tid & 7) * 8;
    f32x4 acc[4][2];
    const f32x4 fz = {0.f, 0.f, 0.f, 0.f};
#pragma unroll
    for (int mi = 0; mi < 4; ++mi)
#pragma unroll
        for (int ni = 0; ni < 2; ++ni) acc[mi][ni] = fz;
    const short8 zz = {0, 0, 0, 0, 0, 0, 0, 0};
    for (int k0 = 0; k0 < Ksub; k0 += 64) {
#pragma unroll
        for (int c = 0; c < 4; ++c) {
            int r = c * 32 + rbase, m = m0 + r;
            int k = k0 + q8;
            int ci = k % DD, t = k / DD;
            int kw = t % KS, kh = kh0 + t / KS;
            short8 v = zz;
            if (m < BS) {
                int b = m / SS, hw = m % SS, oh = hw / GG_, ow = hw % GG_;
                int ih = oh + kh + OFF, iw = ow + kw + OFF;
                v = *(const short8*)((const short*)P + (((b * 36 + ih) * 36 + iw) * DD + ci));
            }
            *(short8*)(As + r * LDK + q8) = v;
        }
#pragma unroll
        for (int c = 0; c < 2; ++c) {
            int r = c * 32 + rbase, n = n0 + r;
            short8 v = *(const short8*)((const short*)Wt + (size_t)n * K + wbase + k0 + q8);
            *(short8*)(Bs + r * LDK + q8) = v;
        }
        __syncthreads();
#pragma unroll
        for (int ks = 0; ks < 64; ks += 32) {
            const int kb = ks + (lane >> 4) * 8;
            short8 af[4], bf[2];
#pragma unroll
            for (int mi = 0; mi < 4; ++mi)
                af[mi] = *(const short8*)(As + (wm * 64 + mi * 16 + (lane & 15)) * LDK + kb);
#pragma unroll
            for (int ni = 0; ni < 2; ++ni)
                bf[ni] = *(const short8*)(Bs + (wn * 32 + ni * 16 + (lane & 15)) * LDK + kb);
#pragma unroll
            for (int mi = 0; mi < 4; ++mi)
#pragma unroll
                for (int ni = 0; ni < 2; ++ni)
                    acc[mi][ni] = __builtin_amdgcn_mfma_f32_16x16x32_bf16(af[mi], bf[ni], acc[mi][ni], 0, 0, 0);
        }
        __syncthreads();
    }
    const int col0 = n0 + wn * 32 + (lane & 15);
    const int rloc = (lane >> 4) * 4;
#pragma unroll
    for (int mi = 0; mi < 4; ++mi) {
#pragma unroll
        for (int ni = 0; ni < 2; ++ni) {
            int col = col0 + ni * 16;
#pragma unroll
            for (int r = 0; r < 4; ++r) {
                int row = m0 + wm * 64 + mi * 16 + rloc + r;
                if (row < BS) Cp[(size_t)row * DD + col] = acc[mi][ni][r];
            }
        }
    }
}

// ---------------- conv partial reduce: relu(sum parts + bias) -> bf16 @ldc ----------------
__global__ __launch_bounds__(256) void creduce_kernel(const float* __restrict__ part, int nsplit,
                                                      const float* __restrict__ bias,
                                                      __hip_bfloat16* __restrict__ outb, int ldc) {
    int idx = blockIdx.x * 256 + threadIdx.x;      // over BS*DD/4 float4s
    if (idx >= BS * DD / 4) return;
    int row = idx / (DD / 4), c4 = (idx % (DD / 4)) * 4;
    f32x4 s = *(const f32x4*)(part + (size_t)row * DD + c4);
    for (int p = 1; p < nsplit; ++p) {
        f32x4 v = *(const f32x4*)(part + (size_t)p * BS * DD + (size_t)row * DD + c4);
        s[0] += v[0]; s[1] += v[1]; s[2] += v[2]; s[3] += v[3];
    }
    __hip_bfloat16* o = outb + (size_t)row * ldc + c4;
#pragma unroll
    for (int j = 0; j < 4; ++j) o[j] = __float2bfloat16(fmaxf(s[j] + bias[c4 + j], 0.f));
}

// ---------------- pad bf16 image for convs ----------------
__global__ void pad_kernel(const __hip_bfloat16* __restrict__ xb, __hip_bfloat16* __restrict__ p) {
    int idx = blockIdx.x * 256 + threadIdx.x;   // 4*36*36*320
    if (idx >= BB * 36 * 36 * DD) return;
    int c = idx % DD, t = idx / DD;
    int wp = t % 36, t2 = t / 36, hp = t2 % 36, b = t2 / 36;
    __hip_bfloat16 v = __float2bfloat16(0.f);
    if (hp >= 3 && hp < 33 && wp >= 3 && wp < 33)
        v = xb[((b * SS + (hp - 3) * GG_ + (wp - 3))) * DD + c];
    p[idx] = v;
}

// ---------------- legacy fp32 GEMM (tiny op heads) ----------------
__global__ __launch_bounds__(256) void gemm_kernel(
    const float* __restrict__ A, int lda, const float* __restrict__ W,
    const float* __restrict__ bias, float* __restrict__ C, int ldc,
    int M, int N, int K, int act) {
    __shared__ float As[16][65];
    __shared__ float Ws[16][65];
    const int tid = threadIdx.x;
    const int m0 = blockIdx.y * 64, n0 = blockIdx.x * 64;
    const int tx = tid & 15, ty = tid >> 4;
    float acc[4][4] = {};
    const int kkA = tid & 15, mloc0 = tid >> 4;
    const int nloc = tid & 63, kk0 = tid >> 6;
    for (int k0 = 0; k0 < K; k0 += 16) {
        const int kA = k0 + kkA;
#pragma unroll
        for (int i = 0; i < 4; ++i) {
            int mloc = mloc0 + i * 16, m = m0 + mloc;
            As[kkA][mloc] = (m < M && kA < K) ? A[m * lda + kA] : 0.f;
        }
#pragma unroll
        for (int i = 0; i < 4; ++i) {
            int kk = kk0 + i * 4, k = k0 + kk, n = n0 + nloc;
            Ws[kk][nloc] = (k < K && n < N) ? W[k * N + n] : 0.f;
        }
        __syncthreads();
#pragma unroll
        for (int kk = 0; kk < 16; ++kk) {
            float a[4], b[4];
#pragma unroll
            for (int i = 0; i < 4; ++i) a[i] = As[kk][ty * 4 + i];
#pragma unroll
            for (int j = 0; j < 4; ++j) b[j] = Ws[kk][tx * 4 + j];
#pragma unroll
            for (int i = 0; i < 4; ++i)
#pragma unroll
                for (int j = 0; j < 4; ++j) acc[i][j] = fmaf(a[i], b[j], acc[i][j]);
        }
        __syncthreads();
    }
#pragma unroll
    for (int i = 0; i < 4; ++i) {
        int m = m0 + ty * 4 + i;
        if (m >= M) continue;
#pragma unroll
        for (int j = 0; j < 4; ++j) {
            int n = n0 + tx * 4 + j;
            if (n >= N) continue;
            float v = acc[i][j] + bias[n];
            if (act == 1) v = gelu_f(v);
            C[m * ldc + n] = v;
        }
    }
}

// ---------------- geometric bias table: [NH][900][960] bf16 ----------------
__global__ __launch_bounds__(256) void bias_kernel(const float* __restrict__ de,
                                                   const float* __restrict__ dre,
                                                   const int* __restrict__ dist,
                                                   const int* __restrict__ dirn,
                                                   __hip_bfloat16* __restrict__ out) {
    const int h = blockIdx.y;
    int idx = blockIdx.x * 256 + threadIdx.x;      // 900*960 = 864000
    int sq = idx / 960, t = idx - sq * 960;
    float v = 0.f;
    if (t < SS) v = de[dist[sq * SS + t] * NHH + h] + dre[dirn[sq * SS + t] * NHH + h];
    out[((size_t)h * SS + sq) * 960 + t] = __float2bfloat16(v);
}

// ---------------- V transpose: Vbf[BS][320] -> VT[b][h][48][960] ----------------
__global__ __launch_bounds__(256) void vt_kernel(const __hip_bfloat16* __restrict__ V,
                                                 __hip_bfloat16* __restrict__ VT) {
    int idx = blockIdx.x * 256 + threadIdx.x;      // 4*8*48*960 = 1474560
    int t = idx % 960;
    int d = (idx / 960) % 48;
    int h = (idx / (960 * 48)) % NHH;
    int b = idx / (960 * 48 * NHH);
    __hip_bfloat16 v = __float2bfloat16(0.f);
    if (t < SS && d < DKK) v = V[((size_t)b * SS + t) * DD + h * DKK + d];
    VT[idx] = v;
}

// ---------------- MFMA flash attention ----------------
#define LQ 56
#define LK 56
#define LV 72
#define LP 72
__global__ __launch_bounds__(256) void mattn_kernel(
    const __hip_bfloat16* __restrict__ Qg, const __hip_bfloat16* __restrict__ Kg,
    const __hip_bfloat16* __restrict__ VTg, const __hip_bfloat16* __restrict__ BIASg,
    __hip_bfloat16* __restrict__ AO) {
    const int qt = blockIdx.x, h = blockIdx.y, b = blockIdx.z;
    const int tid = threadIdx.x, lane = tid & 63, w = tid >> 6;
    const int lhi = lane >> 4, llo = lane & 15;
    __shared__ short Qs[64 * LQ];
    __shared__ short Ks[64 * LK];
    __shared__ short Vs[48 * LV];
    __shared__ short Ps[4][16 * LP];
    short* Ps_w = Ps[w];
    const int q0 = qt * 64;
    const short4v z4 = {0, 0, 0, 0};
    const f32x4 fz = {0.f, 0.f, 0.f, 0.f};
    const float scale = 0.15811388300841898f;  // 1/sqrt(40)

    for (int task = tid; task < 64 * 14; task += 256) {
        int r = task / 14, d0 = (task - r * 14) * 4;
        int q = q0 + r;
        short4v v = z4;
        if (q < SS && d0 < DKK)
            v = *(const short4v*)((const short*)Qg + ((size_t)b * SS + q) * DD + h * DKK + d0);
        *(short4v*)(Qs + r * LQ + d0) = v;
    }
    __syncthreads();
    short8 qa[2];
#pragma unroll
    for (int ks = 0; ks < 2; ++ks)
        qa[ks] = *(const short8*)(Qs + (w * 16 + llo) * LQ + ks * 32 + lhi * 8);

    float mrow[4] = {-1e30f, -1e30f, -1e30f, -1e30f};
    float lrow[4] = {0.f, 0.f, 0.f, 0.f};
    f32x4 o[3] = {fz, fz, fz};
    const int qrow = q0 + w * 16 + lhi * 4;

    for (int t = 0; t < 15; ++t) {
        const int kv0 = t * 64;
        for (int task = tid; task < 64 * 14; task += 256) {
            int r = task / 14, d0 = (task - r * 14) * 4;
            int kv = kv0 + r;
            short4v v = z4;
            if (kv < SS && d0 < DKK)
                v = *(const short4v*)((const short*)Kg + ((size_t)b * SS + kv) * DD + h * DKK + d0);
            *(short4v*)(Ks + r * LK + d0) = v;
        }
        for (int task = tid; task < 48 * 16; task += 256) {
            int r = task / 16, c4 = (task - r * 16) * 4;
            short4v v = *(const short4v*)((const short*)VTg +
                         (((size_t)b * NHH + h) * 48 + r) * 960 + kv0 + c4);
            *(short4v*)(Vs + r * LV + c4) = v;
        }
        __syncthreads();
        f32x4 s[4] = {fz, fz, fz, fz};
#pragma unroll
        for (int ks = 0; ks < 2; ++ks) {
#pragma unroll
            for (int ni = 0; ni < 4; ++ni) {
                short8 kb = *(const short8*)(Ks + (ni * 16 + llo) * LK + ks * 32 + lhi * 8);
                s[ni] = __builtin_amdgcn_mfma_f32_16x16x32_bf16(qa[ks], kb, s[ni], 0, 0, 0);
            }
        }
#pragma unroll
        for (int ni = 0; ni < 4; ++ni) {
            int col = kv0 + ni * 16 + llo;
#pragma unroll
            for (int r = 0; r < 4; ++r) {
                int qc = qrow + r; if (qc > SS - 1) qc = SS - 1;
                float v = s[ni][r] * scale +
                          __bfloat162float(BIASg[((size_t)h * SS + qc) * 960 + col]);
                s[ni][r] = (col < SS) ? v : -1e30f;
            }
        }
        float rmax[4], psum[4], corr[4];
#pragma unroll
        for (int r = 0; r < 4; ++r)
            rmax[r] = fmaxf(fmaxf(s[0][r], s[1][r]), fmaxf(s[2][r], s[3][r]));
#pragma unroll
        for (int off = 1; off < 16; off <<= 1)
#pragma unroll
            for (int r = 0; r < 4; ++r)
                rmax[r] = fmaxf(rmax[r], __shfl_xor(rmax[r], off));
#pragma unroll
        for (int r = 0; r < 4; ++r) {
            float mnew = fmaxf(mrow[r], rmax[r]);
            corr[r] = expf(mrow[r] - mnew);
            mrow[r] = mnew;
            float ps = 0.f;
#pragma unroll
            for (int ni = 0; ni < 4; ++ni) {
                float p = expf(s[ni][r] - mnew);
                s[ni][r] = p;
                ps += p;
            }
            psum[r] = ps;
        }
#pragma unroll
        for (int off = 1; off < 16; off <<= 1)
#pragma unroll
            for (int r = 0; r < 4; ++r) psum[r] += __shfl_xor(psum[r], off);
#pragma unroll
        for (int r = 0; r < 4; ++r) lrow[r] = lrow[r] * corr[r] + psum[r];
#pragma unroll
        for (int nj = 0; nj < 3; ++nj)
#pragma unroll
            for (int r = 0; r < 4; ++r) o[nj][r] *= corr[r];
#pragma unroll
        for (int ni = 0; ni < 4; ++ni)
#pragma unroll
            for (int r = 0; r < 4; ++r)
                ((__hip_bfloat16*)Ps_w)[(lhi * 4 + r) * LP + ni * 16 + llo] =
                    __float2bfloat16(s[ni][r]);
#pragma unroll
        for (int ks = 0; ks < 2; ++ks) {
            short8 pa = *(const short8*)(Ps_w + llo * LP + ks * 32 + lhi * 8);
#pragma unroll
            for (int nj = 0; nj < 3; ++nj) {
                short8 vb = *(const short8*)(Vs + (nj * 16 + llo) * LV + ks * 32 + lhi * 8);
                o[nj] = __builtin_amdgcn_mfma_f32_16x16x32_bf16(pa, vb, o[nj], 0, 0, 0);
            }
        }
        __syncthreads();
    }
#pragma unroll
    for (int nj = 0; nj < 3; ++nj) {
        int d = nj * 16 + llo;
        if (d >= DKK) continue;
#pragma unroll
        for (int r = 0; r < 4; ++r) {
            int q = qrow + r;
            if (q < SS)
                AO[((size_t)b * SS + q) * DD + h * DKK + d] = __float2bfloat16(o[nj][r] / lrow[r]);
        }
    }
}

// ---------------- row LayerNorm (proven LDS-tree version) ----------------
__global__ __launch_bounds__(320) void ln_kernel(const float* __restrict__ a,
                                                 const float* __restrict__ add,
                                                 const float* __restrict__ g,
                                                 const float* __restrict__ bta,
                                                 float* __restrict__ out,
                                                 __hip_bfloat16* __restrict__ outb) {
    const int row = blockIdx.x, i = threadIdx.x;
    __shared__ float red[320];
    __shared__ float s_m, s_v;
    float v = a[row * DD + i];
    if (add) v += add[row * DD + i];
    red[i] = v;
    __syncthreads();
    if (i < 64) red[i] += red[i + 256];
    __syncthreads();
    for (int s = 128; s > 0; s >>= 1) {
        if (i < s) red[i] += red[i + s];
        __syncthreads();
    }
    if (i == 0) s_m = red[0] * (1.0f / DD);
    __syncthreads();
    const float d = v - s_m;
    red[i] = d * d;
    __syncthreads();
    if (i < 64) red[i] += red[i + 256];
    __syncthreads();
    for (int s = 128; s > 0; s >>= 1) {
        if (i < s) red[i] += red[i + s];
        __syncthreads();
    }
    if (i == 0) s_v = red[0] * (1.0f / DD);
    __syncthreads();
    float o = d * rsqrtf(s_v + 1e-5f) * g[i] + bta[i];
    out[row * DD + i] = o;
    outb[row * DD + i] = __float2bfloat16(o);
}

// ---------------- global mean over S ----------------
__global__ __launch_bounds__(256) void mean_kernel(const float* __restrict__ xs, float* __restrict__ g) {
    const int b = blockIdx.y, d = blockIdx.x * 64 + (threadIdx.x & 63);
    const int rg = threadIdx.x >> 6;
    float s = 0.f;
    for (int t = rg; t < SS; t += 4) s += xs[((size_t)b * SS + t) * DD + d];
    __shared__ float red[256];
    red[threadIdx.x] = s;
    __syncthreads();
    if (threadIdx.x < 128) red[threadIdx.x] += red[threadIdx.x + 128];
    __syncthreads();
    if (threadIdx.x < 64) g[b * DD + d] = (red[threadIdx.x] + red[threadIdx.x + 64]) * (1.0f / SS);
}

// ---------------- transform params ----------------
__global__ __launch_bounds__(64) void tp_kernel(const float* __restrict__ g,
                                                const float* __restrict__ wrot, const float* __restrict__ brot,
                                                const float* __restrict__ wrefl, const float* __restrict__ brefl,
                                                const float* __restrict__ wtr, const float* __restrict__ btr,
                                                const float* __restrict__ wsc, const float* __restrict__ bsc,
                                                float* __restrict__ tp) {
    const int b = blockIdx.x, tid = threadIdx.x;
    __shared__ float gs[DD];
    __shared__ float raw[17];
    for (int j = tid; j < DD; j += 64) gs[j] = g[b * DD + j];
    __syncthreads();
    if (tid < 17) {
        float s;
        if (tid < 4) {
            s = brot[tid];
            for (int d = 0; d < DD; ++d) s = fmaf(gs[d], wrot[d * 4 + tid], s);
        } else if (tid < 12) {
            int j = tid - 4;
            s = brefl[j];
            for (int d = 0; d < DD; ++d) s = fmaf(gs[d], wrefl[d * 8 + j], s);
        } else if (tid < 14) {
            int j = tid - 12;
            s = btr[j];
            for (int d = 0; d < DD; ++d) s = fmaf(gs[d], wtr[d * 2 + j], s);
        } else {
            int j = tid - 14;
            s = bsc[j];
            for (int d = 0; d < DD; ++d) s = fmaf(gs[d], wsc[d * 3 + j], s);
        }
        raw[tid] = s;
    }
    __syncthreads();
    if (tid == 0) {
        float mx = -1e30f;
        for (int j = 0; j < 4; ++j) mx = fmaxf(mx, raw[j]);
        float sm = 0.f, e[4];
        for (int j = 0; j < 4; ++j) { e[j] = expf(raw[j] - mx); sm += e[j]; }
        for (int j = 0; j < 4; ++j) tp[b * 17 + j] = e[j] / sm;
    } else if (tid == 1) {
        float mx = -1e30f;
        for (int j = 4; j < 12; ++j) mx = fmaxf(mx, raw[j]);
        float sm = 0.f, e[8];
        for (int j = 0; j < 8; ++j) { e[j] = expf(raw[4 + j] - mx); sm += e[j]; }
        for (int j = 0; j < 8; ++j) tp[b * 17 + 4 + j] = e[j] / sm;
    } else if (tid == 2) {
        tp[b * 17 + 12] = tanhf(raw[12]);
        tp[b * 17 + 13] = tanhf(raw[13]);
    } else if (tid == 3) {
        float mx = -1e30f;
        for (int j = 14; j < 17; ++j) mx = fmaxf(mx, raw[j]);
        float sm = 0.f, e[3];
        for (int j = 0; j < 3; ++j) { e[j] = expf(raw[14 + j] - mx); sm += e[j]; }
        for (int j = 0; j < 3; ++j) tp[b * 17 + 14 + j] = e[j] / sm;
    }
}

// ---------------- concat xs(bf16) + tp -> TIbf [3600, 384] ----------------
__global__ void concat_kernel(const __hip_bfloat16* __restrict__ xb, const float* __restrict__ tp,
                              __hip_bfloat16* __restrict__ ti) {
    int idx = blockIdx.x * 256 + threadIdx.x;
    if (idx >= BS * 384) return;
    int m = idx / 384, j = idx % 384;
    __hip_bfloat16 v;
    if (j < DD) v = xb[m * DD + j];
    else if (j < 337) v = __float2bfloat16(tp[(m / SS) * 17 + (j - DD)]);
    else v = __float2bfloat16(0.f);
    ti[idx] = v;
}

static inline void launch_mgemm(hipStream_t s, const __hip_bfloat16* A, int lda,
                                const __hip_bfloat16* Wt, int ldw, const float* bias,
                                const float* res, int ldr, float alpha, float* Cf,
                                __hip_bfloat16* Cb, int ldc, int M, int N, int K, int act) {
    dim3 g((N + 63) / 64, (M + 127) / 128);
    mgemm_kernel<<<g, 256, 0, s>>>(A, lda, Wt, ldw, bias, res, ldr, alpha, Cf, Cb, ldc, M, N, K, act);
}

extern "C" void kernel_launch(void* const* d_in, const int* in_sizes, int n_in,
                              void* d_out, int out_size, void* d_ws, size_t ws_size,
                              hipStream_t stream) {
    (void)in_sizes; (void)n_in; (void)out_size; (void)ws_size;
    const int* in_grid = (const int*)d_in[0];
    const float* pe = (const float*)d_in[1];
    const float* iew = (const float*)d_in[2];
    const float* ieb = (const float*)d_in[3];
    const float* wq = (const float*)d_in[4], *bq = (const float*)d_in[5];
    const float* wk = (const float*)d_in[6], *bk = (const float*)d_in[7];
    const float* wv = (const float*)d_in[8], *bv = (const float*)d_in[9];
    const float* wo = (const float*)d_in[10], *bo = (const float*)d_in[11];
    const float* lnag = (const float*)d_in[12], *lnab = (const float*)d_in[13];
    const float* dist_emb = (const float*)d_in[14], *dir_emb = (const float*)d_in[15];
    const float* wrot = (const float*)d_in[16], *brot = (const float*)d_in[17];
    const float* wrefl = (const float*)d_in[18], *brefl = (const float*)d_in[19];
    const float* wtr = (const float*)d_in[20], *btr = (const float*)d_in[21];
    const float* wsc = (const float*)d_in[22], *bsc = (const float*)d_in[23];
    const float* tnw1 = (const float*)d_in[24], *tnb1 = (const float*)d_in[25];
    const float* tnw2 = (const float*)d_in[26], *tnb2 = (const float*)d_in[27];
    const float* tnw3 = (const float*)d_in[28], *tnb3 = (const float*)d_in[29];
    const float* ffw1 = (const float*)d_in[30], *ffb1 = (const float*)d_in[31];
    const float* ffw2 = (const float*)d_in[32], *ffb2 = (const float*)d_in[33];
    const float* ln2g = (const float*)d_in[34], *ln2b = (const float*)d_in[35];
    const float* ck1 = (const float*)d_in[36], *cb1 = (const float*)d_in[37];
    const float* ck3 = (const float*)d_in[38], *cb3 = (const float*)d_in[39];
    const float* ck5 = (const float*)d_in[40], *cb5 = (const float*)d_in[41];
    const float* ck7 = (const float*)d_in[42], *cb7 = (const float*)d_in[43];
    const float* fusw = (const float*)d_in[44], *fusb = (const float*)d_in[45];
    const float* opw1 = (const float*)d_in[46], *opb1 = (const float*)d_in[47];
    const float* opw2 = (const float*)d_in[48], *opb2 = (const float*)d_in[49];
    const float* opw3 = (const float*)d_in[50], *opb3 = (const float*)d_in[51];
    const int* dist_idx = (const int*)d_in[52];
    const int* dir_idx = (const int*)d_in[53];
    float* out = (float*)d_out;

    // ---- workspace arena (byte offsets) ----
    char* base = (char*)d_ws;
    typedef __hip_bfloat16 bf;
    bf* WQT = (bf*)(base + 0);
    bf* WKT = (bf*)(base + 819200);
    bf* WVT = (bf*)(base + 1638400);
    bf* WOT = (bf*)(base + 2457600);
    bf* TN1T = (bf*)(base + 3276800);
    bf* TN2T = (bf*)(base + 5242880);
    bf* TN3T = (bf*)(base + 6881280);
    bf* FF1T = (bf*)(base + 7700480);
    bf* FF2T = (bf*)(base + 10977280);
    bf* CK1T = (bf*)(base + 14254080);
    bf* CK3T = (bf*)(base + 14458880);
    bf* CK5T = (bf*)(base + 16302080);
    bf* CK7T = (bf*)(base + 21422080);
    bf* FUST = (bf*)(base + 31457280);
    bf* OP1T = (bf*)(base + 32276480);
    float* XS = (float*)(base + 32378880);
    bf* XSbf = (bf*)(base + 36986880);
    bf* Qbf = (bf*)(base + 39290880);
    bf* Kbf = (bf*)(base + 41594880);
    bf* Vbf = (bf*)(base + 43898880);
    bf* VT = (bf*)(base + 46202880);      // ends 49,152,000
    float* R2 = (float*)(base + 53114880);
    float* Gm = (float*)(base + 57722880);
    float* TP = (float*)(base + 57728000);
    // conv partials: [4][3600][320] fp32 = 18,432,000 B in dead Qbf..R2 region (39,290,880..57,722,880)
    float* CPART = (float*)(base + 39290880);
    char* BIG = base + 57728512;
    bf* AObf = (bf*)(BIG + 0);
    bf* BIAS = (bf*)(BIG + 2764800);
    bf* TIbf = (bf*)(BIG + 0);
    bf* T1bf = (bf*)(BIG + 2764800);
    bf* T2bf = (bf*)(BIG + 7372800);
    bf* F1bf = (bf*)(BIG + 0);
    bf* PADbf = (bf*)(BIG + 0);
    bf* FEATSbf = (bf*)(BIG + 3317760);
    float* H1 = (float*)(BIG + 0);
    float* H2 = (float*)(BIG + 2304000);
    bf* R2bf = XSbf;

    dim3 cb(32, 8);
    convt_kernel<<<dim3(10, 10, 4), cb, 0, stream>>>(wq, WQT, 320, 320, 320, 102400, 102400);
    convt_kernel<<<dim3(10, 10, 4), cb, 0, stream>>>(wk, WKT, 320, 320, 320, 102400, 102400);
    convt_kernel<<<dim3(10, 10, 4), cb, 0, stream>>>(wv, WVT, 320, 320, 320, 102400, 102400);
    convt_kernel<<<dim3(10, 10, 4), cb, 0, stream>>>(wo, WOT, 320, 320, 320, 102400, 102400);
    convt_kernel<<<dim3(12, 20, 4), cb, 0, stream>>>(tnw1, TN1T, 337, 640, 384, 215680, 245760);
    convt_kernel<<<dim3(20, 10, 4), cb, 0, stream>>>(tnw2, TN2T, 640, 320, 640, 204800, 204800);
    convt_kernel<<<dim3(10, 10, 4), cb, 0, stream>>>(tnw3, TN3T, 320, 320, 320, 102400, 102400);
    convt_kernel<<<dim3(10, 40, 4), cb, 0, stream>>>(ffw1, FF1T, 320, 1280, 320, 409600, 409600);
    convt_kernel<<<dim3(40, 10, 4), cb, 0, stream>>>(ffw2, FF2T, 1280, 320, 1280, 409600, 409600);
    convt_kernel<<<dim3(10, 10, 1), cb, 0, stream>>>(ck1, CK1T, 320, 320, 320, 0, 0);
    convt_kernel<<<dim3(90, 10, 1), cb, 0, stream>>>(ck3, CK3T, 2880, 320, 2880, 0, 0);
    convt_kernel<<<dim3(250, 10, 1), cb, 0, stream>>>(ck5, CK5T, 8000, 320, 8000, 0, 0);
    convt_kernel<<<dim3(490, 10, 1), cb, 0, stream>>>(ck7, CK7T, 15680, 320, 15680, 0, 0);
    convt_kernel<<<dim3(40, 10, 1), cb, 0, stream>>>(fusw, FUST, 1280, 320, 1280, 0, 0);
    convt_kernel<<<dim3(10, 5, 1), cb, 0, stream>>>(opw1, OP1T, 320, 160, 320, 0, 0);

    embed_kernel<<<4500, 256, 0, stream>>>(in_grid, pe, iew, ieb, XS, XSbf);

    for (int l = 0; l < LL; ++l) {
        const int wO = l * DD * DD, bO = l * DD;
        launch_mgemm(stream, XSbf, DD, WQT + wO, DD, bq + bO, nullptr, 0, 1.f, nullptr, Qbf, DD, BS, DD, DD, 0);
        launch_mgemm(stream, XSbf, DD, WKT + wO, DD, bk + bO, nullptr, 0, 1.f, nullptr, Kbf, DD, BS, DD, DD, 0);
        launch_mgemm(stream, XSbf, DD, WVT + wO, DD, bv + bO, nullptr, 0, 1.f, nullptr, Vbf, DD, BS, DD, DD, 0);
        vt_kernel<<<5760, 256, 0, stream>>>(Vbf, VT);
        bias_kernel<<<dim3(3375, NHH), 256, 0, stream>>>(dist_emb + l * 60 * NHH, dir_emb + l * 8 * NHH,
                                                         dist_idx, dir_idx, BIAS);
        mattn_kernel<<<dim3(15, NHH, BB), 256, 0, stream>>>(Qbf, Kbf, VT, BIAS, AObf);
        launch_mgemm(stream, AObf, DD, WOT + wO, DD, bo + bO, XS, DD, 1.f, R2, nullptr, DD, BS, DD, DD, 0);
        ln_kernel<<<BS, 320, 0, stream>>>(R2, nullptr, lnag + bO, lnab + bO, XS, XSbf);
        mean_kernel<<<dim3(5, BB), 256, 0, stream>>>(XS, Gm);
        tp_kernel<<<BB, 64, 0, stream>>>(Gm, wrot + l * 1280, brot + l * 4,
                                         wrefl + l * 2560, brefl + l * 8,
                                         wtr + l * 640, btr + l * 2,
                                         wsc + l * 960, bsc + l * 3, TP);
        concat_kernel<<<(BS * 384 + 255) / 256, 256, 0, stream>>>(XSbf, TP, TIbf);
        launch_mgemm(stream, TIbf, 384, TN1T + l * 245760, 384, tnb1 + l * 640, nullptr, 0, 1.f,
                     nullptr, T1bf, 640, BS, 640, 384, 1);
        launch_mgemm(stream, T1bf, 640, TN2T + l * 204800, 640, tnb2 + bO, nullptr, 0, 1.f,
                     nullptr, T2bf, DD, BS, DD, 640, 1);
        launch_mgemm(stream, T2bf, DD, TN3T + wO, DD, tnb3 + bO, XS, DD, 0.3f,
                     XS, XSbf, DD, BS, DD, DD, 0);
        launch_mgemm(stream, XSbf, DD, FF1T + l * 409600, DD, ffb1 + l * FFD, nullptr, 0, 1.f,
                     nullptr, F1bf, FFD, BS, FFD, DD, 1);
        launch_mgemm(stream, F1bf, FFD, FF2T + l * 409600, FFD, ffb2 + bO, nullptr, 0, 1.f,
                     R2, nullptr, DD, BS, DD, FFD, 0);
        ln_kernel<<<BS, 320, 0, stream>>>(R2, XS, ln2g + bO, ln2b + bO, XS, XSbf);
    }

    // ---- multiscale convs: kh-split (z) fp32 partials + reduce ----
    pad_kernel<<<(BB * 36 * 36 * DD + 255) / 256, 256, 0, stream>>>(XSbf, PADbf);
    launch_mgemm(stream, XSbf, DD, CK1T, DD, cb1, nullptr, 0, 1.f, nullptr, FEATSbf + 0, 1280, BS, DD, DD, 2);
    const int RED = (BS * DD / 4 + 255) / 256;
    mconv_kernel<3><<<dim3(5, 29, 2), 256, 0, stream>>>(PADbf, CK3T, CPART);
    creduce_kernel<<<RED, 256, 0, stream>>>(CPART, 2, cb3, FEATSbf + 320, 1280);
    mconv_kernel<5><<<dim3(5, 29, 3), 256, 0, stream>>>(PADbf, CK5T, CPART);
    creduce_kernel<<<RED, 256, 0, stream>>>(CPART, 3, cb5, FEATSbf + 640, 1280);
    mconv_kernel<7><<<dim3(5, 29, 4), 256, 0, stream>>>(PADbf, CK7T, CPART);
    creduce_kernel<<<RED, 256, 0, stream>>>(CPART, 4, cb7, FEATSbf + 960, 1280);
    launch_mgemm(stream, FEATSbf, 1280, FUST, 1280, fusb, nullptr, 0, 1.f, nullptr, R2bf, DD, BS, DD, 1280, 0);
    // ---- output head ----
    launch_mgemm(stream, R2bf, DD, OP1T, DD, opb1, nullptr, 0, 1.f, H1, nullptr, 160, BS, 160, DD, 1);
    gemm_kernel<<<dim3(2, 57), 256, 0, stream>>>(H1, 160, opw2, opb2, H2, 80, BS, 80, 160, 1);
    gemm_kernel<<<dim3(1, 57), 256, 0, stream>>>(H2, 80, opw3, opb3, out, 10, BS, 10, 80, 0);
}

// Round 7
// 2110.573 us; speedup vs baseline: 5.2344x; 1.0674x over previous
//
#include <hip/hip_runtime.h>
#include <hip/hip_bf16.h>

#define BB 4
#define GG_ 30
#define DD 320
#define LL 4
#define NHH 8
#define DKK 40
#define SS 900
#define BS 3600
#define FFD 1280
#define LDK 72   // BK(64) + 8 pad, in bf16 elems -> 144B row stride, 16B aligned

typedef __attribute__((ext_vector_type(8))) short short8;
typedef __attribute__((ext_vector_type(4))) short short4v;
typedef __attribute__((ext_vector_type(4))) float f32x4;

__device__ __forceinline__ float gelu_f(float x) {
    return 0.5f * x * (1.0f + erff(x * 0.70710678118654752f));
}

// ---------------- weight convert fp32[K,N] -> bf16 transposed [N,Kpad] ----------------
__global__ __launch_bounds__(256) void convt_kernel(const float* __restrict__ src,
                                                    __hip_bfloat16* __restrict__ dst,
                                                    int K, int N, int Kpad,
                                                    int srcStride, int dstStride) {
    __shared__ float t[32][33];
    const int mat = blockIdx.z;
    const float* s = src + (size_t)mat * srcStride;
    __hip_bfloat16* d = dst + (size_t)mat * dstStride;
    const int kb = blockIdx.x * 32, nb = blockIdx.y * 32;
    const int tx = threadIdx.x, ty = threadIdx.y;   // (32, 8)
#pragma unroll
    for (int i = 0; i < 4; ++i) {
        int k = kb + ty + i * 8, n = nb + tx;
        t[ty + i * 8][tx] = (k < K && n < N) ? s[(size_t)k * N + n] : 0.f;
    }
    __syncthreads();
#pragma unroll
    for (int i = 0; i < 4; ++i) {
        int n = nb + ty + i * 8, k = kb + tx;
        if (n < N && k < Kpad) d[(size_t)n * Kpad + k] = __float2bfloat16(t[tx][ty + i * 8]);
    }
}

// ---------------- packed QKV weight convert: [L][960][320] bf16 ----------------
__global__ __launch_bounds__(256) void qkvconvt_kernel(const float* __restrict__ wq,
                                                       const float* __restrict__ wk,
                                                       const float* __restrict__ wv,
                                                       __hip_bfloat16* __restrict__ dst) {
    __shared__ float t[32][33];
    const int z = blockIdx.z, l = z / 3, wsel = z % 3;
    const float* s = (wsel == 0 ? wq : wsel == 1 ? wk : wv) + (size_t)l * 102400;
    __hip_bfloat16* d = dst + (size_t)l * 307200 + wsel * 102400;
    const int kb = blockIdx.x * 32, nb = blockIdx.y * 32;
    const int tx = threadIdx.x, ty = threadIdx.y;   // (32, 8)
#pragma unroll
    for (int i = 0; i < 4; ++i) {
        int k = kb + ty + i * 8, n = nb + tx;
        t[ty + i * 8][tx] = s[(size_t)k * 320 + n];
    }
    __syncthreads();
#pragma unroll
    for (int i = 0; i < 4; ++i) {
        int n = nb + ty + i * 8, k = kb + tx;
        d[(size_t)n * 320 + k] = __float2bfloat16(t[tx][ty + i * 8]);
    }
}

// ---------------- embed ----------------
__global__ void embed_kernel(const int* __restrict__ grid, const float* __restrict__ pe,
                             const float* __restrict__ ew, const float* __restrict__ eb,
                             float* __restrict__ x, __hip_bfloat16* __restrict__ xb) {
    int idx = blockIdx.x * 256 + threadIdx.x;   // < 1,152,000
    int m = idx / DD, d = idx % DD;
    int gv = grid[m];
    float v = ew[gv * DD + d] + eb[d] + pe[(m % SS) * DD + d];
    x[idx] = v;
    xb[idx] = __float2bfloat16(v);
}

// ---------------- MFMA bf16 GEMM (proven 128x64 body; optional 3-way bias) ----------------
__global__ __launch_bounds__(256) void mgemm_kernel(
    const __hip_bfloat16* __restrict__ A, int lda,
    const __hip_bfloat16* __restrict__ Wt, int ldw,
    const float* __restrict__ bias, const float* __restrict__ biasB, const float* __restrict__ biasC,
    const float* __restrict__ res, int ldr,
    float alpha, float* __restrict__ Cf, __hip_bfloat16* __restrict__ Cb, int ldc,
    int M, int N, int K, int act) {
    __shared__ short As[128 * LDK];
    __shared__ short Bs[64 * LDK];
    const int tid = threadIdx.x;
    const int m0 = blockIdx.y * 128, n0 = blockIdx.x * 64;
    const int lane = tid & 63;
    const int w = tid >> 6, wm = w >> 1, wn = w & 1;
    const int rbase = tid >> 3, q8 = (tid & 7) * 8;
    f32x4 acc[4][2];
    const f32x4 fz = {0.f, 0.f, 0.f, 0.f};
#pragma unroll
    for (int mi = 0; mi < 4; ++mi)
#pragma unroll
        for (int ni = 0; ni < 2; ++ni) acc[mi][ni] = fz;
    const short8 zz = {0, 0, 0, 0, 0, 0, 0, 0};
    for (int k0 = 0; k0 < K; k0 += 64) {
#pragma unroll
        for (int c = 0; c < 4; ++c) {
            int r = c * 32 + rbase, m = m0 + r;
            short8 v = zz;
            if (m < M) v = *(const short8*)((const short*)A + (size_t)m * lda + k0 + q8);
            *(short8*)(As + r * LDK + q8) = v;
        }
#pragma unroll
        for (int c = 0; c < 2; ++c) {
            int r = c * 32 + rbase, n = n0 + r;
            short8 v = zz;
            if (n < N) v = *(const short8*)((const short*)Wt + (size_t)n * ldw + k0 + q8);
            *(short8*)(Bs + r * LDK + q8) = v;
        }
        __syncthreads();
#pragma unroll
        for (int ks = 0; ks < 64; ks += 32) {
            const int kb = ks + (lane >> 4) * 8;
            short8 af[4], bf[2];
#pragma unroll
            for (int mi = 0; mi < 4; ++mi)
                af[mi] = *(const short8*)(As + (wm * 64 + mi * 16 + (lane & 15)) * LDK + kb);
#pragma unroll
            for (int ni = 0; ni < 2; ++ni)
                bf[ni] = *(const short8*)(Bs + (wn * 32 + ni * 16 + (lane & 15)) * LDK + kb);
#pragma unroll
            for (int mi = 0; mi < 4; ++mi)
#pragma unroll
                for (int ni = 0; ni < 2; ++ni)
                    acc[mi][ni] = __builtin_amdgcn_mfma_f32_16x16x32_bf16(af[mi], bf[ni], acc[mi][ni], 0, 0, 0);
        }
        __syncthreads();
    }
    const int col0 = n0 + wn * 32 + (lane & 15);
    const int rloc = (lane >> 4) * 4;
#pragma unroll
    for (int mi = 0; mi < 4; ++mi) {
#pragma unroll
        for (int ni = 0; ni < 2; ++ni) {
            int col = col0 + ni * 16;
            if (col >= N) continue;
            float bv;
            if (biasC) bv = (col < 320) ? bias[col] : (col < 640) ? biasB[col - 320] : biasC[col - 640];
            else bv = bias ? bias[col] : 0.f;
#pragma unroll
            for (int r = 0; r < 4; ++r) {
                int row = m0 + wm * 64 + mi * 16 + rloc + r;
                if (row >= M) continue;
                float v = acc[mi][ni][r] + bv;
                if (act == 1) v = gelu_f(v);
                else if (act == 2) v = fmaxf(v, 0.f);
                v *= alpha;
                if (res) v += res[(size_t)row * ldr + col];
                if (Cf) Cf[(size_t)row * ldc + col] = v;
                if (Cb) Cb[(size_t)row * ldc + col] = __float2bfloat16(v);
            }
        }
    }
}

// ---------------- MFMA conv (proven 128x64 body + kh-split, runtime step) ----------------
template <int KS>
__global__ __launch_bounds__(256) void mconv_kernel(
    const __hip_bfloat16* __restrict__ P, const __hip_bfloat16* __restrict__ Wt,
    float* __restrict__ part, int kh0step) {
    const int K = KS * KS * DD;
    const int OFF = 3 - KS / 2;
    const int kh0 = blockIdx.z * kh0step;
    const int nkh = (KS - kh0 < kh0step) ? (KS - kh0) : kh0step;
    const int Ksub = nkh * KS * DD;          // multiples of 64 for KS in {3,5,7}
    const int wbase = kh0 * KS * DD;
    float* __restrict__ Cp = part + (size_t)blockIdx.z * BS * DD;
    __shared__ short As[128 * LDK];
    __shared__ short Bs[64 * LDK];
    const int tid = threadIdx.x;
    const int m0 = blockIdx.y * 128, n0 = blockIdx.x * 64;
    const int lane = tid & 63;
    const int w = tid >> 6, wm = w >> 1, wn = w & 1;
    const int rbase = tid >> 3, q8 = (tid & 7) * 8;
    f32x4 acc[4][2];
    const f32x4 fz = {0.f, 0.f, 0.f, 0.f};
#pragma unroll
    for (int mi = 0; mi < 4; ++mi)
#pragma unroll
        for (int ni = 0; ni < 2; ++ni) acc[mi][ni] = fz;
    const short8 zz = {0, 0, 0, 0, 0, 0, 0, 0};
    for (int k0 = 0; k0 < Ksub; k0 += 64) {
#pragma unroll
        for (int c = 0; c < 4; ++c) {
            int r = c * 32 + rbase, m = m0 + r;
            int k = k0 + q8;
            int ci = k % DD, t = k / DD;
            int kw = t % KS, kh = kh0 + t / KS;
            short8 v = zz;
            if (m < BS) {
                int b = m / SS, hw = m % SS, oh = hw / GG_, ow = hw % GG_;
                int ih = oh + kh + OFF, iw = ow + kw + OFF;
                v = *(const short8*)((const short*)P + (((b * 36 + ih) * 36 + iw) * DD + ci));
            }
            *(short8*)(As + r * LDK + q8) = v;
        }
#pragma unroll
        for (int c = 0; c < 2; ++c) {
            int r = c * 32 + rbase, n = n0 + r;
            short8 v = *(const short8*)((const short*)Wt + (size_t)n * K + wbase + k0 + q8);
            *(short8*)(Bs + r * LDK + q8) = v;
        }
        __syncthreads();
#pragma unroll
        for (int ks = 0; ks < 64; ks += 32) {
            const int kb = ks + (lane >> 4) * 8;
            short8 af[4], bf[2];
#pragma unroll
            for (int mi = 0; mi < 4; ++mi)
                af[mi] = *(const short8*)(As + (wm * 64 + mi * 16 + (lane & 15)) * LDK + kb);
#pragma unroll
            for (int ni = 0; ni < 2; ++ni)
                bf[ni] = *(const short8*)(Bs + (wn * 32 + ni * 16 + (lane & 15)) * LDK + kb);
#pragma unroll
            for (int mi = 0; mi < 4; ++mi)
#pragma unroll
                for (int ni = 0; ni < 2; ++ni)
                    acc[mi][ni] = __builtin_amdgcn_mfma_f32_16x16x32_bf16(af[mi], bf[ni], acc[mi][ni], 0, 0, 0);
        }
        __syncthreads();
    }
    const int col0 = n0 + wn * 32 + (lane & 15);
    const int rloc = (lane >> 4) * 4;
#pragma unroll
    for (int mi = 0; mi < 4; ++mi) {
#pragma unroll
        for (int ni = 0; ni < 2; ++ni) {
            int col = col0 + ni * 16;
#pragma unroll
            for (int r = 0; r < 4; ++r) {
                int row = m0 + wm * 64 + mi * 16 + rloc + r;
                if (row < BS) Cp[(size_t)row * DD + col] = acc[mi][ni][r];
            }
        }
    }
}

// ---------------- conv partial reduce: relu(sum parts + bias) -> bf16 @ldc ----------------
__global__ __launch_bounds__(256) void creduce_kernel(const float* __restrict__ part, int nsplit,
                                                      const float* __restrict__ bias,
                                                      __hip_bfloat16* __restrict__ outb, int ldc) {
    int idx = blockIdx.x * 256 + threadIdx.x;      // over BS*DD/4 float4s
    if (idx >= BS * DD / 4) return;
    int row = idx / (DD / 4), c4 = (idx % (DD / 4)) * 4;
    f32x4 s = *(const f32x4*)(part + (size_t)row * DD + c4);
    for (int p = 1; p < nsplit; ++p) {
        f32x4 v = *(const f32x4*)(part + (size_t)p * BS * DD + (size_t)row * DD + c4);
        s[0] += v[0]; s[1] += v[1]; s[2] += v[2]; s[3] += v[3];
    }
    __hip_bfloat16* o = outb + (size_t)row * ldc + c4;
#pragma unroll
    for (int j = 0; j < 4; ++j) o[j] = __float2bfloat16(fmaxf(s[j] + bias[c4 + j], 0.f));
}

// ---------------- pad bf16 image for convs ----------------
__global__ void pad_kernel(const __hip_bfloat16* __restrict__ xb, __hip_bfloat16* __restrict__ p) {
    int idx = blockIdx.x * 256 + threadIdx.x;   // 4*36*36*320
    if (idx >= BB * 36 * 36 * DD) return;
    int c = idx % DD, t = idx / DD;
    int wp = t % 36, t2 = t / 36, hp = t2 % 36, b = t2 / 36;
    __hip_bfloat16 v = __float2bfloat16(0.f);
    if (hp >= 3 && hp < 33 && wp >= 3 && wp < 33)
        v = xb[((b * SS + (hp - 3) * GG_ + (wp - 3))) * DD + c];
    p[idx] = v;
}

// ---------------- legacy fp32 GEMM (tiny op heads) ----------------
__global__ __launch_bounds__(256) void gemm_kernel(
    const float* __restrict__ A, int lda, const float* __restrict__ W,
    const float* __restrict__ bias, float* __restrict__ C, int ldc,
    int M, int N, int K, int act) {
    __shared__ float As[16][65];
    __shared__ float Ws[16][65];
    const int tid = threadIdx.x;
    const int m0 = blockIdx.y * 64, n0 = blockIdx.x * 64;
    const int tx = tid & 15, ty = tid >> 4;
    float acc[4][4] = {};
    const int kkA = tid & 15, mloc0 = tid >> 4;
    const int nloc = tid & 63, kk0 = tid >> 6;
    for (int k0 = 0; k0 < K; k0 += 16) {
        const int kA = k0 + kkA;
#pragma unroll
        for (int i = 0; i < 4; ++i) {
            int mloc = mloc0 + i * 16, m = m0 + mloc;
            As[kkA][mloc] = (m < M && kA < K) ? A[m * lda + kA] : 0.f;
        }
#pragma unroll
        for (int i = 0; i < 4; ++i) {
            int kk = kk0 + i * 4, k = k0 + kk, n = n0 + nloc;
            Ws[kk][nloc] = (k < K && n < N) ? W[k * N + n] : 0.f;
        }
        __syncthreads();
#pragma unroll
        for (int kk = 0; kk < 16; ++kk) {
            float a[4], b[4];
#pragma unroll
            for (int i = 0; i < 4; ++i) a[i] = As[kk][ty * 4 + i];
#pragma unroll
            for (int j = 0; j < 4; ++j) b[j] = Ws[kk][tx * 4 + j];
#pragma unroll
            for (int i = 0; i < 4; ++i)
#pragma unroll
                for (int j = 0; j < 4; ++j) acc[i][j] = fmaf(a[i], b[j], acc[i][j]);
        }
        __syncthreads();
    }
#pragma unroll
    for (int i = 0; i < 4; ++i) {
        int m = m0 + ty * 4 + i;
        if (m >= M) continue;
#pragma unroll
        for (int j = 0; j < 4; ++j) {
            int n = n0 + tx * 4 + j;
            if (n >= N) continue;
            float v = acc[i][j] + bias[n];
            if (act == 1) v = gelu_f(v);
            C[m * ldc + n] = v;
        }
    }
}

// ---------------- merged attn prep: bias table + V transpose ----------------
// blocks [0, 27000): BIAS[NH][900][960] bf16; blocks [27000, 32760): VT[b][h][48][960]
__global__ __launch_bounds__(256) void attprep_kernel(const float* __restrict__ de,
                                                      const float* __restrict__ dre,
                                                      const int* __restrict__ dist,
                                                      const int* __restrict__ dirn,
                                                      const __hip_bfloat16* __restrict__ QKV,
                                                      __hip_bfloat16* __restrict__ biasOut,
                                                      __hip_bfloat16* __restrict__ VT) {
    const int gid = blockIdx.x;
    const int tid = threadIdx.x;
    if (gid < 27000) {
        const int h = gid / 3375;
        int idx = (gid % 3375) * 256 + tid;        // < 864000
        int sq = idx / 960, t = idx - sq * 960;
        float v = 0.f;
        if (t < SS) v = de[dist[sq * SS + t] * NHH + h] + dre[dirn[sq * SS + t] * NHH + h];
        biasOut[((size_t)h * SS + sq) * 960 + t] = __float2bfloat16(v);
    } else {
        int idx = (gid - 27000) * 256 + tid;       // < 1,474,560
        int t = idx % 960;
        int d = (idx / 960) % 48;
        int h = (idx / (960 * 48)) % NHH;
        int b = idx / (960 * 48 * NHH);
        __hip_bfloat16 v = __float2bfloat16(0.f);
        if (t < SS && d < DKK) v = QKV[((size_t)b * SS + t) * 960 + 640 + h * DKK + d];
        VT[idx] = v;
    }
}

// ---------------- MFMA flash attention (Q/K from packed QKV, stride 960) ----------------
#define LQ 56
#define LK 56
#define LV 72
#define LP 72
__global__ __launch_bounds__(256) void mattn_kernel(
    const __hip_bfloat16* __restrict__ Qg, const __hip_bfloat16* __restrict__ Kg,
    const __hip_bfloat16* __restrict__ VTg, const __hip_bfloat16* __restrict__ BIASg,
    __hip_bfloat16* __restrict__ AO) {
    const int qt = blockIdx.x, h = blockIdx.y, b = blockIdx.z;
    const int tid = threadIdx.x, lane = tid & 63, w = tid >> 6;
    const int lhi = lane >> 4, llo = lane & 15;
    __shared__ short Qs[64 * LQ];
    __shared__ short Ks[64 * LK];
    __shared__ short Vs[48 * LV];
    __shared__ short Ps[4][16 * LP];
    short* Ps_w = Ps[w];
    const int q0 = qt * 64;
    const short4v z4 = {0, 0, 0, 0};
    const f32x4 fz = {0.f, 0.f, 0.f, 0.f};
    const float scale = 0.15811388300841898f;  // 1/sqrt(40)

    for (int task = tid; task < 64 * 14; task += 256) {
        int r = task / 14, d0 = (task - r * 14) * 4;
        int q = q0 + r;
        short4v v = z4;
        if (q < SS && d0 < DKK)
            v = *(const short4v*)((const short*)Qg + ((size_t)b * SS + q) * 960 + h * DKK + d0);
        *(short4v*)(Qs + r * LQ + d0) = v;
    }
    __syncthreads();
    short8 qa[2];
#pragma unroll
    for (int ks = 0; ks < 2; ++ks)
        qa[ks] = *(const short8*)(Qs + (w * 16 + llo) * LQ + ks * 32 + lhi * 8);

    float mrow[4] = {-1e30f, -1e30f, -1e30f, -1e30f};
    float lrow[4] = {0.f, 0.f, 0.f, 0.f};
    f32x4 o[3] = {fz, fz, fz};
    const int qrow = q0 + w * 16 + lhi * 4;

    for (int t = 0; t < 15; ++t) {
        const int kv0 = t * 64;
        for (int task = tid; task < 64 * 14; task += 256) {
            int r = task / 14, d0 = (task - r * 14) * 4;
            int kv = kv0 + r;
            short4v v = z4;
            if (kv < SS && d0 < DKK)
                v = *(const short4v*)((const short*)Kg + ((size_t)b * SS + kv) * 960 + h * DKK + d0);
            *(short4v*)(Ks + r * LK + d0) = v;
        }
        for (int task = tid; task < 48 * 16; task += 256) {
            int r = task / 16, c4 = (task - r * 16) * 4;
            short4v v = *(const short4v*)((const short*)VTg +
                         (((size_t)b * NHH + h) * 48 + r) * 960 + kv0 + c4);
            *(short4v*)(Vs + r * LV + c4) = v;
        }
        __syncthreads();
        f32x4 s[4] = {fz, fz, fz, fz};
#pragma unroll
        for (int ks = 0; ks < 2; ++ks) {
#pragma unroll
            for (int ni = 0; ni < 4; ++ni) {
                short8 kb = *(const short8*)(Ks + (ni * 16 + llo) * LK + ks * 32 + lhi * 8);
                s[ni] = __builtin_amdgcn_mfma_f32_16x16x32_bf16(qa[ks], kb, s[ni], 0, 0, 0);
            }
        }
#pragma unroll
        for (int ni = 0; ni < 4; ++ni) {
            int col = kv0 + ni * 16 + llo;
#pragma unroll
            for (int r = 0; r < 4; ++r) {
                int qc = qrow + r; if (qc > SS - 1) qc = SS - 1;
                float v = s[ni][r] * scale +
                          __bfloat162float(BIASg[((size_t)h * SS + qc) * 960 + col]);
                s[ni][r] = (col < SS) ? v : -1e30f;
            }
        }
        float rmax[4], psum[4], corr[4];
#pragma unroll
        for (int r = 0; r < 4; ++r)
            rmax[r] = fmaxf(fmaxf(s[0][r], s[1][r]), fmaxf(s[2][r], s[3][r]));
#pragma unroll
        for (int off = 1; off < 16; off <<= 1)
#pragma unroll
            for (int r = 0; r < 4; ++r)
                rmax[r] = fmaxf(rmax[r], __shfl_xor(rmax[r], off));
#pragma unroll
        for (int r = 0; r < 4; ++r) {
            float mnew = fmaxf(mrow[r], rmax[r]);
            corr[r] = expf(mrow[r] - mnew);
            mrow[r] = mnew;
            float ps = 0.f;
#pragma unroll
            for (int ni = 0; ni < 4; ++ni) {
                float p = expf(s[ni][r] - mnew);
                s[ni][r] = p;
                ps += p;
            }
            psum[r] = ps;
        }
#pragma unroll
        for (int off = 1; off < 16; off <<= 1)
#pragma unroll
            for (int r = 0; r < 4; ++r) psum[r] += __shfl_xor(psum[r], off);
#pragma unroll
        for (int r = 0; r < 4; ++r) lrow[r] = lrow[r] * corr[r] + psum[r];
#pragma unroll
        for (int nj = 0; nj < 3; ++nj)
#pragma unroll
            for (int r = 0; r < 4; ++r) o[nj][r] *= corr[r];
#pragma unroll
        for (int ni = 0; ni < 4; ++ni)
#pragma unroll
            for (int r = 0; r < 4; ++r)
                ((__hip_bfloat16*)Ps_w)[(lhi * 4 + r) * LP + ni * 16 + llo] =
                    __float2bfloat16(s[ni][r]);
#pragma unroll
        for (int ks = 0; ks < 2; ++ks) {
            short8 pa = *(const short8*)(Ps_w + llo * LP + ks * 32 + lhi * 8);
#pragma unroll
            for (int nj = 0; nj < 3; ++nj) {
                short8 vb = *(const short8*)(Vs + (nj * 16 + llo) * LV + ks * 32 + lhi * 8);
                o[nj] = __builtin_amdgcn_mfma_f32_16x16x32_bf16(pa, vb, o[nj], 0, 0, 0);
            }
        }
        __syncthreads();
    }
#pragma unroll
    for (int nj = 0; nj < 3; ++nj) {
        int d = nj * 16 + llo;
        if (d >= DKK) continue;
#pragma unroll
        for (int r = 0; r < 4; ++r) {
            int q = qrow + r;
            if (q < SS)
                AO[((size_t)b * SS + q) * DD + h * DKK + d] = __float2bfloat16(o[nj][r] / lrow[r]);
        }
    }
}

// ---------------- row LayerNorm (proven LDS-tree version) ----------------
__global__ __launch_bounds__(320) void ln_kernel(const float* __restrict__ a,
                                                 const float* __restrict__ add,
                                                 const float* __restrict__ g,
                                                 const float* __restrict__ bta,
                                                 float* __restrict__ out,
                                                 __hip_bfloat16* __restrict__ outb) {
    const int row = blockIdx.x, i = threadIdx.x;
    __shared__ float red[320];
    __shared__ float s_m, s_v;
    float v = a[row * DD + i];
    if (add) v += add[row * DD + i];
    red[i] = v;
    __syncthreads();
    if (i < 64) red[i] += red[i + 256];
    __syncthreads();
    for (int s = 128; s > 0; s >>= 1) {
        if (i < s) red[i] += red[i + s];
        __syncthreads();
    }
    if (i == 0) s_m = red[0] * (1.0f / DD);
    __syncthreads();
    const float d = v - s_m;
    red[i] = d * d;
    __syncthreads();
    if (i < 64) red[i] += red[i + 256];
    __syncthreads();
    for (int s = 128; s > 0; s >>= 1) {
        if (i < s) red[i] += red[i + s];
        __syncthreads();
    }
    if (i == 0) s_v = red[0] * (1.0f / DD);
    __syncthreads();
    float o = d * rsqrtf(s_v + 1e-5f) * g[i] + bta[i];
    out[row * DD + i] = o;
    outb[row * DD + i] = __float2bfloat16(o);
}

// ---------------- global mean over S ----------------
__global__ __launch_bounds__(256) void mean_kernel(const float* __restrict__ xs, float* __restrict__ g) {
    const int b = blockIdx.y, d = blockIdx.x * 64 + (threadIdx.x & 63);
    const int rg = threadIdx.x >> 6;
    float s = 0.f;
    for (int t = rg; t < SS; t += 4) s += xs[((size_t)b * SS + t) * DD + d];
    __shared__ float red[256];
    red[threadIdx.x] = s;
    __syncthreads();
    if (threadIdx.x < 128) red[threadIdx.x] += red[threadIdx.x + 128];
    __syncthreads();
    if (threadIdx.x < 64) g[b * DD + d] = (red[threadIdx.x] + red[threadIdx.x + 64]) * (1.0f / SS);
}

// ---------------- transform params ----------------
__global__ __launch_bounds__(64) void tp_kernel(const float* __restrict__ g,
                                                const float* __restrict__ wrot, const float* __restrict__ brot,
                                                const float* __restrict__ wrefl, const float* __restrict__ brefl,
                                                const float* __restrict__ wtr, const float* __restrict__ btr,
                                                const float* __restrict__ wsc, const float* __restrict__ bsc,
                                                float* __restrict__ tp) {
    const int b = blockIdx.x, tid = threadIdx.x;
    __shared__ float gs[DD];
    __shared__ float raw[17];
    for (int j = tid; j < DD; j += 64) gs[j] = g[b * DD + j];
    __syncthreads();
    if (tid < 17) {
        float s;
        if (tid < 4) {
            s = brot[tid];
            for (int d = 0; d < DD; ++d) s = fmaf(gs[d], wrot[d * 4 + tid], s);
        } else if (tid < 12) {
            int j = tid - 4;
            s = brefl[j];
            for (int d = 0; d < DD; ++d) s = fmaf(gs[d], wrefl[d * 8 + j], s);
        } else if (tid < 14) {
            int j = tid - 12;
            s = btr[j];
            for (int d = 0; d < DD; ++d) s = fmaf(gs[d], wtr[d * 2 + j], s);
        } else {
            int j = tid - 14;
            s = bsc[j];
            for (int d = 0; d < DD; ++d) s = fmaf(gs[d], wsc[d * 3 + j], s);
        }
        raw[tid] = s;
    }
    __syncthreads();
    if (tid == 0) {
        float mx = -1e30f;
        for (int j = 0; j < 4; ++j) mx = fmaxf(mx, raw[j]);
        float sm = 0.f, e[4];
        for (int j = 0; j < 4; ++j) { e[j] = expf(raw[j] - mx); sm += e[j]; }
        for (int j = 0; j < 4; ++j) tp[b * 17 + j] = e[j] / sm;
    } else if (tid == 1) {
        float mx = -1e30f;
        for (int j = 4; j < 12; ++j) mx = fmaxf(mx, raw[j]);
        float sm = 0.f, e[8];
        for (int j = 0; j < 8; ++j) { e[j] = expf(raw[4 + j] - mx); sm += e[j]; }
        for (int j = 0; j < 8; ++j) tp[b * 17 + 4 + j] = e[j] / sm;
    } else if (tid == 2) {
        tp[b * 17 + 12] = tanhf(raw[12]);
        tp[b * 17 + 13] = tanhf(raw[13]);
    } else if (tid == 3) {
        float mx = -1e30f;
        for (int j = 14; j < 17; ++j) mx = fmaxf(mx, raw[j]);
        float sm = 0.f, e[3];
        for (int j = 0; j < 3; ++j) { e[j] = expf(raw[14 + j] - mx); sm += e[j]; }
        for (int j = 0; j < 3; ++j) tp[b * 17 + 14 + j] = e[j] / sm;
    }
}

// ---------------- concat xs(bf16) + tp -> TIbf [3600, 384] ----------------
__global__ void concat_kernel(const __hip_bfloat16* __restrict__ xb, const float* __restrict__ tp,
                              __hip_bfloat16* __restrict__ ti) {
    int idx = blockIdx.x * 256 + threadIdx.x;
    if (idx >= BS * 384) return;
    int m = idx / 384, j = idx % 384;
    __hip_bfloat16 v;
    if (j < DD) v = xb[m * DD + j];
    else if (j < 337) v = __float2bfloat16(tp[(m / SS) * 17 + (j - DD)]);
    else v = __float2bfloat16(0.f);
    ti[idx] = v;
}

static inline void launch_mgemm(hipStream_t s, const __hip_bfloat16* A, int lda,
                                const __hip_bfloat16* Wt, int ldw, const float* bias,
                                const float* biasB, const float* biasC,
                                const float* res, int ldr, float alpha, float* Cf,
                                __hip_bfloat16* Cb, int ldc, int M, int N, int K, int act) {
    dim3 g((N + 63) / 64, (M + 127) / 128);
    mgemm_kernel<<<g, 256, 0, s>>>(A, lda, Wt, ldw, bias, biasB, biasC, res, ldr, alpha, Cf, Cb, ldc, M, N, K, act);
}

extern "C" void kernel_launch(void* const* d_in, const int* in_sizes, int n_in,
                              void* d_out, int out_size, void* d_ws, size_t ws_size,
                              hipStream_t stream) {
    (void)in_sizes; (void)n_in; (void)out_size; (void)ws_size;
    const int* in_grid = (const int*)d_in[0];
    const float* pe = (const float*)d_in[1];
    const float* iew = (const float*)d_in[2];
    const float* ieb = (const float*)d_in[3];
    const float* wq = (const float*)d_in[4], *bq = (const float*)d_in[5];
    const float* wk = (const float*)d_in[6], *bk = (const float*)d_in[7];
    const float* wv = (const float*)d_in[8], *bv = (const float*)d_in[9];
    const float* wo = (const float*)d_in[10], *bo = (const float*)d_in[11];
    const float* lnag = (const float*)d_in[12], *lnab = (const float*)d_in[13];
    const float* dist_emb = (const float*)d_in[14], *dir_emb = (const float*)d_in[15];
    const float* wrot = (const float*)d_in[16], *brot = (const float*)d_in[17];
    const float* wrefl = (const float*)d_in[18], *brefl = (const float*)d_in[19];
    const float* wtr = (const float*)d_in[20], *btr = (const float*)d_in[21];
    const float* wsc = (const float*)d_in[22], *bsc = (const float*)d_in[23];
    const float* tnw1 = (const float*)d_in[24], *tnb1 = (const float*)d_in[25];
    const float* tnw2 = (const float*)d_in[26], *tnb2 = (const float*)d_in[27];
    const float* tnw3 = (const float*)d_in[28], *tnb3 = (const float*)d_in[29];
    const float* ffw1 = (const float*)d_in[30], *ffb1 = (const float*)d_in[31];
    const float* ffw2 = (const float*)d_in[32], *ffb2 = (const float*)d_in[33];
    const float* ln2g = (const float*)d_in[34], *ln2b = (const float*)d_in[35];
    const float* ck1 = (const float*)d_in[36], *cb1 = (const float*)d_in[37];
    const float* ck3 = (const float*)d_in[38], *cb3 = (const float*)d_in[39];
    const float* ck5 = (const float*)d_in[40], *cb5 = (const float*)d_in[41];
    const float* ck7 = (const float*)d_in[42], *cb7 = (const float*)d_in[43];
    const float* fusw = (const float*)d_in[44], *fusb = (const float*)d_in[45];
    const float* opw1 = (const float*)d_in[46], *opb1 = (const float*)d_in[47];
    const float* opw2 = (const float*)d_in[48], *opb2 = (const float*)d_in[49];
    const float* opw3 = (const float*)d_in[50], *opb3 = (const float*)d_in[51];
    const int* dist_idx = (const int*)d_in[52];
    const int* dir_idx = (const int*)d_in[53];
    float* out = (float*)d_out;

    // ---- workspace arena (byte offsets) ----
    char* base = (char*)d_ws;
    typedef __hip_bfloat16 bf;
    bf* WQKVT = (bf*)(base + 0);          // [4][960][320] = 2,457,600 B (replaces WQT/WKT/WVT)
    bf* WOT = (bf*)(base + 2457600);
    bf* TN1T = (bf*)(base + 3276800);
    bf* TN2T = (bf*)(base + 5242880);
    bf* TN3T = (bf*)(base + 6881280);
    bf* FF1T = (bf*)(base + 7700480);
    bf* FF2T = (bf*)(base + 10977280);
    bf* CK1T = (bf*)(base + 14254080);
    bf* CK3T = (bf*)(base + 14458880);
    bf* CK5T = (bf*)(base + 16302080);
    bf* CK7T = (bf*)(base + 21422080);
    bf* FUST = (bf*)(base + 31457280);
    bf* OP1T = (bf*)(base + 32276480);
    float* XS = (float*)(base + 32378880);
    bf* XSbf = (bf*)(base + 36986880);
    bf* QKVbf = (bf*)(base + 39290880);   // [3600][960] = 6,912,000 B, ends 46,202,880
    bf* VT = (bf*)(base + 46202880);      // ends 49,152,000
    float* R2 = (float*)(base + 53114880);
    float* Gm = (float*)(base + 57722880);
    float* TP = (float*)(base + 57728000);
    // conv partials: up to [4][3600][320] fp32 = 18,432,000 B in dead QKV..R2 region
    float* CPART = (float*)(base + 39290880);
    char* BIG = base + 57728512;
    bf* AObf = (bf*)(BIG + 0);
    bf* BIAS = (bf*)(BIG + 2764800);
    bf* TIbf = (bf*)(BIG + 0);
    bf* T1bf = (bf*)(BIG + 2764800);
    bf* T2bf = (bf*)(BIG + 7372800);
    bf* F1bf = (bf*)(BIG + 0);
    bf* PADbf = (bf*)(BIG + 0);
    bf* FEATSbf = (bf*)(BIG + 3317760);
    float* H1 = (float*)(BIG + 0);
    float* H2 = (float*)(BIG + 2304000);
    bf* R2bf = XSbf;

    dim3 cb(32, 8);
    qkvconvt_kernel<<<dim3(10, 10, 12), cb, 0, stream>>>(wq, wk, wv, WQKVT);
    convt_kernel<<<dim3(10, 10, 4), cb, 0, stream>>>(wo, WOT, 320, 320, 320, 102400, 102400);
    convt_kernel<<<dim3(12, 20, 4), cb, 0, stream>>>(tnw1, TN1T, 337, 640, 384, 215680, 245760);
    convt_kernel<<<dim3(20, 10, 4), cb, 0, stream>>>(tnw2, TN2T, 640, 320, 640, 204800, 204800);
    convt_kernel<<<dim3(10, 10, 4), cb, 0, stream>>>(tnw3, TN3T, 320, 320, 320, 102400, 102400);
    convt_kernel<<<dim3(10, 40, 4), cb, 0, stream>>>(ffw1, FF1T, 320, 1280, 320, 409600, 409600);
    convt_kernel<<<dim3(40, 10, 4), cb, 0, stream>>>(ffw2, FF2T, 1280, 320, 1280, 409600, 409600);
    convt_kernel<<<dim3(10, 10, 1), cb, 0, stream>>>(ck1, CK1T, 320, 320, 320, 0, 0);
    convt_kernel<<<dim3(90, 10, 1), cb, 0, stream>>>(ck3, CK3T, 2880, 320, 2880, 0, 0);
    convt_kernel<<<dim3(250, 10, 1), cb, 0, stream>>>(ck5, CK5T, 8000, 320, 8000, 0, 0);
    convt_kernel<<<dim3(490, 10, 1), cb, 0, stream>>>(ck7, CK7T, 15680, 320, 15680, 0, 0);
    convt_kernel<<<dim3(40, 10, 1), cb, 0, stream>>>(fusw, FUST, 1280, 320, 1280, 0, 0);
    convt_kernel<<<dim3(10, 5, 1), cb, 0, stream>>>(opw1, OP1T, 320, 160, 320, 0, 0);

    embed_kernel<<<4500, 256, 0, stream>>>(in_grid, pe, iew, ieb, XS, XSbf);

    for (int l = 0; l < LL; ++l) {
        const int wO = l * DD * DD, bO = l * DD;
        // fused QKV projection: N=960, grid (15, 29) = 435 blocks
        launch_mgemm(stream, XSbf, DD, WQKVT + l * 307200, 320, bq + bO, bk + bO, bv + bO,
                     nullptr, 0, 1.f, nullptr, QKVbf, 960, BS, 960, 320, 0);
        attprep_kernel<<<32760, 256, 0, stream>>>(dist_emb + l * 60 * NHH, dir_emb + l * 8 * NHH,
                                                  dist_idx, dir_idx, QKVbf, BIAS, VT);
        mattn_kernel<<<dim3(15, NHH, BB), 256, 0, stream>>>(QKVbf, QKVbf + 320, VT, BIAS, AObf);
        launch_mgemm(stream, AObf, DD, WOT + wO, DD, bo + bO, nullptr, nullptr, XS, DD, 1.f,
                     R2, nullptr, DD, BS, DD, DD, 0);
        ln_kernel<<<BS, 320, 0, stream>>>(R2, nullptr, lnag + bO, lnab + bO, XS, XSbf);
        mean_kernel<<<dim3(5, BB), 256, 0, stream>>>(XS, Gm);
        tp_kernel<<<BB, 64, 0, stream>>>(Gm, wrot + l * 1280, brot + l * 4,
                                         wrefl + l * 2560, brefl + l * 8,
                                         wtr + l * 640, btr + l * 2,
                                         wsc + l * 960, bsc + l * 3, TP);
        concat_kernel<<<(BS * 384 + 255) / 256, 256, 0, stream>>>(XSbf, TP, TIbf);
        launch_mgemm(stream, TIbf, 384, TN1T + l * 245760, 384, tnb1 + l * 640, nullptr, nullptr,
                     nullptr, 0, 1.f, nullptr, T1bf, 640, BS, 640, 384, 1);
        launch_mgemm(stream, T1bf, 640, TN2T + l * 204800, 640, tnb2 + bO, nullptr, nullptr,
                     nullptr, 0, 1.f, nullptr, T2bf, DD, BS, DD, 640, 1);
        launch_mgemm(stream, T2bf, DD, TN3T + wO, DD, tnb3 + bO, nullptr, nullptr, XS, DD, 0.3f,
                     XS, XSbf, DD, BS, DD, DD, 0);
        launch_mgemm(stream, XSbf, DD, FF1T + l * 409600, DD, ffb1 + l * FFD, nullptr, nullptr,
                     nullptr, 0, 1.f, nullptr, F1bf, FFD, BS, FFD, DD, 1);
        launch_mgemm(stream, F1bf, FFD, FF2T + l * 409600, FFD, ffb2 + bO, nullptr, nullptr,
                     nullptr, 0, 1.f, R2, nullptr, DD, BS, DD, FFD, 0);
        ln_kernel<<<BS, 320, 0, stream>>>(R2, XS, ln2g + bO, ln2b + bO, XS, XSbf);
    }

    // ---- multiscale convs: kh-split (z) fp32 partials + reduce ----
    pad_kernel<<<(BB * 36 * 36 * DD + 255) / 256, 256, 0, stream>>>(XSbf, PADbf);
    launch_mgemm(stream, XSbf, DD, CK1T, DD, cb1, nullptr, nullptr, nullptr, 0, 1.f,
                 nullptr, FEATSbf + 0, 1280, BS, DD, DD, 2);
    const int RED = (BS * DD / 4 + 255) / 256;
    mconv_kernel<3><<<dim3(5, 29, 3), 256, 0, stream>>>(PADbf, CK3T, CPART, 1);
    creduce_kernel<<<RED, 256, 0, stream>>>(CPART, 3, cb3, FEATSbf + 320, 1280);
    mconv_kernel<5><<<dim3(5, 29, 3), 256, 0, stream>>>(PADbf, CK5T, CPART, 2);
    creduce_kernel<<<RED, 256, 0, stream>>>(CPART, 3, cb5, FEATSbf + 640, 1280);
    mconv_kernel<7><<<dim3(5, 29, 4), 256, 0, stream>>>(PADbf, CK7T, CPART, 2);
    creduce_kernel<<<RED, 256, 0, stream>>>(CPART, 4, cb7, FEATSbf + 960, 1280);
    launch_mgemm(stream, FEATSbf, 1280, FUST, 1280, fusb, nullptr, nullptr, nullptr, 0, 1.f,
                 nullptr, R2bf, DD, BS, DD, 1280, 0);
    // ---- output head ----
    launch_mgemm(stream, R2bf, DD, OP1T, DD, opb1, nullptr, nullptr, nullptr, 0, 1.f,
                 H1, nullptr, 160, BS, 160, DD, 1);
    gemm_kernel<<<dim3(2, 57), 256, 0, stream>>>(H1, 160, opw2, opb2, H2, 80, BS, 80, 160, 1);
    gemm_kernel<<<dim3(1, 57), 256, 0, stream>>>(H2, 80, opw3, opb3, out, 10, BS, 10, 80, 0);
}

// Round 8
// 1742.570 us; speedup vs baseline: 6.3398x; 1.2112x over previous
//
#include <hip/hip_runtime.h>
#include <hip/hip_bf16.h>

#define BB 4
#define GG_ 30
#define DD 320
#define LL 4
#define NHH 8
#define DKK 40
#define SS 900
#define BS 3600
#define FFD 1280
#define LDK 72   // BK(64) + 8 pad, in bf16 elems -> 144B row stride, 16B aligned

typedef __attribute__((ext_vector_type(8))) short short8;
typedef __attribute__((ext_vector_type(4))) short short4v;
typedef __attribute__((ext_vector_type(4))) float f32x4;

__device__ __forceinline__ float gelu_f(float x) {
    return 0.5f * x * (1.0f + erff(x * 0.70710678118654752f));
}

__device__ __forceinline__ float bfbits2f(short b) {
    return __uint_as_float(((unsigned)(unsigned short)b) << 16);
}

// ---------------- shared convt tile body ----------------
__device__ __forceinline__ void convt_tile(const float* __restrict__ s,
                                           __hip_bfloat16* __restrict__ d,
                                           int K, int N, int Kpad, int kb, int nb) {
    __shared__ float t[32][33];
    const int tx = threadIdx.x, ty = threadIdx.y;   // (32, 8)
#pragma unroll
    for (int i = 0; i < 4; ++i) {
        int k = kb + ty + i * 8, n = nb + tx;
        t[ty + i * 8][tx] = (k < K && n < N) ? s[(size_t)k * N + n] : 0.f;
    }
    __syncthreads();
#pragma unroll
    for (int i = 0; i < 4; ++i) {
        int n = nb + ty + i * 8, k = kb + tx;
        if (n < N && k < Kpad) d[(size_t)n * Kpad + k] = __float2bfloat16(t[tx][ty + i * 8]);
    }
}

// ---------------- ALL weight transposes in one launch (14610 blocks) ----------------
__global__ __launch_bounds__(256) void allconvt_kernel(
    const float* wo, const float* tnw1, const float* tnw2, const float* tnw3,
    const float* ffw1, const float* ffw2, const float* ck1, const float* ck3,
    const float* ck5, const float* ck7, const float* fusw, const float* opw1,
    __hip_bfloat16* WOT, __hip_bfloat16* TN1T, __hip_bfloat16* TN2T, __hip_bfloat16* TN3T,
    __hip_bfloat16* FF1T, __hip_bfloat16* FF2T, __hip_bfloat16* CK1T, __hip_bfloat16* CK3T,
    __hip_bfloat16* CK5T, __hip_bfloat16* CK7T, __hip_bfloat16* FUST, __hip_bfloat16* OP1T) {
    const int bid = blockIdx.x;
    const float* s; __hip_bfloat16* d;
    int K, N, Kpad, gx, per, local, sS, dS;
    if (bid < 400)        { local = bid;         s = wo;   d = WOT;  K = 320;  N = 320;  Kpad = 320;  sS = 102400; dS = 102400; gx = 10;  per = 100; }
    else if (bid < 1360)  { local = bid - 400;   s = tnw1; d = TN1T; K = 337;  N = 640;  Kpad = 384;  sS = 215680; dS = 245760; gx = 12;  per = 240; }
    else if (bid < 2160)  { local = bid - 1360;  s = tnw2; d = TN2T; K = 640;  N = 320;  Kpad = 640;  sS = 204800; dS = 204800; gx = 20;  per = 200; }
    else if (bid < 2560)  { local = bid - 2160;  s = tnw3; d = TN3T; K = 320;  N = 320;  Kpad = 320;  sS = 102400; dS = 102400; gx = 10;  per = 100; }
    else if (bid < 4160)  { local = bid - 2560;  s = ffw1; d = FF1T; K = 320;  N = 1280; Kpad = 320;  sS = 409600; dS = 409600; gx = 10;  per = 400; }
    else if (bid < 5760)  { local = bid - 4160;  s = ffw2; d = FF2T; K = 1280; N = 320;  Kpad = 1280; sS = 409600; dS = 409600; gx = 40;  per = 400; }
    else if (bid < 5860)  { local = bid - 5760;  s = ck1;  d = CK1T; K = 320;  N = 320;  Kpad = 320;  sS = 0; dS = 0; gx = 10;  per = 100; }
    else if (bid < 6760)  { local = bid - 5860;  s = ck3;  d = CK3T; K = 2880; N = 320;  Kpad = 2880; sS = 0; dS = 0; gx = 90;  per = 900; }
    else if (bid < 9260)  { local = bid - 6760;  s = ck5;  d = CK5T; K = 8000; N = 320;  Kpad = 8000; sS = 0; dS = 0; gx = 250; per = 2500; }
    else if (bid < 14160) { local = bid - 9260;  s = ck7;  d = CK7T; K = 15680; N = 320; Kpad = 15680; sS = 0; dS = 0; gx = 490; per = 4900; }
    else if (bid < 14560) { local = bid - 14160; s = fusw; d = FUST; K = 1280; N = 320;  Kpad = 1280; sS = 0; dS = 0; gx = 40;  per = 400; }
    else                  { local = bid - 14560; s = opw1; d = OP1T; K = 320;  N = 160;  Kpad = 320;  sS = 0; dS = 0; gx = 10;  per = 50; }
    const int mat = local / per, rem = local - mat * per;
    const int kb = (rem % gx) * 32, nb = (rem / gx) * 32;
    convt_tile(s + (size_t)mat * sS, d + (size_t)mat * dS, K, N, Kpad, kb, nb);
}

// ---------------- packed QKV weight convert: [L][960][320] bf16 ----------------
__global__ __launch_bounds__(256) void qkvconvt_kernel(const float* __restrict__ wq,
                                                       const float* __restrict__ wk,
                                                       const float* __restrict__ wv,
                                                       __hip_bfloat16* __restrict__ dst) {
    __shared__ float t[32][33];
    const int z = blockIdx.z, l = z / 3, wsel = z % 3;
    const float* s = (wsel == 0 ? wq : wsel == 1 ? wk : wv) + (size_t)l * 102400;
    __hip_bfloat16* d = dst + (size_t)l * 307200 + wsel * 102400;
    const int kb = blockIdx.x * 32, nb = blockIdx.y * 32;
    const int tx = threadIdx.x, ty = threadIdx.y;   // (32, 8)
#pragma unroll
    for (int i = 0; i < 4; ++i) {
        int k = kb + ty + i * 8, n = nb + tx;
        t[ty + i * 8][tx] = s[(size_t)k * 320 + n];
    }
    __syncthreads();
#pragma unroll
    for (int i = 0; i < 4; ++i) {
        int n = nb + ty + i * 8, k = kb + tx;
        d[(size_t)n * 320 + k] = __float2bfloat16(t[tx][ty + i * 8]);
    }
}

// ---------------- embed ----------------
__global__ void embed_kernel(const int* __restrict__ grid, const float* __restrict__ pe,
                             const float* __restrict__ ew, const float* __restrict__ eb,
                             float* __restrict__ x, __hip_bfloat16* __restrict__ xb) {
    int idx = blockIdx.x * 256 + threadIdx.x;   // < 1,152,000
    int m = idx / DD, d = idx % DD;
    int gv = grid[m];
    float v = ew[gv * DD + d] + eb[d] + pe[(m % SS) * DD + d];
    x[idx] = v;
    xb[idx] = __float2bfloat16(v);
}

// ---------------- MFMA bf16 GEMM (proven 128x64 body; 3-way bias; optional K-split z) ----------------
__global__ __launch_bounds__(256) void mgemm_kernel(
    const __hip_bfloat16* __restrict__ A, int lda,
    const __hip_bfloat16* __restrict__ Wt, int ldw,
    const float* __restrict__ bias, const float* __restrict__ biasB, const float* __restrict__ biasC,
    const float* __restrict__ res, int ldr,
    float alpha, float* __restrict__ Cf, float* __restrict__ Cf2,
    __hip_bfloat16* __restrict__ Cb, int ldc,
    int M, int N, int K, int act) {
    __shared__ short As[128 * LDK];
    __shared__ short Bs[64 * LDK];
    const int tid = threadIdx.x;
    const int m0 = blockIdx.y * 128, n0 = blockIdx.x * 64;
    const int kb0 = blockIdx.z * K;                 // K-split offset (z=0 for normal calls)
    float* __restrict__ CfO = (blockIdx.z == 0) ? Cf : Cf2;
    const int lane = tid & 63;
    const int w = tid >> 6, wm = w >> 1, wn = w & 1;
    const int rbase = tid >> 3, q8 = (tid & 7) * 8;
    f32x4 acc[4][2];
    const f32x4 fz = {0.f, 0.f, 0.f, 0.f};
#pragma unroll
    for (int mi = 0; mi < 4; ++mi)
#pragma unroll
        for (int ni = 0; ni < 2; ++ni) acc[mi][ni] = fz;
    const short8 zz = {0, 0, 0, 0, 0, 0, 0, 0};
    for (int k0 = 0; k0 < K; k0 += 64) {
#pragma unroll
        for (int c = 0; c < 4; ++c) {
            int r = c * 32 + rbase, m = m0 + r;
            short8 v = zz;
            if (m < M) v = *(const short8*)((const short*)A + (size_t)m * lda + kb0 + k0 + q8);
            *(short8*)(As + r * LDK + q8) = v;
        }
#pragma unroll
        for (int c = 0; c < 2; ++c) {
            int r = c * 32 + rbase, n = n0 + r;
            short8 v = zz;
            if (n < N) v = *(const short8*)((const short*)Wt + (size_t)n * ldw + kb0 + k0 + q8);
            *(short8*)(Bs + r * LDK + q8) = v;
        }
        __syncthreads();
#pragma unroll
        for (int ks = 0; ks < 64; ks += 32) {
            const int kb = ks + (lane >> 4) * 8;
            short8 af[4], bf[2];
#pragma unroll
            for (int mi = 0; mi < 4; ++mi)
                af[mi] = *(const short8*)(As + (wm * 64 + mi * 16 + (lane & 15)) * LDK + kb);
#pragma unroll
            for (int ni = 0; ni < 2; ++ni)
                bf[ni] = *(const short8*)(Bs + (wn * 32 + ni * 16 + (lane & 15)) * LDK + kb);
#pragma unroll
            for (int mi = 0; mi < 4; ++mi)
#pragma unroll
                for (int ni = 0; ni < 2; ++ni)
                    acc[mi][ni] = __builtin_amdgcn_mfma_f32_16x16x32_bf16(af[mi], bf[ni], acc[mi][ni], 0, 0, 0);
        }
        __syncthreads();
    }
    const int col0 = n0 + wn * 32 + (lane & 15);
    const int rloc = (lane >> 4) * 4;
#pragma unroll
    for (int mi = 0; mi < 4; ++mi) {
#pragma unroll
        for (int ni = 0; ni < 2; ++ni) {
            int col = col0 + ni * 16;
            if (col >= N) continue;
            float bv;
            if (biasC) bv = (col < 320) ? bias[col] : (col < 640) ? biasB[col - 320] : biasC[col - 640];
            else bv = bias ? bias[col] : 0.f;
#pragma unroll
            for (int r = 0; r < 4; ++r) {
                int row = m0 + wm * 64 + mi * 16 + rloc + r;
                if (row >= M) continue;
                float v = acc[mi][ni][r] + bv;
                if (act == 1) v = gelu_f(v);
                else if (act == 2) v = fmaxf(v, 0.f);
                v *= alpha;
                if (res) v += res[(size_t)row * ldr + col];
                if (CfO) CfO[(size_t)row * ldc + col] = v;
                if (Cb) Cb[(size_t)row * ldc + col] = __float2bfloat16(v);
            }
        }
    }
}

// ---------------- MFMA conv (proven 128x64 body + kh-split, bf16 partial out) ----------------
template <int KS>
__global__ __launch_bounds__(256) void mconv_kernel(
    const __hip_bfloat16* __restrict__ P, const __hip_bfloat16* __restrict__ Wt,
    __hip_bfloat16* __restrict__ part, int kh0step) {
    const int K = KS * KS * DD;
    const int OFF = 3 - KS / 2;
    const int kh0 = blockIdx.z * kh0step;
    const int nkh = (KS - kh0 < kh0step) ? (KS - kh0) : kh0step;
    const int Ksub = nkh * KS * DD;          // multiples of 64 for KS in {3,5,7}
    const int wbase = kh0 * KS * DD;
    __hip_bfloat16* __restrict__ Cp = part + (size_t)blockIdx.z * BS * DD;
    __shared__ short As[128 * LDK];
    __shared__ short Bs[64 * LDK];
    const int tid = threadIdx.x;
    const int m0 = blockIdx.y * 128, n0 = blockIdx.x * 64;
    const int lane = tid & 63;
    const int w = tid >> 6, wm = w >> 1, wn = w & 1;
    const int rbase = tid >> 3, q8 = (tid & 7) * 8;
    f32x4 acc[4][2];
    const f32x4 fz = {0.f, 0.f, 0.f, 0.f};
#pragma unroll
    for (int mi = 0; mi < 4; ++mi)
#pragma unroll
        for (int ni = 0; ni < 2; ++ni) acc[mi][ni] = fz;
    const short8 zz = {0, 0, 0, 0, 0, 0, 0, 0};
    for (int k0 = 0; k0 < Ksub; k0 += 64) {
#pragma unroll
        for (int c = 0; c < 4; ++c) {
            int r = c * 32 + rbase, m = m0 + r;
            int k = k0 + q8;
            int ci = k % DD, t = k / DD;
            int kw = t % KS, kh = kh0 + t / KS;
            short8 v = zz;
            if (m < BS) {
                int b = m / SS, hw = m % SS, oh = hw / GG_, ow = hw % GG_;
                int ih = oh + kh + OFF, iw = ow + kw + OFF;
                v = *(const short8*)((const short*)P + (((b * 36 + ih) * 36 + iw) * DD + ci));
            }
            *(short8*)(As + r * LDK + q8) = v;
        }
#pragma unroll
        for (int c = 0; c < 2; ++c) {
            int r = c * 32 + rbase, n = n0 + r;
            short8 v = *(const short8*)((const short*)Wt + (size_t)n * K + wbase + k0 + q8);
            *(short8*)(Bs + r * LDK + q8) = v;
        }
        __syncthreads();
#pragma unroll
        for (int ks = 0; ks < 64; ks += 32) {
            const int kb = ks + (lane >> 4) * 8;
            short8 af[4], bf[2];
#pragma unroll
            for (int mi = 0; mi < 4; ++mi)
                af[mi] = *(const short8*)(As + (wm * 64 + mi * 16 + (lane & 15)) * LDK + kb);
#pragma unroll
            for (int ni = 0; ni < 2; ++ni)
                bf[ni] = *(const short8*)(Bs + (wn * 32 + ni * 16 + (lane & 15)) * LDK + kb);
#pragma unroll
            for (int mi = 0; mi < 4; ++mi)
#pragma unroll
                for (int ni = 0; ni < 2; ++ni)
                    acc[mi][ni] = __builtin_amdgcn_mfma_f32_16x16x32_bf16(af[mi], bf[ni], acc[mi][ni], 0, 0, 0);
        }
        __syncthreads();
    }
    const int col0 = n0 + wn * 32 + (lane & 15);
    const int rloc = (lane >> 4) * 4;
#pragma unroll
    for (int mi = 0; mi < 4; ++mi) {
#pragma unroll
        for (int ni = 0; ni < 2; ++ni) {
            int col = col0 + ni * 16;
#pragma unroll
            for (int r = 0; r < 4; ++r) {
                int row = m0 + wm * 64 + mi * 16 + rloc + r;
                if (row < BS) Cp[(size_t)row * DD + col] = __float2bfloat16(acc[mi][ni][r]);
            }
        }
    }
}

// ---------------- conv partial reduce: relu(sum bf16 parts + bias) -> bf16 @ldc ----------------
__global__ __launch_bounds__(256) void creduce_kernel(const __hip_bfloat16* __restrict__ part,
                                                      int nsplit, const float* __restrict__ bias,
                                                      __hip_bfloat16* __restrict__ outb, int ldc) {
    int idx = blockIdx.x * 256 + threadIdx.x;      // over BS*DD/8 groups of 8 cols
    if (idx >= BS * DD / 8) return;
    int row = idx / (DD / 8), c8 = (idx % (DD / 8)) * 8;
    float s[8] = {};
    for (int p = 0; p < nsplit; ++p) {
        short8 v = *(const short8*)((const short*)part + (size_t)p * BS * DD + (size_t)row * DD + c8);
#pragma unroll
        for (int j = 0; j < 8; ++j) s[j] += bfbits2f(v[j]);
    }
    __hip_bfloat16* o = outb + (size_t)row * ldc + c8;
#pragma unroll
    for (int j = 0; j < 8; ++j) o[j] = __float2bfloat16(fmaxf(s[j] + bias[c8 + j], 0.f));
}

// ---------------- pad bf16 image for convs ----------------
__global__ void pad_kernel(const __hip_bfloat16* __restrict__ xb, __hip_bfloat16* __restrict__ p) {
    int idx = blockIdx.x * 256 + threadIdx.x;   // 4*36*36*320
    if (idx >= BB * 36 * 36 * DD) return;
    int c = idx % DD, t = idx / DD;
    int wp = t % 36, t2 = t / 36, hp = t2 % 36, b = t2 / 36;
    __hip_bfloat16 v = __float2bfloat16(0.f);
    if (hp >= 3 && hp < 33 && wp >= 3 && wp < 33)
        v = xb[((b * SS + (hp - 3) * GG_ + (wp - 3))) * DD + c];
    p[idx] = v;
}

// ---------------- legacy fp32 GEMM (tiny op heads) ----------------
__global__ __launch_bounds__(256) void gemm_kernel(
    const float* __restrict__ A, int lda, const float* __restrict__ W,
    const float* __restrict__ bias, float* __restrict__ C, int ldc,
    int M, int N, int K, int act) {
    __shared__ float As[16][65];
    __shared__ float Ws[16][65];
    const int tid = threadIdx.x;
    const int m0 = blockIdx.y * 64, n0 = blockIdx.x * 64;
    const int tx = tid & 15, ty = tid >> 4;
    float acc[4][4] = {};
    const int kkA = tid & 15, mloc0 = tid >> 4;
    const int nloc = tid & 63, kk0 = tid >> 6;
    for (int k0 = 0; k0 < K; k0 += 16) {
        const int kA = k0 + kkA;
#pragma unroll
        for (int i = 0; i < 4; ++i) {
            int mloc = mloc0 + i * 16, m = m0 + mloc;
            As[kkA][mloc] = (m < M && kA < K) ? A[m * lda + kA] : 0.f;
        }
#pragma unroll
        for (int i = 0; i < 4; ++i) {
            int kk = kk0 + i * 4, k = k0 + kk, n = n0 + nloc;
            Ws[kk][nloc] = (k < K && n < N) ? W[k * N + n] : 0.f;
        }
        __syncthreads();
#pragma unroll
        for (int kk = 0; kk < 16; ++kk) {
            float a[4], b[4];
#pragma unroll
            for (int i = 0; i < 4; ++i) a[i] = As[kk][ty * 4 + i];
#pragma unroll
            for (int j = 0; j < 4; ++j) b[j] = Ws[kk][tx * 4 + j];
#pragma unroll
            for (int i = 0; i < 4; ++i)
#pragma unroll
                for (int j = 0; j < 4; ++j) acc[i][j] = fmaf(a[i], b[j], acc[i][j]);
        }
        __syncthreads();
    }
#pragma unroll
    for (int i = 0; i < 4; ++i) {
        int m = m0 + ty * 4 + i;
        if (m >= M) continue;
#pragma unroll
        for (int j = 0; j < 4; ++j) {
            int n = n0 + tx * 4 + j;
            if (n >= N) continue;
            float v = acc[i][j] + bias[n];
            if (act == 1) v = gelu_f(v);
            C[m * ldc + n] = v;
        }
    }
}

// ---------------- merged attn prep: bias table + V transpose ----------------
__global__ __launch_bounds__(256) void attprep_kernel(const float* __restrict__ de,
                                                      const float* __restrict__ dre,
                                                      const int* __restrict__ dist,
                                                      const int* __restrict__ dirn,
                                                      const __hip_bfloat16* __restrict__ QKV,
                                                      __hip_bfloat16* __restrict__ biasOut,
                                                      __hip_bfloat16* __restrict__ VT) {
    const int gid = blockIdx.x;
    const int tid = threadIdx.x;
    if (gid < 27000) {
        const int h = gid / 3375;
        int idx = (gid % 3375) * 256 + tid;        // < 864000
        int sq = idx / 960, t = idx - sq * 960;
        float v = 0.f;
        if (t < SS) v = de[dist[sq * SS + t] * NHH + h] + dre[dirn[sq * SS + t] * NHH + h];
        biasOut[((size_t)h * SS + sq) * 960 + t] = __float2bfloat16(v);
    } else {
        int idx = (gid - 27000) * 256 + tid;       // < 1,474,560
        int t = idx % 960;
        int d = (idx / 960) % 48;
        int h = (idx / (960 * 48)) % NHH;
        int b = idx / (960 * 48 * NHH);
        __hip_bfloat16 v = __float2bfloat16(0.f);
        if (t < SS && d < DKK) v = QKV[((size_t)b * SS + t) * 960 + 640 + h * DKK + d];
        VT[idx] = v;
    }
}

// ---------------- MFMA flash attention (Q/K from packed QKV, stride 960) ----------------
#define LQ 56
#define LK 56
#define LV 72
#define LP 72
__global__ __launch_bounds__(256) void mattn_kernel(
    const __hip_bfloat16* __restrict__ Qg, const __hip_bfloat16* __restrict__ Kg,
    const __hip_bfloat16* __restrict__ VTg, const __hip_bfloat16* __restrict__ BIASg,
    __hip_bfloat16* __restrict__ AO) {
    const int qt = blockIdx.x, h = blockIdx.y, b = blockIdx.z;
    const int tid = threadIdx.x, lane = tid & 63, w = tid >> 6;
    const int lhi = lane >> 4, llo = lane & 15;
    __shared__ short Qs[64 * LQ];
    __shared__ short Ks[64 * LK];
    __shared__ short Vs[48 * LV];
    __shared__ short Ps[4][16 * LP];
    short* Ps_w = Ps[w];
    const int q0 = qt * 64;
    const short4v z4 = {0, 0, 0, 0};
    const f32x4 fz = {0.f, 0.f, 0.f, 0.f};
    const float scale = 0.15811388300841898f;  // 1/sqrt(40)

    for (int task = tid; task < 64 * 14; task += 256) {
        int r = task / 14, d0 = (task - r * 14) * 4;
        int q = q0 + r;
        short4v v = z4;
        if (q < SS && d0 < DKK)
            v = *(const short4v*)((const short*)Qg + ((size_t)b * SS + q) * 960 + h * DKK + d0);
        *(short4v*)(Qs + r * LQ + d0) = v;
    }
    __syncthreads();
    short8 qa[2];
#pragma unroll
    for (int ks = 0; ks < 2; ++ks)
        qa[ks] = *(const short8*)(Qs + (w * 16 + llo) * LQ + ks * 32 + lhi * 8);

    float mrow[4] = {-1e30f, -1e30f, -1e30f, -1e30f};
    float lrow[4] = {0.f, 0.f, 0.f, 0.f};
    f32x4 o[3] = {fz, fz, fz};
    const int qrow = q0 + w * 16 + lhi * 4;

    for (int t = 0; t < 15; ++t) {
        const int kv0 = t * 64;
        for (int task = tid; task < 64 * 14; task += 256) {
            int r = task / 14, d0 = (task - r * 14) * 4;
            int kv = kv0 + r;
            short4v v = z4;
            if (kv < SS && d0 < DKK)
                v = *(const short4v*)((const short*)Kg + ((size_t)b * SS + kv) * 960 + h * DKK + d0);
            *(short4v*)(Ks + r * LK + d0) = v;
        }
        for (int task = tid; task < 48 * 16; task += 256) {
            int r = task / 16, c4 = (task - r * 16) * 4;
            short4v v = *(const short4v*)((const short*)VTg +
                         (((size_t)b * NHH + h) * 48 + r) * 960 + kv0 + c4);
            *(short4v*)(Vs + r * LV + c4) = v;
        }
        __syncthreads();
        f32x4 s[4] = {fz, fz, fz, fz};
#pragma unroll
        for (int ks = 0; ks < 2; ++ks) {
#pragma unroll
            for (int ni = 0; ni < 4; ++ni) {
                short8 kb = *(const short8*)(Ks + (ni * 16 + llo) * LK + ks * 32 + lhi * 8);
                s[ni] = __builtin_amdgcn_mfma_f32_16x16x32_bf16(qa[ks], kb, s[ni], 0, 0, 0);
            }
        }
#pragma unroll
        for (int ni = 0; ni < 4; ++ni) {
            int col = kv0 + ni * 16 + llo;
#pragma unroll
            for (int r = 0; r < 4; ++r) {
                int qc = qrow + r; if (qc > SS - 1) qc = SS - 1;
                float v = s[ni][r] * scale +
                          __bfloat162float(BIASg[((size_t)h * SS + qc) * 960 + col]);
                s[ni][r] = (col < SS) ? v : -1e30f;
            }
        }
        float rmax[4], psum[4], corr[4];
#pragma unroll
        for (int r = 0; r < 4; ++r)
            rmax[r] = fmaxf(fmaxf(s[0][r], s[1][r]), fmaxf(s[2][r], s[3][r]));
#pragma unroll
        for (int off = 1; off < 16; off <<= 1)
#pragma unroll
            for (int r = 0; r < 4; ++r)
                rmax[r] = fmaxf(rmax[r], __shfl_xor(rmax[r], off));
#pragma unroll
        for (int r = 0; r < 4; ++r) {
            float mnew = fmaxf(mrow[r], rmax[r]);
            corr[r] = expf(mrow[r] - mnew);
            mrow[r] = mnew;
            float ps = 0.f;
#pragma unroll
            for (int ni = 0; ni < 4; ++ni) {
                float p = expf(s[ni][r] - mnew);
                s[ni][r] = p;
                ps += p;
            }
            psum[r] = ps;
        }
#pragma unroll
        for (int off = 1; off < 16; off <<= 1)
#pragma unroll
            for (int r = 0; r < 4; ++r) psum[r] += __shfl_xor(psum[r], off);
#pragma unroll
        for (int r = 0; r < 4; ++r) lrow[r] = lrow[r] * corr[r] + psum[r];
#pragma unroll
        for (int nj = 0; nj < 3; ++nj)
#pragma unroll
            for (int r = 0; r < 4; ++r) o[nj][r] *= corr[r];
#pragma unroll
        for (int ni = 0; ni < 4; ++ni)
#pragma unroll
            for (int r = 0; r < 4; ++r)
                ((__hip_bfloat16*)Ps_w)[(lhi * 4 + r) * LP + ni * 16 + llo] =
                    __float2bfloat16(s[ni][r]);
#pragma unroll
        for (int ks = 0; ks < 2; ++ks) {
            short8 pa = *(const short8*)(Ps_w + llo * LP + ks * 32 + lhi * 8);
#pragma unroll
            for (int nj = 0; nj < 3; ++nj) {
                short8 vb = *(const short8*)(Vs + (nj * 16 + llo) * LV + ks * 32 + lhi * 8);
                o[nj] = __builtin_amdgcn_mfma_f32_16x16x32_bf16(pa, vb, o[nj], 0, 0, 0);
            }
        }
        __syncthreads();
    }
#pragma unroll
    for (int nj = 0; nj < 3; ++nj) {
        int d = nj * 16 + llo;
        if (d >= DKK) continue;
#pragma unroll
        for (int r = 0; r < 4; ++r) {
            int q = qrow + r;
            if (q < SS)
                AO[((size_t)b * SS + q) * DD + h * DKK + d] = __float2bfloat16(o[nj][r] / lrow[r]);
        }
    }
}

// ---------------- row LayerNorm: ln((a + a2? + cb? + add?)) ----------------
__global__ __launch_bounds__(320) void ln_kernel(const float* __restrict__ a,
                                                 const float* __restrict__ a2,
                                                 const float* __restrict__ cb,
                                                 const float* __restrict__ add,
                                                 const float* __restrict__ g,
                                                 const float* __restrict__ bta,
                                                 float* __restrict__ out,
                                                 __hip_bfloat16* __restrict__ outb) {
    const int row = blockIdx.x, i = threadIdx.x;
    __shared__ float red[320];
    __shared__ float s_m, s_v;
    float v = a[row * DD + i];
    if (a2) v += a2[row * DD + i];
    if (cb) v += cb[i];
    if (add) v += add[row * DD + i];
    red[i] = v;
    __syncthreads();
    if (i < 64) red[i] += red[i + 256];
    __syncthreads();
    for (int s = 128; s > 0; s >>= 1) {
        if (i < s) red[i] += red[i + s];
        __syncthreads();
    }
    if (i == 0) s_m = red[0] * (1.0f / DD);
    __syncthreads();
    const float d = v - s_m;
    red[i] = d * d;
    __syncthreads();
    if (i < 64) red[i] += red[i + 256];
    __syncthreads();
    for (int s = 128; s > 0; s >>= 1) {
        if (i < s) red[i] += red[i + s];
        __syncthreads();
    }
    if (i == 0) s_v = red[0] * (1.0f / DD);
    __syncthreads();
    float o = d * rsqrtf(s_v + 1e-5f) * g[i] + bta[i];
    out[row * DD + i] = o;
    outb[row * DD + i] = __float2bfloat16(o);
}

// ---------------- mean stage 1: partial sums over 150-row chunks ----------------
__global__ __launch_bounds__(256) void mpart_kernel(const float* __restrict__ xs,
                                                    float* __restrict__ mp) {
    const int b = blockIdx.y, z = blockIdx.z;
    const int d = blockIdx.x * 64 + (threadIdx.x & 63);
    const int rg = threadIdx.x >> 6;
    float s = 0.f;
    const int t0 = z * 150;
    for (int t = t0 + rg; t < t0 + 150; t += 4) s += xs[((size_t)b * SS + t) * DD + d];
    __shared__ float red[256];
    red[threadIdx.x] = s;
    __syncthreads();
    if (threadIdx.x < 128) red[threadIdx.x] += red[threadIdx.x + 128];
    __syncthreads();
    if (threadIdx.x < 64) mp[((size_t)b * 6 + z) * DD + d] = red[threadIdx.x] + red[threadIdx.x + 64];
}

// ---------------- transform params (reads 6 mean partials) ----------------
__global__ __launch_bounds__(64) void tp_kernel(const float* __restrict__ mp,
                                                const float* __restrict__ wrot, const float* __restrict__ brot,
                                                const float* __restrict__ wrefl, const float* __restrict__ brefl,
                                                const float* __restrict__ wtr, const float* __restrict__ btr,
                                                const float* __restrict__ wsc, const float* __restrict__ bsc,
                                                float* __restrict__ tp) {
    const int b = blockIdx.x, tid = threadIdx.x;
    __shared__ float gs[DD];
    __shared__ float raw[17];
    for (int j = tid; j < DD; j += 64) {
        float s6 = 0.f;
#pragma unroll
        for (int z = 0; z < 6; ++z) s6 += mp[((size_t)b * 6 + z) * DD + j];
        gs[j] = s6 * (1.0f / SS);
    }
    __syncthreads();
    if (tid < 17) {
        float s;
        if (tid < 4) {
            s = brot[tid];
            for (int d = 0; d < DD; ++d) s = fmaf(gs[d], wrot[d * 4 + tid], s);
        } else if (tid < 12) {
            int j = tid - 4;
            s = brefl[j];
            for (int d = 0; d < DD; ++d) s = fmaf(gs[d], wrefl[d * 8 + j], s);
        } else if (tid < 14) {
            int j = tid - 12;
            s = btr[j];
            for (int d = 0; d < DD; ++d) s = fmaf(gs[d], wtr[d * 2 + j], s);
        } else {
            int j = tid - 14;
            s = bsc[j];
            for (int d = 0; d < DD; ++d) s = fmaf(gs[d], wsc[d * 3 + j], s);
        }
        raw[tid] = s;
    }
    __syncthreads();
    if (tid == 0) {
        float mx = -1e30f;
        for (int j = 0; j < 4; ++j) mx = fmaxf(mx, raw[j]);
        float sm = 0.f, e[4];
        for (int j = 0; j < 4; ++j) { e[j] = expf(raw[j] - mx); sm += e[j]; }
        for (int j = 0; j < 4; ++j) tp[b * 17 + j] = e[j] / sm;
    } else if (tid == 1) {
        float mx = -1e30f;
        for (int j = 4; j < 12; ++j) mx = fmaxf(mx, raw[j]);
        float sm = 0.f, e[8];
        for (int j = 0; j < 8; ++j) { e[j] = expf(raw[4 + j] - mx); sm += e[j]; }
        for (int j = 0; j < 8; ++j) tp[b * 17 + 4 + j] = e[j] / sm;
    } else if (tid == 2) {
        tp[b * 17 + 12] = tanhf(raw[12]);
        tp[b * 17 + 13] = tanhf(raw[13]);
    } else if (tid == 3) {
        float mx = -1e30f;
        for (int j = 14; j < 17; ++j) mx = fmaxf(mx, raw[j]);
        float sm = 0.f, e[3];
        for (int j = 0; j < 3; ++j) { e[j] = expf(raw[14 + j] - mx); sm += e[j]; }
        for (int j = 0; j < 3; ++j) tp[b * 17 + 14 + j] = e[j] / sm;
    }
}

// ---------------- concat xs(bf16) + tp -> TIbf [3600, 384] ----------------
__global__ void concat_kernel(const __hip_bfloat16* __restrict__ xb, const float* __restrict__ tp,
                              __hip_bfloat16* __restrict__ ti) {
    int idx = blockIdx.x * 256 + threadIdx.x;
    if (idx >= BS * 384) return;
    int m = idx / 384, j = idx % 384;
    __hip_bfloat16 v;
    if (j < DD) v = xb[m * DD + j];
    else if (j < 337) v = __float2bfloat16(tp[(m / SS) * 17 + (j - DD)]);
    else v = __float2bfloat16(0.f);
    ti[idx] = v;
}

static inline void launch_mgemm(hipStream_t s, const __hip_bfloat16* A, int lda,
                                const __hip_bfloat16* Wt, int ldw, const float* bias,
                                const float* biasB, const float* biasC,
                                const float* res, int ldr, float alpha, float* Cf,
                                __hip_bfloat16* Cb, int ldc, int M, int N, int K, int act) {
    dim3 g((N + 63) / 64, (M + 127) / 128);
    mgemm_kernel<<<g, 256, 0, s>>>(A, lda, Wt, ldw, bias, biasB, biasC, res, ldr, alpha,
                                   Cf, nullptr, Cb, ldc, M, N, K, act);
}

extern "C" void kernel_launch(void* const* d_in, const int* in_sizes, int n_in,
                              void* d_out, int out_size, void* d_ws, size_t ws_size,
                              hipStream_t stream) {
    (void)in_sizes; (void)n_in; (void)out_size; (void)ws_size;
    const int* in_grid = (const int*)d_in[0];
    const float* pe = (const float*)d_in[1];
    const float* iew = (const float*)d_in[2];
    const float* ieb = (const float*)d_in[3];
    const float* wq = (const float*)d_in[4], *bq = (const float*)d_in[5];
    const float* wk = (const float*)d_in[6], *bk = (const float*)d_in[7];
    const float* wv = (const float*)d_in[8], *bv = (const float*)d_in[9];
    const float* wo = (const float*)d_in[10], *bo = (const float*)d_in[11];
    const float* lnag = (const float*)d_in[12], *lnab = (const float*)d_in[13];
    const float* dist_emb = (const float*)d_in[14], *dir_emb = (const float*)d_in[15];
    const float* wrot = (const float*)d_in[16], *brot = (const float*)d_in[17];
    const float* wrefl = (const float*)d_in[18], *brefl = (const float*)d_in[19];
    const float* wtr = (const float*)d_in[20], *btr = (const float*)d_in[21];
    const float* wsc = (const float*)d_in[22], *bsc = (const float*)d_in[23];
    const float* tnw1 = (const float*)d_in[24], *tnb1 = (const float*)d_in[25];
    const float* tnw2 = (const float*)d_in[26], *tnb2 = (const float*)d_in[27];
    const float* tnw3 = (const float*)d_in[28], *tnb3 = (const float*)d_in[29];
    const float* ffw1 = (const float*)d_in[30], *ffb1 = (const float*)d_in[31];
    const float* ffw2 = (const float*)d_in[32], *ffb2 = (const float*)d_in[33];
    const float* ln2g = (const float*)d_in[34], *ln2b = (const float*)d_in[35];
    const float* ck1 = (const float*)d_in[36], *cb1 = (const float*)d_in[37];
    const float* ck3 = (const float*)d_in[38], *cb3 = (const float*)d_in[39];
    const float* ck5 = (const float*)d_in[40], *cb5 = (const float*)d_in[41];
    const float* ck7 = (const float*)d_in[42], *cb7 = (const float*)d_in[43];
    const float* fusw = (const float*)d_in[44], *fusb = (const float*)d_in[45];
    const float* opw1 = (const float*)d_in[46], *opb1 = (const float*)d_in[47];
    const float* opw2 = (const float*)d_in[48], *opb2 = (const float*)d_in[49];
    const float* opw3 = (const float*)d_in[50], *opb3 = (const float*)d_in[51];
    const int* dist_idx = (const int*)d_in[52];
    const int* dir_idx = (const int*)d_in[53];
    float* out = (float*)d_out;

    // ---- workspace arena (byte offsets) ----
    char* base = (char*)d_ws;
    typedef __hip_bfloat16 bf;
    bf* WQKVT = (bf*)(base + 0);          // [4][960][320]
    bf* WOT = (bf*)(base + 2457600);
    bf* TN1T = (bf*)(base + 3276800);
    bf* TN2T = (bf*)(base + 5242880);
    bf* TN3T = (bf*)(base + 6881280);
    bf* FF1T = (bf*)(base + 7700480);
    bf* FF2T = (bf*)(base + 10977280);
    bf* CK1T = (bf*)(base + 14254080);
    bf* CK3T = (bf*)(base + 14458880);
    bf* CK5T = (bf*)(base + 16302080);
    bf* CK7T = (bf*)(base + 21422080);
    bf* FUST = (bf*)(base + 31457280);
    bf* OP1T = (bf*)(base + 32276480);
    float* XS = (float*)(base + 32378880);
    bf* XSbf = (bf*)(base + 36986880);
    bf* QKVbf = (bf*)(base + 39290880);   // [3600][960], ends 46,202,880
    bf* VT = (bf*)(base + 46202880);      // ends 49,152,000
    float* P1f = (float*)(base + 39290880);  // ff2 K-split partial (QKV region, dead post-attn)
    float* R2 = (float*)(base + 53114880);
    float* TP = (float*)(base + 57728000);
    // conv bf16 partials: [7][3600][320] bf16 = 16,128,000 B in dead QKV..R2 region
    bf* CPART = (bf*)(base + 39290880);
    char* BIG = base + 57728512;
    bf* AObf = (bf*)(BIG + 0);
    float* MPart = (float*)(BIG + 0);     // [4][6][320] f32, mean partials (AObf dead; pre-concat)
    bf* BIAS = (bf*)(BIG + 2764800);
    bf* TIbf = (bf*)(BIG + 0);
    bf* T1bf = (bf*)(BIG + 2764800);
    bf* T2bf = (bf*)(BIG + 7372800);
    bf* F1bf = (bf*)(BIG + 0);
    bf* PADbf = (bf*)(BIG + 0);
    bf* FEATSbf = (bf*)(BIG + 3317760);
    float* H1 = (float*)(BIG + 0);
    float* H2 = (float*)(BIG + 2304000);
    bf* R2bf = XSbf;

    dim3 cb(32, 8);
    qkvconvt_kernel<<<dim3(10, 10, 12), cb, 0, stream>>>(wq, wk, wv, WQKVT);
    allconvt_kernel<<<14610, cb, 0, stream>>>(wo, tnw1, tnw2, tnw3, ffw1, ffw2,
                                              ck1, ck3, ck5, ck7, fusw, opw1,
                                              WOT, TN1T, TN2T, TN3T, FF1T, FF2T,
                                              CK1T, CK3T, CK5T, CK7T, FUST, OP1T);

    embed_kernel<<<4500, 256, 0, stream>>>(in_grid, pe, iew, ieb, XS, XSbf);

    for (int l = 0; l < LL; ++l) {
        const int wO = l * DD * DD, bO = l * DD;
        // fused QKV projection: N=960
        launch_mgemm(stream, XSbf, DD, WQKVT + l * 307200, 320, bq + bO, bk + bO, bv + bO,
                     nullptr, 0, 1.f, nullptr, QKVbf, 960, BS, 960, 320, 0);
        attprep_kernel<<<32760, 256, 0, stream>>>(dist_emb + l * 60 * NHH, dir_emb + l * 8 * NHH,
                                                  dist_idx, dir_idx, QKVbf, BIAS, VT);
        mattn_kernel<<<dim3(15, NHH, BB), 256, 0, stream>>>(QKVbf, QKVbf + 320, VT, BIAS, AObf);
        launch_mgemm(stream, AObf, DD, WOT + wO, DD, bo + bO, nullptr, nullptr, XS, DD, 1.f,
                     R2, nullptr, DD, BS, DD, DD, 0);
        ln_kernel<<<BS, 320, 0, stream>>>(R2, nullptr, nullptr, nullptr, lnag + bO, lnab + bO, XS, XSbf);
        mpart_kernel<<<dim3(5, BB, 6), 256, 0, stream>>>(XS, MPart);
        tp_kernel<<<BB, 64, 0, stream>>>(MPart, wrot + l * 1280, brot + l * 4,
                                         wrefl + l * 2560, brefl + l * 8,
                                         wtr + l * 640, btr + l * 2,
                                         wsc + l * 960, bsc + l * 3, TP);
        concat_kernel<<<(BS * 384 + 255) / 256, 256, 0, stream>>>(XSbf, TP, TIbf);
        launch_mgemm(stream, TIbf, 384, TN1T + l * 245760, 384, tnb1 + l * 640, nullptr, nullptr,
                     nullptr, 0, 1.f, nullptr, T1bf, 640, BS, 640, 384, 1);
        launch_mgemm(stream, T1bf, 640, TN2T + l * 204800, 640, tnb2 + bO, nullptr, nullptr,
                     nullptr, 0, 1.f, nullptr, T2bf, DD, BS, DD, 640, 1);
        launch_mgemm(stream, T2bf, DD, TN3T + wO, DD, tnb3 + bO, nullptr, nullptr, XS, DD, 0.3f,
                     XS, XSbf, DD, BS, DD, DD, 0);
        launch_mgemm(stream, XSbf, DD, FF1T + l * 409600, DD, ffb1 + l * FFD, nullptr, nullptr,
                     nullptr, 0, 1.f, nullptr, F1bf, FFD, BS, FFD, DD, 1);
        // ff2 split-K: z=0 -> R2 (K rows 0..639), z=1 -> P1f (rows 640..1279); merged in ln
        {
            dim3 g(5, 29, 2);
            mgemm_kernel<<<g, 256, 0, stream>>>(F1bf, FFD, FF2T + l * 409600, FFD,
                                                nullptr, nullptr, nullptr, nullptr, 0, 1.f,
                                                R2, P1f, nullptr, DD, BS, DD, 640, 0);
        }
        ln_kernel<<<BS, 320, 0, stream>>>(R2, P1f, ffb2 + bO, XS, ln2g + bO, ln2b + bO, XS, XSbf);
    }

    // ---- multiscale convs: per-kh bf16 partials + reduce ----
    pad_kernel<<<(BB * 36 * 36 * DD + 255) / 256, 256, 0, stream>>>(XSbf, PADbf);
    launch_mgemm(stream, XSbf, DD, CK1T, DD, cb1, nullptr, nullptr, nullptr, 0, 1.f,
                 nullptr, FEATSbf + 0, 1280, BS, DD, DD, 2);
    const int RED = (BS * DD / 8 + 255) / 256;
    mconv_kernel<3><<<dim3(5, 29, 3), 256, 0, stream>>>(PADbf, CK3T, CPART, 1);
    creduce_kernel<<<RED, 256, 0, stream>>>(CPART, 3, cb3, FEATSbf + 320, 1280);
    mconv_kernel<5><<<dim3(5, 29, 5), 256, 0, stream>>>(PADbf, CK5T, CPART, 1);
    creduce_kernel<<<RED, 256, 0, stream>>>(CPART, 5, cb5, FEATSbf + 640, 1280);
    mconv_kernel<7><<<dim3(5, 29, 7), 256, 0, stream>>>(PADbf, CK7T, CPART, 1);
    creduce_kernel<<<RED, 256, 0, stream>>>(CPART, 7, cb7, FEATSbf + 960, 1280);
    launch_mgemm(stream, FEATSbf, 1280, FUST, 1280, fusb, nullptr, nullptr, nullptr, 0, 1.f,
                 nullptr, R2bf, DD, BS, DD, 1280, 0);
    // ---- output head ----
    launch_mgemm(stream, R2bf, DD, OP1T, DD, opb1, nullptr, nullptr, nullptr, 0, 1.f,
                 H1, nullptr, 160, BS, 160, DD, 1);
    gemm_kernel<<<dim3(2, 57), 256, 0, stream>>>(H1, 160, opw2, opb2, H2, 80, BS, 80, 160, 1);
    gemm_kernel<<<dim3(1, 57), 256, 0, stream>>>(H2, 80, opw3, opb3, out, 10, BS, 10, 80, 0);
}

// Round 9
// 1609.833 us; speedup vs baseline: 6.8625x; 1.0825x over previous
//
#include <hip/hip_runtime.h>
#include <hip/hip_bf16.h>

#define BB 4
#define GG_ 30
#define DD 320
#define LL 4
#define NHH 8
#define DKK 40
#define SS 900
#define BS 3600
#define FFD 1280
#define LDK 72   // BK(64) + 8 pad, in bf16 elems -> 144B row stride, 16B aligned

typedef __attribute__((ext_vector_type(8))) short short8;
typedef __attribute__((ext_vector_type(4))) short short4v;
typedef __attribute__((ext_vector_type(4))) float f32x4;

__device__ __forceinline__ float gelu_f(float x) {
    return 0.5f * x * (1.0f + erff(x * 0.70710678118654752f));
}

__device__ __forceinline__ float bfbits2f(short b) {
    return __uint_as_float(((unsigned)(unsigned short)b) << 16);
}

// ---------------- shared convt tile body ----------------
__device__ __forceinline__ void convt_tile(const float* __restrict__ s,
                                           __hip_bfloat16* __restrict__ d,
                                           int K, int N, int Kpad, int kb, int nb) {
    __shared__ float t[32][33];
    const int tx = threadIdx.x, ty = threadIdx.y;   // (32, 8)
#pragma unroll
    for (int i = 0; i < 4; ++i) {
        int k = kb + ty + i * 8, n = nb + tx;
        t[ty + i * 8][tx] = (k < K && n < N) ? s[(size_t)k * N + n] : 0.f;
    }
    __syncthreads();
#pragma unroll
    for (int i = 0; i < 4; ++i) {
        int n = nb + ty + i * 8, k = kb + tx;
        if (n < N && k < Kpad) d[(size_t)n * Kpad + k] = __float2bfloat16(t[tx][ty + i * 8]);
    }
}

// ---------------- ALL weight transposes in one launch (14610 blocks) ----------------
__global__ __launch_bounds__(256) void allconvt_kernel(
    const float* wo, const float* tnw1, const float* tnw2, const float* tnw3,
    const float* ffw1, const float* ffw2, const float* ck1, const float* ck3,
    const float* ck5, const float* ck7, const float* fusw, const float* opw1,
    __hip_bfloat16* WOT, __hip_bfloat16* TN1T, __hip_bfloat16* TN2T, __hip_bfloat16* TN3T,
    __hip_bfloat16* FF1T, __hip_bfloat16* FF2T, __hip_bfloat16* CK1T, __hip_bfloat16* CK3T,
    __hip_bfloat16* CK5T, __hip_bfloat16* CK7T, __hip_bfloat16* FUST, __hip_bfloat16* OP1T) {
    const int bid = blockIdx.x;
    const float* s; __hip_bfloat16* d;
    int K, N, Kpad, gx, per, local, sS, dS;
    if (bid < 400)        { local = bid;         s = wo;   d = WOT;  K = 320;  N = 320;  Kpad = 320;  sS = 102400; dS = 102400; gx = 10;  per = 100; }
    else if (bid < 1360)  { local = bid - 400;   s = tnw1; d = TN1T; K = 337;  N = 640;  Kpad = 384;  sS = 215680; dS = 245760; gx = 12;  per = 240; }
    else if (bid < 2160)  { local = bid - 1360;  s = tnw2; d = TN2T; K = 640;  N = 320;  Kpad = 640;  sS = 204800; dS = 204800; gx = 20;  per = 200; }
    else if (bid < 2560)  { local = bid - 2160;  s = tnw3; d = TN3T; K = 320;  N = 320;  Kpad = 320;  sS = 102400; dS = 102400; gx = 10;  per = 100; }
    else if (bid < 4160)  { local = bid - 2560;  s = ffw1; d = FF1T; K = 320;  N = 1280; Kpad = 320;  sS = 409600; dS = 409600; gx = 10;  per = 400; }
    else if (bid < 5760)  { local = bid - 4160;  s = ffw2; d = FF2T; K = 1280; N = 320;  Kpad = 1280; sS = 409600; dS = 409600; gx = 40;  per = 400; }
    else if (bid < 5860)  { local = bid - 5760;  s = ck1;  d = CK1T; K = 320;  N = 320;  Kpad = 320;  sS = 0; dS = 0; gx = 10;  per = 100; }
    else if (bid < 6760)  { local = bid - 5860;  s = ck3;  d = CK3T; K = 2880; N = 320;  Kpad = 2880; sS = 0; dS = 0; gx = 90;  per = 900; }
    else if (bid < 9260)  { local = bid - 6760;  s = ck5;  d = CK5T; K = 8000; N = 320;  Kpad = 8000; sS = 0; dS = 0; gx = 250; per = 2500; }
    else if (bid < 14160) { local = bid - 9260;  s = ck7;  d = CK7T; K = 15680; N = 320; Kpad = 15680; sS = 0; dS = 0; gx = 490; per = 4900; }
    else if (bid < 14560) { local = bid - 14160; s = fusw; d = FUST; K = 1280; N = 320;  Kpad = 1280; sS = 0; dS = 0; gx = 40;  per = 400; }
    else                  { local = bid - 14560; s = opw1; d = OP1T; K = 320;  N = 160;  Kpad = 320;  sS = 0; dS = 0; gx = 10;  per = 50; }
    const int mat = local / per, rem = local - mat * per;
    const int kb = (rem % gx) * 32, nb = (rem / gx) * 32;
    convt_tile(s + (size_t)mat * sS, d + (size_t)mat * dS, K, N, Kpad, kb, nb);
}

// ---------------- packed QKV weight convert: [L][960][320] bf16 ----------------
__global__ __launch_bounds__(256) void qkvconvt_kernel(const float* __restrict__ wq,
                                                       const float* __restrict__ wk,
                                                       const float* __restrict__ wv,
                                                       __hip_bfloat16* __restrict__ dst) {
    __shared__ float t[32][33];
    const int z = blockIdx.z, l = z / 3, wsel = z % 3;
    const float* s = (wsel == 0 ? wq : wsel == 1 ? wk : wv) + (size_t)l * 102400;
    __hip_bfloat16* d = dst + (size_t)l * 307200 + wsel * 102400;
    const int kb = blockIdx.x * 32, nb = blockIdx.y * 32;
    const int tx = threadIdx.x, ty = threadIdx.y;   // (32, 8)
#pragma unroll
    for (int i = 0; i < 4; ++i) {
        int k = kb + ty + i * 8, n = nb + tx;
        t[ty + i * 8][tx] = s[(size_t)k * 320 + n];
    }
    __syncthreads();
#pragma unroll
    for (int i = 0; i < 4; ++i) {
        int n = nb + ty + i * 8, k = kb + tx;
        d[(size_t)n * 320 + k] = __float2bfloat16(t[tx][ty + i * 8]);
    }
}

// ---------------- embed ----------------
__global__ void embed_kernel(const int* __restrict__ grid, const float* __restrict__ pe,
                             const float* __restrict__ ew, const float* __restrict__ eb,
                             float* __restrict__ x, __hip_bfloat16* __restrict__ xb) {
    int idx = blockIdx.x * 256 + threadIdx.x;   // < 1,152,000
    int m = idx / DD, d = idx % DD;
    int gv = grid[m];
    float v = ew[gv * DD + d] + eb[d] + pe[(m % SS) * DD + d];
    x[idx] = v;
    xb[idx] = __float2bfloat16(v);
}

// ---------------- MFMA bf16 GEMM (proven 128x64 body; 3-way bias; optional K-split z) ----------------
__global__ __launch_bounds__(256) void mgemm_kernel(
    const __hip_bfloat16* __restrict__ A, int lda,
    const __hip_bfloat16* __restrict__ Wt, int ldw,
    const float* __restrict__ bias, const float* __restrict__ biasB, const float* __restrict__ biasC,
    const float* __restrict__ res, int ldr,
    float alpha, float* __restrict__ Cf, float* __restrict__ Cf2,
    __hip_bfloat16* __restrict__ Cb, int ldc,
    int M, int N, int K, int act) {
    __shared__ short As[128 * LDK];
    __shared__ short Bs[64 * LDK];
    const int tid = threadIdx.x;
    const int m0 = blockIdx.y * 128, n0 = blockIdx.x * 64;
    const int kb0 = blockIdx.z * K;                 // K-split offset (z=0 for normal calls)
    float* __restrict__ CfO = (blockIdx.z == 0) ? Cf : Cf2;
    const int lane = tid & 63;
    const int w = tid >> 6, wm = w >> 1, wn = w & 1;
    const int rbase = tid >> 3, q8 = (tid & 7) * 8;
    f32x4 acc[4][2];
    const f32x4 fz = {0.f, 0.f, 0.f, 0.f};
#pragma unroll
    for (int mi = 0; mi < 4; ++mi)
#pragma unroll
        for (int ni = 0; ni < 2; ++ni) acc[mi][ni] = fz;
    const short8 zz = {0, 0, 0, 0, 0, 0, 0, 0};
    for (int k0 = 0; k0 < K; k0 += 64) {
#pragma unroll
        for (int c = 0; c < 4; ++c) {
            int r = c * 32 + rbase, m = m0 + r;
            short8 v = zz;
            if (m < M) v = *(const short8*)((const short*)A + (size_t)m * lda + kb0 + k0 + q8);
            *(short8*)(As + r * LDK + q8) = v;
        }
#pragma unroll
        for (int c = 0; c < 2; ++c) {
            int r = c * 32 + rbase, n = n0 + r;
            short8 v = zz;
            if (n < N) v = *(const short8*)((const short*)Wt + (size_t)n * ldw + kb0 + k0 + q8);
            *(short8*)(Bs + r * LDK + q8) = v;
        }
        __syncthreads();
#pragma unroll
        for (int ks = 0; ks < 64; ks += 32) {
            const int kb = ks + (lane >> 4) * 8;
            short8 af[4], bf[2];
#pragma unroll
            for (int mi = 0; mi < 4; ++mi)
                af[mi] = *(const short8*)(As + (wm * 64 + mi * 16 + (lane & 15)) * LDK + kb);
#pragma unroll
            for (int ni = 0; ni < 2; ++ni)
                bf[ni] = *(const short8*)(Bs + (wn * 32 + ni * 16 + (lane & 15)) * LDK + kb);
#pragma unroll
            for (int mi = 0; mi < 4; ++mi)
#pragma unroll
                for (int ni = 0; ni < 2; ++ni)
                    acc[mi][ni] = __builtin_amdgcn_mfma_f32_16x16x32_bf16(af[mi], bf[ni], acc[mi][ni], 0, 0, 0);
        }
        __syncthreads();
    }
    const int col0 = n0 + wn * 32 + (lane & 15);
    const int rloc = (lane >> 4) * 4;
#pragma unroll
    for (int mi = 0; mi < 4; ++mi) {
#pragma unroll
        for (int ni = 0; ni < 2; ++ni) {
            int col = col0 + ni * 16;
            if (col >= N) continue;
            float bv;
            if (biasC) bv = (col < 320) ? bias[col] : (col < 640) ? biasB[col - 320] : biasC[col - 640];
            else bv = bias ? bias[col] : 0.f;
#pragma unroll
            for (int r = 0; r < 4; ++r) {
                int row = m0 + wm * 64 + mi * 16 + rloc + r;
                if (row >= M) continue;
                float v = acc[mi][ni][r] + bv;
                if (act == 1) v = gelu_f(v);
                else if (act == 2) v = fmaxf(v, 0.f);
                v *= alpha;
                if (res) v += res[(size_t)row * ldr + col];
                if (CfO) CfO[(size_t)row * ldc + col] = v;
                if (Cb) Cb[(size_t)row * ldc + col] = __float2bfloat16(v);
            }
        }
    }
}

// ---------------- MFMA conv (128x64 body + kh-split; grid x=M-tiles for W locality) ----------------
template <int KS>
__global__ __launch_bounds__(256) void mconv_kernel(
    const __hip_bfloat16* __restrict__ P, const __hip_bfloat16* __restrict__ Wt,
    __hip_bfloat16* __restrict__ part, int kh0step) {
    const int K = KS * KS * DD;
    const int OFF = 3 - KS / 2;
    const int kh0 = blockIdx.z * kh0step;
    const int nkh = (KS - kh0 < kh0step) ? (KS - kh0) : kh0step;
    const int Ksub = nkh * KS * DD;          // multiples of 64 for KS in {3,5,7}
    const int wbase = kh0 * KS * DD;
    __hip_bfloat16* __restrict__ Cp = part + (size_t)blockIdx.z * BS * DD;
    __shared__ short As[128 * LDK];
    __shared__ short Bs[64 * LDK];
    const int tid = threadIdx.x;
    const int m0 = blockIdx.x * 128, n0 = blockIdx.y * 64;   // x=M (29), y=N (5)
    const int lane = tid & 63;
    const int w = tid >> 6, wm = w >> 1, wn = w & 1;
    const int rbase = tid >> 3, q8 = (tid & 7) * 8;
    f32x4 acc[4][2];
    const f32x4 fz = {0.f, 0.f, 0.f, 0.f};
#pragma unroll
    for (int mi = 0; mi < 4; ++mi)
#pragma unroll
        for (int ni = 0; ni < 2; ++ni) acc[mi][ni] = fz;
    const short8 zz = {0, 0, 0, 0, 0, 0, 0, 0};
    for (int k0 = 0; k0 < Ksub; k0 += 64) {
#pragma unroll
        for (int c = 0; c < 4; ++c) {
            int r = c * 32 + rbase, m = m0 + r;
            int k = k0 + q8;
            int ci = k % DD, t = k / DD;
            int kw = t % KS, kh = kh0 + t / KS;
            short8 v = zz;
            if (m < BS) {
                int b = m / SS, hw = m % SS, oh = hw / GG_, ow = hw % GG_;
                int ih = oh + kh + OFF, iw = ow + kw + OFF;
                v = *(const short8*)((const short*)P + (((b * 36 + ih) * 36 + iw) * DD + ci));
            }
            *(short8*)(As + r * LDK + q8) = v;
        }
#pragma unroll
        for (int c = 0; c < 2; ++c) {
            int r = c * 32 + rbase, n = n0 + r;
            short8 v = *(const short8*)((const short*)Wt + (size_t)n * K + wbase + k0 + q8);
            *(short8*)(Bs + r * LDK + q8) = v;
        }
        __syncthreads();
#pragma unroll
        for (int ks = 0; ks < 64; ks += 32) {
            const int kb = ks + (lane >> 4) * 8;
            short8 af[4], bf[2];
#pragma unroll
            for (int mi = 0; mi < 4; ++mi)
                af[mi] = *(const short8*)(As + (wm * 64 + mi * 16 + (lane & 15)) * LDK + kb);
#pragma unroll
            for (int ni = 0; ni < 2; ++ni)
                bf[ni] = *(const short8*)(Bs + (wn * 32 + ni * 16 + (lane & 15)) * LDK + kb);
#pragma unroll
            for (int mi = 0; mi < 4; ++mi)
#pragma unroll
                for (int ni = 0; ni < 2; ++ni)
                    acc[mi][ni] = __builtin_amdgcn_mfma_f32_16x16x32_bf16(af[mi], bf[ni], acc[mi][ni], 0, 0, 0);
        }
        __syncthreads();
    }
    const int col0 = n0 + wn * 32 + (lane & 15);
    const int rloc = (lane >> 4) * 4;
#pragma unroll
    for (int mi = 0; mi < 4; ++mi) {
#pragma unroll
        for (int ni = 0; ni < 2; ++ni) {
            int col = col0 + ni * 16;
#pragma unroll
            for (int r = 0; r < 4; ++r) {
                int row = m0 + wm * 64 + mi * 16 + rloc + r;
                if (row < BS) Cp[(size_t)row * DD + col] = __float2bfloat16(acc[mi][ni][r]);
            }
        }
    }
}

// ---------------- conv partial reduce: relu(sum bf16 parts + bias) -> bf16 @ldc ----------------
__global__ __launch_bounds__(256) void creduce_kernel(const __hip_bfloat16* __restrict__ part,
                                                      int nsplit, const float* __restrict__ bias,
                                                      __hip_bfloat16* __restrict__ outb, int ldc) {
    int idx = blockIdx.x * 256 + threadIdx.x;      // over BS*DD/8 groups of 8 cols
    if (idx >= BS * DD / 8) return;
    int row = idx / (DD / 8), c8 = (idx % (DD / 8)) * 8;
    float s[8] = {};
    for (int p = 0; p < nsplit; ++p) {
        short8 v = *(const short8*)((const short*)part + (size_t)p * BS * DD + (size_t)row * DD + c8);
#pragma unroll
        for (int j = 0; j < 8; ++j) s[j] += bfbits2f(v[j]);
    }
    __hip_bfloat16* o = outb + (size_t)row * ldc + c8;
#pragma unroll
    for (int j = 0; j < 8; ++j) o[j] = __float2bfloat16(fmaxf(s[j] + bias[c8 + j], 0.f));
}

// ---------------- pad bf16 image for convs ----------------
__global__ void pad_kernel(const __hip_bfloat16* __restrict__ xb, __hip_bfloat16* __restrict__ p) {
    int idx = blockIdx.x * 256 + threadIdx.x;   // 4*36*36*320
    if (idx >= BB * 36 * 36 * DD) return;
    int c = idx % DD, t = idx / DD;
    int wp = t % 36, t2 = t / 36, hp = t2 % 36, b = t2 / 36;
    __hip_bfloat16 v = __float2bfloat16(0.f);
    if (hp >= 3 && hp < 33 && wp >= 3 && wp < 33)
        v = xb[((b * SS + (hp - 3) * GG_ + (wp - 3))) * DD + c];
    p[idx] = v;
}

// ---------------- legacy fp32 GEMM (tiny op heads) ----------------
__global__ __launch_bounds__(256) void gemm_kernel(
    const float* __restrict__ A, int lda, const float* __restrict__ W,
    const float* __restrict__ bias, float* __restrict__ C, int ldc,
    int M, int N, int K, int act) {
    __shared__ float As[16][65];
    __shared__ float Ws[16][65];
    const int tid = threadIdx.x;
    const int m0 = blockIdx.y * 64, n0 = blockIdx.x * 64;
    const int tx = tid & 15, ty = tid >> 4;
    float acc[4][4] = {};
    const int kkA = tid & 15, mloc0 = tid >> 4;
    const int nloc = tid & 63, kk0 = tid >> 6;
    for (int k0 = 0; k0 < K; k0 += 16) {
        const int kA = k0 + kkA;
#pragma unroll
        for (int i = 0; i < 4; ++i) {
            int mloc = mloc0 + i * 16, m = m0 + mloc;
            As[kkA][mloc] = (m < M && kA < K) ? A[m * lda + kA] : 0.f;
        }
#pragma unroll
        for (int i = 0; i < 4; ++i) {
            int kk = kk0 + i * 4, k = k0 + kk, n = n0 + nloc;
            Ws[kk][nloc] = (k < K && n < N) ? W[k * N + n] : 0.f;
        }
        __syncthreads();
#pragma unroll
        for (int kk = 0; kk < 16; ++kk) {
            float a[4], b[4];
#pragma unroll
            for (int i = 0; i < 4; ++i) a[i] = As[kk][ty * 4 + i];
#pragma unroll
            for (int j = 0; j < 4; ++j) b[j] = Ws[kk][tx * 4 + j];
#pragma unroll
            for (int i = 0; i < 4; ++i)
#pragma unroll
                for (int j = 0; j < 4; ++j) acc[i][j] = fmaf(a[i], b[j], acc[i][j]);
        }
        __syncthreads();
    }
#pragma unroll
    for (int i = 0; i < 4; ++i) {
        int m = m0 + ty * 4 + i;
        if (m >= M) continue;
#pragma unroll
        for (int j = 0; j < 4; ++j) {
            int n = n0 + tx * 4 + j;
            if (n >= N) continue;
            float v = acc[i][j] + bias[n];
            if (act == 1) v = gelu_f(v);
            C[m * ldc + n] = v;
        }
    }
}

// ---------------- merged attn prep: bias table + V transpose ----------------
__global__ __launch_bounds__(256) void attprep_kernel(const float* __restrict__ de,
                                                      const float* __restrict__ dre,
                                                      const int* __restrict__ dist,
                                                      const int* __restrict__ dirn,
                                                      const __hip_bfloat16* __restrict__ QKV,
                                                      __hip_bfloat16* __restrict__ biasOut,
                                                      __hip_bfloat16* __restrict__ VT) {
    const int gid = blockIdx.x;
    const int tid = threadIdx.x;
    if (gid < 27000) {
        const int h = gid / 3375;
        int idx = (gid % 3375) * 256 + tid;        // < 864000
        int sq = idx / 960, t = idx - sq * 960;
        float v = 0.f;
        if (t < SS) v = de[dist[sq * SS + t] * NHH + h] + dre[dirn[sq * SS + t] * NHH + h];
        biasOut[((size_t)h * SS + sq) * 960 + t] = __float2bfloat16(v);
    } else {
        int idx = (gid - 27000) * 256 + tid;       // < 1,474,560
        int t = idx % 960;
        int d = (idx / 960) % 48;
        int h = (idx / (960 * 48)) % NHH;
        int b = idx / (960 * 48 * NHH);
        __hip_bfloat16 v = __float2bfloat16(0.f);
        if (t < SS && d < DKK) v = QKV[((size_t)b * SS + t) * 960 + 640 + h * DKK + d];
        VT[idx] = v;
    }
}

// ---------------- MFMA flash attention: 512 thr, in-block KV-split + merge ----------------
// waves 0-3 (ws=0): even kv tiles; waves 4-7 (ws=1): odd kv tiles; same 64 q rows.
#define LQ 72
#define LK 72
#define LV 72
#define LP 72
__global__ __launch_bounds__(512) void mattn_kernel(
    const __hip_bfloat16* __restrict__ Qg, const __hip_bfloat16* __restrict__ Kg,
    const __hip_bfloat16* __restrict__ VTg, const __hip_bfloat16* __restrict__ BIASg,
    __hip_bfloat16* __restrict__ AO) {
    const int qt = blockIdx.x, h = blockIdx.y, b = blockIdx.z;
    const int tid = threadIdx.x, lane = tid & 63, w = tid >> 6;
    const int wq = w & 3, ws = w >> 2;
    const int tid2 = tid & 255;
    const int lhi = lane >> 4, llo = lane & 15;
    __shared__ short Qs[64 * LQ];
    __shared__ short Ks[2][64 * LK];
    __shared__ short Vs[2][48 * LV];
    __shared__ short Ps[8][16 * LP];
    __shared__ float Lm[4][16];
    __shared__ float Ll[4][16];
    __shared__ float Lo[4][16][DKK];
    short* Ps_w = Ps[w];
    short* Ks_s = Ks[ws];
    short* Vs_s = Vs[ws];
    const int q0 = qt * 64;
    const short4v z4 = {0, 0, 0, 0};
    const f32x4 fz = {0.f, 0.f, 0.f, 0.f};
    const float scale = 0.15811388300841898f;  // 1/sqrt(40)

    // stage Q tile (64 x 64 valid region of LQ=72 rows; k in [40,64) zeroed)
    for (int task = tid; task < 64 * 16; task += 512) {
        int r = task >> 4, d0 = (task & 15) * 4;
        int q = q0 + r;
        short4v v = z4;
        if (q < SS && d0 < DKK)
            v = *(const short4v*)((const short*)Qg + ((size_t)b * SS + q) * 960 + h * DKK + d0);
        *(short4v*)(Qs + r * LQ + d0) = v;
    }
    __syncthreads();
    short8 qa[2];
#pragma unroll
    for (int ks = 0; ks < 2; ++ks)
        qa[ks] = *(const short8*)(Qs + (wq * 16 + llo) * LQ + ks * 32 + lhi * 8);

    float mrow[4] = {-1e30f, -1e30f, -1e30f, -1e30f};
    float lrow[4] = {0.f, 0.f, 0.f, 0.f};
    f32x4 o[3] = {fz, fz, fz};
    const int qrow = q0 + wq * 16 + lhi * 4;

    for (int tt = 0; tt < 8; ++tt) {
        const int t = tt * 2 + ws;
        const int kv0 = t * 64;
        if (t < 15) {
            for (int task = tid2; task < 64 * 16; task += 256) {
                int r = task >> 4, d0 = (task & 15) * 4;
                int kv = kv0 + r;
                short4v v = z4;
                if (kv < SS && d0 < DKK)
                    v = *(const short4v*)((const short*)Kg + ((size_t)b * SS + kv) * 960 + h * DKK + d0);
                *(short4v*)(Ks_s + r * LK + d0) = v;
            }
            for (int task = tid2; task < 48 * 16; task += 256) {
                int r = task >> 4, c4 = (task & 15) * 4;
                short4v v = *(const short4v*)((const short*)VTg +
                             (((size_t)b * NHH + h) * 48 + r) * 960 + kv0 + c4);
                *(short4v*)(Vs_s + r * LV + c4) = v;
            }
        }
        __syncthreads();
        if (t < 15) {
            f32x4 s[4] = {fz, fz, fz, fz};
#pragma unroll
            for (int ks = 0; ks < 2; ++ks) {
#pragma unroll
                for (int ni = 0; ni < 4; ++ni) {
                    short8 kb = *(const short8*)(Ks_s + (ni * 16 + llo) * LK + ks * 32 + lhi * 8);
                    s[ni] = __builtin_amdgcn_mfma_f32_16x16x32_bf16(qa[ks], kb, s[ni], 0, 0, 0);
                }
            }
#pragma unroll
            for (int ni = 0; ni < 4; ++ni) {
                int col = kv0 + ni * 16 + llo;
#pragma unroll
                for (int r = 0; r < 4; ++r) {
                    int qc = qrow + r; if (qc > SS - 1) qc = SS - 1;
                    float v = s[ni][r] * scale +
                              __bfloat162float(BIASg[((size_t)h * SS + qc) * 960 + col]);
                    s[ni][r] = (col < SS) ? v : -1e30f;
                }
            }
            float rmax[4], psum[4], corr[4];
#pragma unroll
            for (int r = 0; r < 4; ++r)
                rmax[r] = fmaxf(fmaxf(s[0][r], s[1][r]), fmaxf(s[2][r], s[3][r]));
#pragma unroll
            for (int off = 1; off < 16; off <<= 1)
#pragma unroll
                for (int r = 0; r < 4; ++r)
                    rmax[r] = fmaxf(rmax[r], __shfl_xor(rmax[r], off));
#pragma unroll
            for (int r = 0; r < 4; ++r) {
                float mnew = fmaxf(mrow[r], rmax[r]);
                corr[r] = __expf(mrow[r] - mnew);
                mrow[r] = mnew;
                float ps = 0.f;
#pragma unroll
                for (int ni = 0; ni < 4; ++ni) {
                    float p = __expf(s[ni][r] - mnew);
                    s[ni][r] = p;
                    ps += p;
                }
                psum[r] = ps;
            }
#pragma unroll
            for (int off = 1; off < 16; off <<= 1)
#pragma unroll
                for (int r = 0; r < 4; ++r) psum[r] += __shfl_xor(psum[r], off);
#pragma unroll
            for (int r = 0; r < 4; ++r) lrow[r] = lrow[r] * corr[r] + psum[r];
#pragma unroll
            for (int nj = 0; nj < 3; ++nj)
#pragma unroll
                for (int r = 0; r < 4; ++r) o[nj][r] *= corr[r];
#pragma unroll
            for (int ni = 0; ni < 4; ++ni)
#pragma unroll
                for (int r = 0; r < 4; ++r)
                    ((__hip_bfloat16*)Ps_w)[(lhi * 4 + r) * LP + ni * 16 + llo] =
                        __float2bfloat16(s[ni][r]);
#pragma unroll
            for (int ks = 0; ks < 2; ++ks) {
                short8 pa = *(const short8*)(Ps_w + llo * LP + ks * 32 + lhi * 8);
#pragma unroll
                for (int nj = 0; nj < 3; ++nj) {
                    short8 vb = *(const short8*)(Vs_s + (nj * 16 + llo) * LV + ks * 32 + lhi * 8);
                    o[nj] = __builtin_amdgcn_mfma_f32_16x16x32_bf16(pa, vb, o[nj], 0, 0, 0);
                }
            }
        }
        __syncthreads();
    }
    // flash combine: ws=1 publishes partials, ws=0 merges + writes
    if (ws == 1) {
#pragma unroll
        for (int r = 0; r < 4; ++r) {
            int lr = lhi * 4 + r;
            if (llo == 0) { Lm[wq][lr] = mrow[r]; Ll[wq][lr] = lrow[r]; }
#pragma unroll
            for (int nj = 0; nj < 3; ++nj) {
                int d = nj * 16 + llo;
                if (d < DKK) Lo[wq][lr][d] = o[nj][r];
            }
        }
    }
    __syncthreads();
    if (ws == 0) {
#pragma unroll
        for (int r = 0; r < 4; ++r) {
            int lr = lhi * 4 + r;
            float m1 = Lm[wq][lr], l1 = Ll[wq][lr];
            float m = fmaxf(mrow[r], m1);
            float a0 = __expf(mrow[r] - m), a1 = __expf(m1 - m);
            float linv = 1.f / (lrow[r] * a0 + l1 * a1);
            int q = qrow + r;
            if (q < SS) {
#pragma unroll
                for (int nj = 0; nj < 3; ++nj) {
                    int d = nj * 16 + llo;
                    if (d < DKK)
                        AO[((size_t)b * SS + q) * DD + h * DKK + d] =
                            __float2bfloat16((o[nj][r] * a0 + Lo[wq][lr][d] * a1) * linv);
                }
            }
        }
    }
}

// ---------------- row LayerNorm: ln((a + a2? + cb? + add?)) ----------------
__global__ __launch_bounds__(320) void ln_kernel(const float* __restrict__ a,
                                                 const float* __restrict__ a2,
                                                 const float* __restrict__ cb,
                                                 const float* __restrict__ add,
                                                 const float* __restrict__ g,
                                                 const float* __restrict__ bta,
                                                 float* __restrict__ out,
                                                 __hip_bfloat16* __restrict__ outb) {
    const int row = blockIdx.x, i = threadIdx.x;
    __shared__ float red[320];
    __shared__ float s_m, s_v;
    float v = a[row * DD + i];
    if (a2) v += a2[row * DD + i];
    if (cb) v += cb[i];
    if (add) v += add[row * DD + i];
    red[i] = v;
    __syncthreads();
    if (i < 64) red[i] += red[i + 256];
    __syncthreads();
    for (int s = 128; s > 0; s >>= 1) {
        if (i < s) red[i] += red[i + s];
        __syncthreads();
    }
    if (i == 0) s_m = red[0] * (1.0f / DD);
    __syncthreads();
    const float d = v - s_m;
    red[i] = d * d;
    __syncthreads();
    if (i < 64) red[i] += red[i + 256];
    __syncthreads();
    for (int s = 128; s > 0; s >>= 1) {
        if (i < s) red[i] += red[i + s];
        __syncthreads();
    }
    if (i == 0) s_v = red[0] * (1.0f / DD);
    __syncthreads();
    float o = d * rsqrtf(s_v + 1e-5f) * g[i] + bta[i];
    out[row * DD + i] = o;
    outb[row * DD + i] = __float2bfloat16(o);
}

// ---------------- mean stage 1: partial sums over 150-row chunks ----------------
__global__ __launch_bounds__(256) void mpart_kernel(const float* __restrict__ xs,
                                                    float* __restrict__ mp) {
    const int b = blockIdx.y, z = blockIdx.z;
    const int d = blockIdx.x * 64 + (threadIdx.x & 63);
    const int rg = threadIdx.x >> 6;
    float s = 0.f;
    const int t0 = z * 150;
    for (int t = t0 + rg; t < t0 + 150; t += 4) s += xs[((size_t)b * SS + t) * DD + d];
    __shared__ float red[256];
    red[threadIdx.x] = s;
    __syncthreads();
    if (threadIdx.x < 128) red[threadIdx.x] += red[threadIdx.x + 128];
    __syncthreads();
    if (threadIdx.x < 64) mp[((size_t)b * 6 + z) * DD + d] = red[threadIdx.x] + red[threadIdx.x + 64];
}

// ---------------- transform params (reads 6 mean partials) ----------------
__global__ __launch_bounds__(64) void tp_kernel(const float* __restrict__ mp,
                                                const float* __restrict__ wrot, const float* __restrict__ brot,
                                                const float* __restrict__ wrefl, const float* __restrict__ brefl,
                                                const float* __restrict__ wtr, const float* __restrict__ btr,
                                                const float* __restrict__ wsc, const float* __restrict__ bsc,
                                                float* __restrict__ tp) {
    const int b = blockIdx.x, tid = threadIdx.x;
    __shared__ float gs[DD];
    __shared__ float raw[17];
    for (int j = tid; j < DD; j += 64) {
        float s6 = 0.f;
#pragma unroll
        for (int z = 0; z < 6; ++z) s6 += mp[((size_t)b * 6 + z) * DD + j];
        gs[j] = s6 * (1.0f / SS);
    }
    __syncthreads();
    if (tid < 17) {
        float s;
        if (tid < 4) {
            s = brot[tid];
            for (int d = 0; d < DD; ++d) s = fmaf(gs[d], wrot[d * 4 + tid], s);
        } else if (tid < 12) {
            int j = tid - 4;
            s = brefl[j];
            for (int d = 0; d < DD; ++d) s = fmaf(gs[d], wrefl[d * 8 + j], s);
        } else if (tid < 14) {
            int j = tid - 12;
            s = btr[j];
            for (int d = 0; d < DD; ++d) s = fmaf(gs[d], wtr[d * 2 + j], s);
        } else {
            int j = tid - 14;
            s = bsc[j];
            for (int d = 0; d < DD; ++d) s = fmaf(gs[d], wsc[d * 3 + j], s);
        }
        raw[tid] = s;
    }
    __syncthreads();
    if (tid == 0) {
        float mx = -1e30f;
        for (int j = 0; j < 4; ++j) mx = fmaxf(mx, raw[j]);
        float sm = 0.f, e[4];
        for (int j = 0; j < 4; ++j) { e[j] = expf(raw[j] - mx); sm += e[j]; }
        for (int j = 0; j < 4; ++j) tp[b * 17 + j] = e[j] / sm;
    } else if (tid == 1) {
        float mx = -1e30f;
        for (int j = 4; j < 12; ++j) mx = fmaxf(mx, raw[j]);
        float sm = 0.f, e[8];
        for (int j = 0; j < 8; ++j) { e[j] = expf(raw[4 + j] - mx); sm += e[j]; }
        for (int j = 0; j < 8; ++j) tp[b * 17 + 4 + j] = e[j] / sm;
    } else if (tid == 2) {
        tp[b * 17 + 12] = tanhf(raw[12]);
        tp[b * 17 + 13] = tanhf(raw[13]);
    } else if (tid == 3) {
        float mx = -1e30f;
        for (int j = 14; j < 17; ++j) mx = fmaxf(mx, raw[j]);
        float sm = 0.f, e[3];
        for (int j = 0; j < 3; ++j) { e[j] = expf(raw[14 + j] - mx); sm += e[j]; }
        for (int j = 0; j < 3; ++j) tp[b * 17 + 14 + j] = e[j] / sm;
    }
}

// ---------------- concat xs(bf16) + tp -> TIbf [3600, 384] ----------------
__global__ void concat_kernel(const __hip_bfloat16* __restrict__ xb, const float* __restrict__ tp,
                              __hip_bfloat16* __restrict__ ti) {
    int idx = blockIdx.x * 256 + threadIdx.x;
    if (idx >= BS * 384) return;
    int m = idx / 384, j = idx % 384;
    __hip_bfloat16 v;
    if (j < DD) v = xb[m * DD + j];
    else if (j < 337) v = __float2bfloat16(tp[(m / SS) * 17 + (j - DD)]);
    else v = __float2bfloat16(0.f);
    ti[idx] = v;
}

static inline void launch_mgemm(hipStream_t s, const __hip_bfloat16* A, int lda,
                                const __hip_bfloat16* Wt, int ldw, const float* bias,
                                const float* biasB, const float* biasC,
                                const float* res, int ldr, float alpha, float* Cf,
                                __hip_bfloat16* Cb, int ldc, int M, int N, int K, int act) {
    dim3 g((N + 63) / 64, (M + 127) / 128);
    mgemm_kernel<<<g, 256, 0, s>>>(A, lda, Wt, ldw, bias, biasB, biasC, res, ldr, alpha,
                                   Cf, nullptr, Cb, ldc, M, N, K, act);
}

extern "C" void kernel_launch(void* const* d_in, const int* in_sizes, int n_in,
                              void* d_out, int out_size, void* d_ws, size_t ws_size,
                              hipStream_t stream) {
    (void)in_sizes; (void)n_in; (void)out_size; (void)ws_size;
    const int* in_grid = (const int*)d_in[0];
    const float* pe = (const float*)d_in[1];
    const float* iew = (const float*)d_in[2];
    const float* ieb = (const float*)d_in[3];
    const float* wq = (const float*)d_in[4], *bq = (const float*)d_in[5];
    const float* wk = (const float*)d_in[6], *bk = (const float*)d_in[7];
    const float* wv = (const float*)d_in[8], *bv = (const float*)d_in[9];
    const float* wo = (const float*)d_in[10], *bo = (const float*)d_in[11];
    const float* lnag = (const float*)d_in[12], *lnab = (const float*)d_in[13];
    const float* dist_emb = (const float*)d_in[14], *dir_emb = (const float*)d_in[15];
    const float* wrot = (const float*)d_in[16], *brot = (const float*)d_in[17];
    const float* wrefl = (const float*)d_in[18], *brefl = (const float*)d_in[19];
    const float* wtr = (const float*)d_in[20], *btr = (const float*)d_in[21];
    const float* wsc = (const float*)d_in[22], *bsc = (const float*)d_in[23];
    const float* tnw1 = (const float*)d_in[24], *tnb1 = (const float*)d_in[25];
    const float* tnw2 = (const float*)d_in[26], *tnb2 = (const float*)d_in[27];
    const float* tnw3 = (const float*)d_in[28], *tnb3 = (const float*)d_in[29];
    const float* ffw1 = (const float*)d_in[30], *ffb1 = (const float*)d_in[31];
    const float* ffw2 = (const float*)d_in[32], *ffb2 = (const float*)d_in[33];
    const float* ln2g = (const float*)d_in[34], *ln2b = (const float*)d_in[35];
    const float* ck1 = (const float*)d_in[36], *cb1 = (const float*)d_in[37];
    const float* ck3 = (const float*)d_in[38], *cb3 = (const float*)d_in[39];
    const float* ck5 = (const float*)d_in[40], *cb5 = (const float*)d_in[41];
    const float* ck7 = (const float*)d_in[42], *cb7 = (const float*)d_in[43];
    const float* fusw = (const float*)d_in[44], *fusb = (const float*)d_in[45];
    const float* opw1 = (const float*)d_in[46], *opb1 = (const float*)d_in[47];
    const float* opw2 = (const float*)d_in[48], *opb2 = (const float*)d_in[49];
    const float* opw3 = (const float*)d_in[50], *opb3 = (const float*)d_in[51];
    const int* dist_idx = (const int*)d_in[52];
    const int* dir_idx = (const int*)d_in[53];
    float* out = (float*)d_out;

    // ---- workspace arena (byte offsets) ----
    char* base = (char*)d_ws;
    typedef __hip_bfloat16 bf;
    bf* WQKVT = (bf*)(base + 0);          // [4][960][320]
    bf* WOT = (bf*)(base + 2457600);
    bf* TN1T = (bf*)(base + 3276800);
    bf* TN2T = (bf*)(base + 5242880);
    bf* TN3T = (bf*)(base + 6881280);
    bf* FF1T = (bf*)(base + 7700480);
    bf* FF2T = (bf*)(base + 10977280);
    bf* CK1T = (bf*)(base + 14254080);
    bf* CK3T = (bf*)(base + 14458880);
    bf* CK5T = (bf*)(base + 16302080);
    bf* CK7T = (bf*)(base + 21422080);
    bf* FUST = (bf*)(base + 31457280);
    bf* OP1T = (bf*)(base + 32276480);
    float* XS = (float*)(base + 32378880);
    bf* XSbf = (bf*)(base + 36986880);
    bf* QKVbf = (bf*)(base + 39290880);   // [3600][960], ends 46,202,880
    bf* VT = (bf*)(base + 46202880);      // ends 49,152,000
    float* P1f = (float*)(base + 39290880);  // ff2 K-split partial (QKV region, dead post-attn)
    float* R2 = (float*)(base + 53114880);
    float* TP = (float*)(base + 57728000);
    // conv bf16 partials: [7][3600][320] bf16 = 16,128,000 B in dead QKV..R2 region
    bf* CPART = (bf*)(base + 39290880);
    char* BIG = base + 57728512;
    bf* AObf = (bf*)(BIG + 0);
    float* MPart = (float*)(BIG + 0);     // [4][6][320] f32, mean partials (AObf dead; pre-concat)
    bf* BIAS = (bf*)(BIG + 2764800);
    bf* TIbf = (bf*)(BIG + 0);
    bf* T1bf = (bf*)(BIG + 2764800);
    bf* T2bf = (bf*)(BIG + 7372800);
    bf* F1bf = (bf*)(BIG + 0);
    bf* PADbf = (bf*)(BIG + 0);
    bf* FEATSbf = (bf*)(BIG + 3317760);
    float* H1 = (float*)(BIG + 0);
    float* H2 = (float*)(BIG + 2304000);
    bf* R2bf = XSbf;

    dim3 cb(32, 8);
    qkvconvt_kernel<<<dim3(10, 10, 12), cb, 0, stream>>>(wq, wk, wv, WQKVT);
    allconvt_kernel<<<14610, cb, 0, stream>>>(wo, tnw1, tnw2, tnw3, ffw1, ffw2,
                                              ck1, ck3, ck5, ck7, fusw, opw1,
                                              WOT, TN1T, TN2T, TN3T, FF1T, FF2T,
                                              CK1T, CK3T, CK5T, CK7T, FUST, OP1T);

    embed_kernel<<<4500, 256, 0, stream>>>(in_grid, pe, iew, ieb, XS, XSbf);

    for (int l = 0; l < LL; ++l) {
        const int wO = l * DD * DD, bO = l * DD;
        // fused QKV projection: N=960
        launch_mgemm(stream, XSbf, DD, WQKVT + l * 307200, 320, bq + bO, bk + bO, bv + bO,
                     nullptr, 0, 1.f, nullptr, QKVbf, 960, BS, 960, 320, 0);
        attprep_kernel<<<32760, 256, 0, stream>>>(dist_emb + l * 60 * NHH, dir_emb + l * 8 * NHH,
                                                  dist_idx, dir_idx, QKVbf, BIAS, VT);
        mattn_kernel<<<dim3(15, NHH, BB), 512, 0, stream>>>(QKVbf, QKVbf + 320, VT, BIAS, AObf);
        launch_mgemm(stream, AObf, DD, WOT + wO, DD, bo + bO, nullptr, nullptr, XS, DD, 1.f,
                     R2, nullptr, DD, BS, DD, DD, 0);
        ln_kernel<<<BS, 320, 0, stream>>>(R2, nullptr, nullptr, nullptr, lnag + bO, lnab + bO, XS, XSbf);
        mpart_kernel<<<dim3(5, BB, 6), 256, 0, stream>>>(XS, MPart);
        tp_kernel<<<BB, 64, 0, stream>>>(MPart, wrot + l * 1280, brot + l * 4,
                                         wrefl + l * 2560, brefl + l * 8,
                                         wtr + l * 640, btr + l * 2,
                                         wsc + l * 960, bsc + l * 3, TP);
        concat_kernel<<<(BS * 384 + 255) / 256, 256, 0, stream>>>(XSbf, TP, TIbf);
        launch_mgemm(stream, TIbf, 384, TN1T + l * 245760, 384, tnb1 + l * 640, nullptr, nullptr,
                     nullptr, 0, 1.f, nullptr, T1bf, 640, BS, 640, 384, 1);
        launch_mgemm(stream, T1bf, 640, TN2T + l * 204800, 640, tnb2 + bO, nullptr, nullptr,
                     nullptr, 0, 1.f, nullptr, T2bf, DD, BS, DD, 640, 1);
        launch_mgemm(stream, T2bf, DD, TN3T + wO, DD, tnb3 + bO, nullptr, nullptr, XS, DD, 0.3f,
                     XS, XSbf, DD, BS, DD, DD, 0);
        launch_mgemm(stream, XSbf, DD, FF1T + l * 409600, DD, ffb1 + l * FFD, nullptr, nullptr,
                     nullptr, 0, 1.f, nullptr, F1bf, FFD, BS, FFD, DD, 1);
        // ff2 split-K: z=0 -> R2 (K rows 0..639), z=1 -> P1f (rows 640..1279); merged in ln
        {
            dim3 g(5, 29, 2);
            mgemm_kernel<<<g, 256, 0, stream>>>(F1bf, FFD, FF2T + l * 409600, FFD,
                                                nullptr, nullptr, nullptr, nullptr, 0, 1.f,
                                                R2, P1f, nullptr, DD, BS, DD, 640, 0);
        }
        ln_kernel<<<BS, 320, 0, stream>>>(R2, P1f, ffb2 + bO, XS, ln2g + bO, ln2b + bO, XS, XSbf);
    }

    // ---- multiscale convs: per-kh bf16 partials + reduce (x=M-tiles for W locality) ----
    pad_kernel<<<(BB * 36 * 36 * DD + 255) / 256, 256, 0, stream>>>(XSbf, PADbf);
    launch_mgemm(stream, XSbf, DD, CK1T, DD, cb1, nullptr, nullptr, nullptr, 0, 1.f,
                 nullptr, FEATSbf + 0, 1280, BS, DD, DD, 2);
    const int RED = (BS * DD / 8 + 255) / 256;
    mconv_kernel<3><<<dim3(29, 5, 3), 256, 0, stream>>>(PADbf, CK3T, CPART, 1);
    creduce_kernel<<<RED, 256, 0, stream>>>(CPART, 3, cb3, FEATSbf + 320, 1280);
    mconv_kernel<5><<<dim3(29, 5, 5), 256, 0, stream>>>(PADbf, CK5T, CPART, 1);
    creduce_kernel<<<RED, 256, 0, stream>>>(CPART, 5, cb5, FEATSbf + 640, 1280);
    mconv_kernel<7><<<dim3(29, 5, 7), 256, 0, stream>>>(PADbf, CK7T, CPART, 1);
    creduce_kernel<<<RED, 256, 0, stream>>>(CPART, 7, cb7, FEATSbf + 960, 1280);
    launch_mgemm(stream, FEATSbf, 1280, FUST, 1280, fusb, nullptr, nullptr, nullptr, 0, 1.f,
                 nullptr, R2bf, DD, BS, DD, 1280, 0);
    // ---- output head ----
    launch_mgemm(stream, R2bf, DD, OP1T, DD, opb1, nullptr, nullptr, nullptr, 0, 1.f,
                 H1, nullptr, 160, BS, 160, DD, 1);
    gemm_kernel<<<dim3(2, 57), 256, 0, stream>>>(H1, 160, opw2, opb2, H2, 80, BS, 80, 160, 1);
    gemm_kernel<<<dim3(1, 57), 256, 0, stream>>>(H2, 80, opw3, opb3, out, 10, BS, 10, 80, 0);
}

// Round 10
// 1560.024 us; speedup vs baseline: 7.0816x; 1.0319x over previous
//
#include <hip/hip_runtime.h>
#include <hip/hip_bf16.h>

#define BB 4
#define GG_ 30
#define DD 320
#define LL 4
#define NHH 8
#define DKK 40
#define SS 900
#define BS 3600
#define FFD 1280
#define LDK 72   // BK(64) + 8 pad, in bf16 elems -> 144B row stride, 16B aligned

typedef __attribute__((ext_vector_type(8))) short short8;
typedef __attribute__((ext_vector_type(4))) short short4v;
typedef __attribute__((ext_vector_type(4))) float f32x4;

__device__ __forceinline__ float gelu_f(float x) {
    return 0.5f * x * (1.0f + erff(x * 0.70710678118654752f));
}

__device__ __forceinline__ float bfbits2f(short b) {
    return __uint_as_float(((unsigned)(unsigned short)b) << 16);
}

// ---------------- shared convt tile body ----------------
__device__ __forceinline__ void convt_tile(const float* __restrict__ s,
                                           __hip_bfloat16* __restrict__ d,
                                           int K, int N, int Kpad, int kb, int nb) {
    __shared__ float t[32][33];
    const int tx = threadIdx.x, ty = threadIdx.y;   // (32, 8)
#pragma unroll
    for (int i = 0; i < 4; ++i) {
        int k = kb + ty + i * 8, n = nb + tx;
        t[ty + i * 8][tx] = (k < K && n < N) ? s[(size_t)k * N + n] : 0.f;
    }
    __syncthreads();
#pragma unroll
    for (int i = 0; i < 4; ++i) {
        int n = nb + ty + i * 8, k = kb + tx;
        if (n < N && k < Kpad) d[(size_t)n * Kpad + k] = __float2bfloat16(t[tx][ty + i * 8]);
    }
}

// ---------------- ALL weight transposes in one launch (14610 blocks) ----------------
__global__ __launch_bounds__(256) void allconvt_kernel(
    const float* wo, const float* tnw1, const float* tnw2, const float* tnw3,
    const float* ffw1, const float* ffw2, const float* ck1, const float* ck3,
    const float* ck5, const float* ck7, const float* fusw, const float* opw1,
    __hip_bfloat16* WOT, __hip_bfloat16* TN1T, __hip_bfloat16* TN2T, __hip_bfloat16* TN3T,
    __hip_bfloat16* FF1T, __hip_bfloat16* FF2T, __hip_bfloat16* CK1T, __hip_bfloat16* CK3T,
    __hip_bfloat16* CK5T, __hip_bfloat16* CK7T, __hip_bfloat16* FUST, __hip_bfloat16* OP1T) {
    const int bid = blockIdx.x;
    const float* s; __hip_bfloat16* d;
    int K, N, Kpad, gx, per, local, sS, dS;
    if (bid < 400)        { local = bid;         s = wo;   d = WOT;  K = 320;  N = 320;  Kpad = 320;  sS = 102400; dS = 102400; gx = 10;  per = 100; }
    else if (bid < 1360)  { local = bid - 400;   s = tnw1; d = TN1T; K = 337;  N = 640;  Kpad = 384;  sS = 215680; dS = 245760; gx = 12;  per = 240; }
    else if (bid < 2160)  { local = bid - 1360;  s = tnw2; d = TN2T; K = 640;  N = 320;  Kpad = 640;  sS = 204800; dS = 204800; gx = 20;  per = 200; }
    else if (bid < 2560)  { local = bid - 2160;  s = tnw3; d = TN3T; K = 320;  N = 320;  Kpad = 320;  sS = 102400; dS = 102400; gx = 10;  per = 100; }
    else if (bid < 4160)  { local = bid - 2560;  s = ffw1; d = FF1T; K = 320;  N = 1280; Kpad = 320;  sS = 409600; dS = 409600; gx = 10;  per = 400; }
    else if (bid < 5760)  { local = bid - 4160;  s = ffw2; d = FF2T; K = 1280; N = 320;  Kpad = 1280; sS = 409600; dS = 409600; gx = 40;  per = 400; }
    else if (bid < 5860)  { local = bid - 5760;  s = ck1;  d = CK1T; K = 320;  N = 320;  Kpad = 320;  sS = 0; dS = 0; gx = 10;  per = 100; }
    else if (bid < 6760)  { local = bid - 5860;  s = ck3;  d = CK3T; K = 2880; N = 320;  Kpad = 2880; sS = 0; dS = 0; gx = 90;  per = 900; }
    else if (bid < 9260)  { local = bid - 6760;  s = ck5;  d = CK5T; K = 8000; N = 320;  Kpad = 8000; sS = 0; dS = 0; gx = 250; per = 2500; }
    else if (bid < 14160) { local = bid - 9260;  s = ck7;  d = CK7T; K = 15680; N = 320; Kpad = 15680; sS = 0; dS = 0; gx = 490; per = 4900; }
    else if (bid < 14560) { local = bid - 14160; s = fusw; d = FUST; K = 1280; N = 320;  Kpad = 1280; sS = 0; dS = 0; gx = 40;  per = 400; }
    else                  { local = bid - 14560; s = opw1; d = OP1T; K = 320;  N = 160;  Kpad = 320;  sS = 0; dS = 0; gx = 10;  per = 50; }
    const int mat = local / per, rem = local - mat * per;
    const int kb = (rem % gx) * 32, nb = (rem / gx) * 32;
    convt_tile(s + (size_t)mat * sS, d + (size_t)mat * dS, K, N, Kpad, kb, nb);
}

// ---------------- packed QKV weight convert: [L][960][320] bf16 ----------------
__global__ __launch_bounds__(256) void qkvconvt_kernel(const float* __restrict__ wq,
                                                       const float* __restrict__ wk,
                                                       const float* __restrict__ wv,
                                                       __hip_bfloat16* __restrict__ dst) {
    __shared__ float t[32][33];
    const int z = blockIdx.z, l = z / 3, wsel = z % 3;
    const float* s = (wsel == 0 ? wq : wsel == 1 ? wk : wv) + (size_t)l * 102400;
    __hip_bfloat16* d = dst + (size_t)l * 307200 + wsel * 102400;
    const int kb = blockIdx.x * 32, nb = blockIdx.y * 32;
    const int tx = threadIdx.x, ty = threadIdx.y;   // (32, 8)
#pragma unroll
    for (int i = 0; i < 4; ++i) {
        int k = kb + ty + i * 8, n = nb + tx;
        t[ty + i * 8][tx] = s[(size_t)k * 320 + n];
    }
    __syncthreads();
#pragma unroll
    for (int i = 0; i < 4; ++i) {
        int n = nb + ty + i * 8, k = kb + tx;
        d[(size_t)n * 320 + k] = __float2bfloat16(t[tx][ty + i * 8]);
    }
}

// ---------------- embed ----------------
__global__ void embed_kernel(const int* __restrict__ grid, const float* __restrict__ pe,
                             const float* __restrict__ ew, const float* __restrict__ eb,
                             float* __restrict__ x, __hip_bfloat16* __restrict__ xb) {
    int idx = blockIdx.x * 256 + threadIdx.x;   // < 1,152,000
    int m = idx / DD, d = idx % DD;
    int gv = grid[m];
    float v = ew[gv * DD + d] + eb[d] + pe[(m % SS) * DD + d];
    x[idx] = v;
    xb[idx] = __float2bfloat16(v);
}

// ---------------- MFMA bf16 GEMM (proven 128x64 body; 3-way bias; optional K-split z) ----------------
__global__ __launch_bounds__(256) void mgemm_kernel(
    const __hip_bfloat16* __restrict__ A, int lda,
    const __hip_bfloat16* __restrict__ Wt, int ldw,
    const float* __restrict__ bias, const float* __restrict__ biasB, const float* __restrict__ biasC,
    const float* __restrict__ res, int ldr,
    float alpha, float* __restrict__ Cf, float* __restrict__ Cf2,
    __hip_bfloat16* __restrict__ Cb, int ldc,
    int M, int N, int K, int act) {
    __shared__ short As[128 * LDK];
    __shared__ short Bs[64 * LDK];
    const int tid = threadIdx.x;
    const int m0 = blockIdx.y * 128, n0 = blockIdx.x * 64;
    const int kb0 = blockIdx.z * K;                 // K-split offset (z=0 for normal calls)
    float* __restrict__ CfO = (blockIdx.z == 0) ? Cf : Cf2;
    const int lane = tid & 63;
    const int w = tid >> 6, wm = w >> 1, wn = w & 1;
    const int rbase = tid >> 3, q8 = (tid & 7) * 8;
    f32x4 acc[4][2];
    const f32x4 fz = {0.f, 0.f, 0.f, 0.f};
#pragma unroll
    for (int mi = 0; mi < 4; ++mi)
#pragma unroll
        for (int ni = 0; ni < 2; ++ni) acc[mi][ni] = fz;
    const short8 zz = {0, 0, 0, 0, 0, 0, 0, 0};
    for (int k0 = 0; k0 < K; k0 += 64) {
#pragma unroll
        for (int c = 0; c < 4; ++c) {
            int r = c * 32 + rbase, m = m0 + r;
            short8 v = zz;
            if (m < M) v = *(const short8*)((const short*)A + (size_t)m * lda + kb0 + k0 + q8);
            *(short8*)(As + r * LDK + q8) = v;
        }
#pragma unroll
        for (int c = 0; c < 2; ++c) {
            int r = c * 32 + rbase, n = n0 + r;
            short8 v = zz;
            if (n < N) v = *(const short8*)((const short*)Wt + (size_t)n * ldw + kb0 + k0 + q8);
            *(short8*)(Bs + r * LDK + q8) = v;
        }
        __syncthreads();
#pragma unroll
        for (int ks = 0; ks < 64; ks += 32) {
            const int kb = ks + (lane >> 4) * 8;
            short8 af[4], bf[2];
#pragma unroll
            for (int mi = 0; mi < 4; ++mi)
                af[mi] = *(const short8*)(As + (wm * 64 + mi * 16 + (lane & 15)) * LDK + kb);
#pragma unroll
            for (int ni = 0; ni < 2; ++ni)
                bf[ni] = *(const short8*)(Bs + (wn * 32 + ni * 16 + (lane & 15)) * LDK + kb);
#pragma unroll
            for (int mi = 0; mi < 4; ++mi)
#pragma unroll
                for (int ni = 0; ni < 2; ++ni)
                    acc[mi][ni] = __builtin_amdgcn_mfma_f32_16x16x32_bf16(af[mi], bf[ni], acc[mi][ni], 0, 0, 0);
        }
        __syncthreads();
    }
    const int col0 = n0 + wn * 32 + (lane & 15);
    const int rloc = (lane >> 4) * 4;
#pragma unroll
    for (int mi = 0; mi < 4; ++mi) {
#pragma unroll
        for (int ni = 0; ni < 2; ++ni) {
            int col = col0 + ni * 16;
            if (col >= N) continue;
            float bv;
            if (biasC) bv = (col < 320) ? bias[col] : (col < 640) ? biasB[col - 320] : biasC[col - 640];
            else bv = bias ? bias[col] : 0.f;
#pragma unroll
            for (int r = 0; r < 4; ++r) {
                int row = m0 + wm * 64 + mi * 16 + rloc + r;
                if (row >= M) continue;
                float v = acc[mi][ni][r] + bv;
                if (act == 1) v = gelu_f(v);
                else if (act == 2) v = fmaxf(v, 0.f);
                v *= alpha;
                if (res) v += res[(size_t)row * ldr + col];
                if (CfO) CfO[(size_t)row * ldc + col] = v;
                if (Cb) Cb[(size_t)row * ldc + col] = __float2bfloat16(v);
            }
        }
    }
}

// ---------------- MFMA conv (128x64 body + kh-split + XCD-aware block swizzle) ----------------
// grid (29, 5, NZ); work id remapped so each XCD owns contiguous (N-tile, kh) slices.
template <int KS>
__global__ __launch_bounds__(256) void mconv_kernel(
    const __hip_bfloat16* __restrict__ P, const __hip_bfloat16* __restrict__ Wt,
    __hip_bfloat16* __restrict__ part, int kh0step) {
    const int K = KS * KS * DD;
    const int OFF = 3 - KS / 2;
    // --- XCD-aware bijective swizzle (m204): hw id -> work id ---
    const int nwg = 145 * gridDim.z;
    const int ib = blockIdx.x + 29 * (blockIdx.y + 5 * blockIdx.z);
    const int xcd = ib & 7, kk2 = ib >> 3;
    const int qq = nwg >> 3, rr = nwg & 7;
    const int wid = (xcd < rr) ? (xcd * (qq + 1) + kk2) : (rr * (qq + 1) + (xcd - rr) * qq + kk2);
    const int mt = wid % 29, rest = wid / 29;
    const int nt = rest % 5, zt = rest / 5;
    const int kh0 = zt * kh0step;
    const int nkh = (KS - kh0 < kh0step) ? (KS - kh0) : kh0step;
    const int Ksub = nkh * KS * DD;          // multiples of 64 for KS in {3,5,7}
    const int wbase = kh0 * KS * DD;
    __hip_bfloat16* __restrict__ Cp = part + (size_t)zt * BS * DD;
    __shared__ short As[128 * LDK];
    __shared__ short Bs[64 * LDK];
    const int tid = threadIdx.x;
    const int m0 = mt * 128, n0 = nt * 64;
    const int lane = tid & 63;
    const int w = tid >> 6, wm = w >> 1, wn = w & 1;
    const int rbase = tid >> 3, q8 = (tid & 7) * 8;
    f32x4 acc[4][2];
    const f32x4 fz = {0.f, 0.f, 0.f, 0.f};
#pragma unroll
    for (int mi = 0; mi < 4; ++mi)
#pragma unroll
        for (int ni = 0; ni < 2; ++ni) acc[mi][ni] = fz;
    const short8 zz = {0, 0, 0, 0, 0, 0, 0, 0};
    for (int k0 = 0; k0 < Ksub; k0 += 64) {
#pragma unroll
        for (int c = 0; c < 4; ++c) {
            int r = c * 32 + rbase, m = m0 + r;
            int k = k0 + q8;
            int ci = k % DD, t = k / DD;
            int kw = t % KS, kh = kh0 + t / KS;
            short8 v = zz;
            if (m < BS) {
                int b = m / SS, hw = m % SS, oh = hw / GG_, ow = hw % GG_;
                int ih = oh + kh + OFF, iw = ow + kw + OFF;
                v = *(const short8*)((const short*)P + (((b * 36 + ih) * 36 + iw) * DD + ci));
            }
            *(short8*)(As + r * LDK + q8) = v;
        }
#pragma unroll
        for (int c = 0; c < 2; ++c) {
            int r = c * 32 + rbase, n = n0 + r;
            short8 v = *(const short8*)((const short*)Wt + (size_t)n * K + wbase + k0 + q8);
            *(short8*)(Bs + r * LDK + q8) = v;
        }
        __syncthreads();
#pragma unroll
        for (int ks = 0; ks < 64; ks += 32) {
            const int kb = ks + (lane >> 4) * 8;
            short8 af[4], bf[2];
#pragma unroll
            for (int mi = 0; mi < 4; ++mi)
                af[mi] = *(const short8*)(As + (wm * 64 + mi * 16 + (lane & 15)) * LDK + kb);
#pragma unroll
            for (int ni = 0; ni < 2; ++ni)
                bf[ni] = *(const short8*)(Bs + (wn * 32 + ni * 16 + (lane & 15)) * LDK + kb);
#pragma unroll
            for (int mi = 0; mi < 4; ++mi)
#pragma unroll
                for (int ni = 0; ni < 2; ++ni)
                    acc[mi][ni] = __builtin_amdgcn_mfma_f32_16x16x32_bf16(af[mi], bf[ni], acc[mi][ni], 0, 0, 0);
        }
        __syncthreads();
    }
    const int col0 = n0 + wn * 32 + (lane & 15);
    const int rloc = (lane >> 4) * 4;
#pragma unroll
    for (int mi = 0; mi < 4; ++mi) {
#pragma unroll
        for (int ni = 0; ni < 2; ++ni) {
            int col = col0 + ni * 16;
#pragma unroll
            for (int r = 0; r < 4; ++r) {
                int row = m0 + wm * 64 + mi * 16 + rloc + r;
                if (row < BS) Cp[(size_t)row * DD + col] = __float2bfloat16(acc[mi][ni][r]);
            }
        }
    }
}

// ---------------- conv partial reduce: relu(sum bf16 parts + bias) -> bf16 @ldc ----------------
__global__ __launch_bounds__(256) void creduce_kernel(const __hip_bfloat16* __restrict__ part,
                                                      int nsplit, const float* __restrict__ bias,
                                                      __hip_bfloat16* __restrict__ outb, int ldc) {
    int idx = blockIdx.x * 256 + threadIdx.x;      // over BS*DD/8 groups of 8 cols
    if (idx >= BS * DD / 8) return;
    int row = idx / (DD / 8), c8 = (idx % (DD / 8)) * 8;
    float s[8] = {};
    for (int p = 0; p < nsplit; ++p) {
        short8 v = *(const short8*)((const short*)part + (size_t)p * BS * DD + (size_t)row * DD + c8);
#pragma unroll
        for (int j = 0; j < 8; ++j) s[j] += bfbits2f(v[j]);
    }
    __hip_bfloat16* o = outb + (size_t)row * ldc + c8;
#pragma unroll
    for (int j = 0; j < 8; ++j) o[j] = __float2bfloat16(fmaxf(s[j] + bias[c8 + j], 0.f));
}

// ---------------- pad bf16 image for convs ----------------
__global__ void pad_kernel(const __hip_bfloat16* __restrict__ xb, __hip_bfloat16* __restrict__ p) {
    int idx = blockIdx.x * 256 + threadIdx.x;   // 4*36*36*320
    if (idx >= BB * 36 * 36 * DD) return;
    int c = idx % DD, t = idx / DD;
    int wp = t % 36, t2 = t / 36, hp = t2 % 36, b = t2 / 36;
    __hip_bfloat16 v = __float2bfloat16(0.f);
    if (hp >= 3 && hp < 33 && wp >= 3 && wp < 33)
        v = xb[((b * SS + (hp - 3) * GG_ + (wp - 3))) * DD + c];
    p[idx] = v;
}

// ---------------- legacy fp32 GEMM (tiny op heads) ----------------
__global__ __launch_bounds__(256) void gemm_kernel(
    const float* __restrict__ A, int lda, const float* __restrict__ W,
    const float* __restrict__ bias, float* __restrict__ C, int ldc,
    int M, int N, int K, int act) {
    __shared__ float As[16][65];
    __shared__ float Ws[16][65];
    const int tid = threadIdx.x;
    const int m0 = blockIdx.y * 64, n0 = blockIdx.x * 64;
    const int tx = tid & 15, ty = tid >> 4;
    float acc[4][4] = {};
    const int kkA = tid & 15, mloc0 = tid >> 4;
    const int nloc = tid & 63, kk0 = tid >> 6;
    for (int k0 = 0; k0 < K; k0 += 16) {
        const int kA = k0 + kkA;
#pragma unroll
        for (int i = 0; i < 4; ++i) {
            int mloc = mloc0 + i * 16, m = m0 + mloc;
            As[kkA][mloc] = (m < M && kA < K) ? A[m * lda + kA] : 0.f;
        }
#pragma unroll
        for (int i = 0; i < 4; ++i) {
            int kk = kk0 + i * 4, k = k0 + kk, n = n0 + nloc;
            Ws[kk][nloc] = (k < K && n < N) ? W[k * N + n] : 0.f;
        }
        __syncthreads();
#pragma unroll
        for (int kk = 0; kk < 16; ++kk) {
            float a[4], b[4];
#pragma unroll
            for (int i = 0; i < 4; ++i) a[i] = As[kk][ty * 4 + i];
#pragma unroll
            for (int j = 0; j < 4; ++j) b[j] = Ws[kk][tx * 4 + j];
#pragma unroll
            for (int i = 0; i < 4; ++i)
#pragma unroll
                for (int j = 0; j < 4; ++j) acc[i][j] = fmaf(a[i], b[j], acc[i][j]);
        }
        __syncthreads();
    }
#pragma unroll
    for (int i = 0; i < 4; ++i) {
        int m = m0 + ty * 4 + i;
        if (m >= M) continue;
#pragma unroll
        for (int j = 0; j < 4; ++j) {
            int n = n0 + tx * 4 + j;
            if (n >= N) continue;
            float v = acc[i][j] + bias[n];
            if (act == 1) v = gelu_f(v);
            C[m * ldc + n] = v;
        }
    }
}

// ---------------- merged attn prep v2: 8-head bias per thread + 4-elem VT ----------------
// blocks [0, 3375): BIAS for all 8 heads; blocks [3375, 4815): VT, 4 elems/thread.
__global__ __launch_bounds__(256) void attprep_kernel(const float* __restrict__ de,
                                                      const float* __restrict__ dre,
                                                      const int* __restrict__ dist,
                                                      const int* __restrict__ dirn,
                                                      const __hip_bfloat16* __restrict__ QKV,
                                                      __hip_bfloat16* __restrict__ biasOut,
                                                      __hip_bfloat16* __restrict__ VT) {
    const int gid = blockIdx.x;
    const int tid = threadIdx.x;
    if (gid < 3375) {
        int idx = gid * 256 + tid;                 // < 864000
        int sq = idx / 960, t = idx - sq * 960;
        float lut[NHH];
        if (t < SS) {
            int dv = dist[sq * SS + t], rv = dirn[sq * SS + t];
#pragma unroll
            for (int h = 0; h < NHH; ++h) lut[h] = de[dv * NHH + h] + dre[rv * NHH + h];
        } else {
#pragma unroll
            for (int h = 0; h < NHH; ++h) lut[h] = 0.f;
        }
#pragma unroll
        for (int h = 0; h < NHH; ++h)
            biasOut[((size_t)h * SS + sq) * 960 + t] = __float2bfloat16(lut[h]);
    } else {
        int vidx = (gid - 3375) * 256 + tid;       // < 368,640
        int t0 = (vidx % 240) * 4;
        int d = (vidx / 240) % 48;
        int h = (vidx / (240 * 48)) % NHH;
        int b = vidx / (240 * 48 * NHH);
        short4v v = {0, 0, 0, 0};
        if (d < DKK) {
#pragma unroll
            for (int j = 0; j < 4; ++j) {
                int t = t0 + j;
                if (t < SS)
                    v[j] = ((const short*)QKV)[((size_t)b * SS + t) * 960 + 640 + h * DKK + d];
            }
        }
        *(short4v*)((short*)VT + (((size_t)b * NHH + h) * 48 + d) * 960 + t0) = v;
    }
}

// ---------------- MFMA flash attention: 512 thr, in-block KV-split + merge ----------------
// waves 0-3 (ws=0): even kv tiles; waves 4-7 (ws=1): odd kv tiles; same 64 q rows.
#define LQ 72
#define LK 72
#define LV 72
#define LP 72
__global__ __launch_bounds__(512) void mattn_kernel(
    const __hip_bfloat16* __restrict__ Qg, const __hip_bfloat16* __restrict__ Kg,
    const __hip_bfloat16* __restrict__ VTg, const __hip_bfloat16* __restrict__ BIASg,
    __hip_bfloat16* __restrict__ AO) {
    const int qt = blockIdx.x, h = blockIdx.y, b = blockIdx.z;
    const int tid = threadIdx.x, lane = tid & 63, w = tid >> 6;
    const int wq = w & 3, ws = w >> 2;
    const int tid2 = tid & 255;
    const int lhi = lane >> 4, llo = lane & 15;
    __shared__ short Qs[64 * LQ];
    __shared__ short Ks[2][64 * LK];
    __shared__ short Vs[2][48 * LV];
    __shared__ short Ps[8][16 * LP];
    __shared__ float Lm[4][16];
    __shared__ float Ll[4][16];
    __shared__ float Lo[4][16][DKK];
    short* Ps_w = Ps[w];
    short* Ks_s = Ks[ws];
    short* Vs_s = Vs[ws];
    const int q0 = qt * 64;
    const short4v z4 = {0, 0, 0, 0};
    const f32x4 fz = {0.f, 0.f, 0.f, 0.f};
    const float scale = 0.15811388300841898f;  // 1/sqrt(40)

    // stage Q tile (64 x 64 valid region of LQ=72 rows; k in [40,64) zeroed)
    for (int task = tid; task < 64 * 16; task += 512) {
        int r = task >> 4, d0 = (task & 15) * 4;
        int q = q0 + r;
        short4v v = z4;
        if (q < SS && d0 < DKK)
            v = *(const short4v*)((const short*)Qg + ((size_t)b * SS + q) * 960 + h * DKK + d0);
        *(short4v*)(Qs + r * LQ + d0) = v;
    }
    __syncthreads();
    short8 qa[2];
#pragma unroll
    for (int ks = 0; ks < 2; ++ks)
        qa[ks] = *(const short8*)(Qs + (wq * 16 + llo) * LQ + ks * 32 + lhi * 8);

    float mrow[4] = {-1e30f, -1e30f, -1e30f, -1e30f};
    float lrow[4] = {0.f, 0.f, 0.f, 0.f};
    f32x4 o[3] = {fz, fz, fz};
    const int qrow = q0 + wq * 16 + lhi * 4;

    for (int tt = 0; tt < 8; ++tt) {
        const int t = tt * 2 + ws;
        const int kv0 = t * 64;
        if (t < 15) {
            for (int task = tid2; task < 64 * 16; task += 256) {
                int r = task >> 4, d0 = (task & 15) * 4;
                int kv = kv0 + r;
                short4v v = z4;
                if (kv < SS && d0 < DKK)
                    v = *(const short4v*)((const short*)Kg + ((size_t)b * SS + kv) * 960 + h * DKK + d0);
                *(short4v*)(Ks_s + r * LK + d0) = v;
            }
            for (int task = tid2; task < 48 * 16; task += 256) {
                int r = task >> 4, c4 = (task & 15) * 4;
                short4v v = *(const short4v*)((const short*)VTg +
                             (((size_t)b * NHH + h) * 48 + r) * 960 + kv0 + c4);
                *(short4v*)(Vs_s + r * LV + c4) = v;
            }
        }
        __syncthreads();
        if (t < 15) {
            f32x4 s[4] = {fz, fz, fz, fz};
#pragma unroll
            for (int ks = 0; ks < 2; ++ks) {
#pragma unroll
                for (int ni = 0; ni < 4; ++ni) {
                    short8 kb = *(const short8*)(Ks_s + (ni * 16 + llo) * LK + ks * 32 + lhi * 8);
                    s[ni] = __builtin_amdgcn_mfma_f32_16x16x32_bf16(qa[ks], kb, s[ni], 0, 0, 0);
                }
            }
#pragma unroll
            for (int ni = 0; ni < 4; ++ni) {
                int col = kv0 + ni * 16 + llo;
#pragma unroll
                for (int r = 0; r < 4; ++r) {
                    int qc = qrow + r; if (qc > SS - 1) qc = SS - 1;
                    float v = s[ni][r] * scale +
                              __bfloat162float(BIASg[((size_t)h * SS + qc) * 960 + col]);
                    s[ni][r] = (col < SS) ? v : -1e30f;
                }
            }
            float rmax[4], psum[4], corr[4];
#pragma unroll
            for (int r = 0; r < 4; ++r)
                rmax[r] = fmaxf(fmaxf(s[0][r], s[1][r]), fmaxf(s[2][r], s[3][r]));
#pragma unroll
            for (int off = 1; off < 16; off <<= 1)
#pragma unroll
                for (int r = 0; r < 4; ++r)
                    rmax[r] = fmaxf(rmax[r], __shfl_xor(rmax[r], off));
#pragma unroll
            for (int r = 0; r < 4; ++r) {
                float mnew = fmaxf(mrow[r], rmax[r]);
                corr[r] = __expf(mrow[r] - mnew);
                mrow[r] = mnew;
                float ps = 0.f;
#pragma unroll
                for (int ni = 0; ni < 4; ++ni) {
                    float p = __expf(s[ni][r] - mnew);
                    s[ni][r] = p;
                    ps += p;
                }
                psum[r] = ps;
            }
#pragma unroll
            for (int off = 1; off < 16; off <<= 1)
#pragma unroll
                for (int r = 0; r < 4; ++r) psum[r] += __shfl_xor(psum[r], off);
#pragma unroll
            for (int r = 0; r < 4; ++r) lrow[r] = lrow[r] * corr[r] + psum[r];
#pragma unroll
            for (int nj = 0; nj < 3; ++nj)
#pragma unroll
                for (int r = 0; r < 4; ++r) o[nj][r] *= corr[r];
#pragma unroll
            for (int ni = 0; ni < 4; ++ni)
#pragma unroll
                for (int r = 0; r < 4; ++r)
                    ((__hip_bfloat16*)Ps_w)[(lhi * 4 + r) * LP + ni * 16 + llo] =
                        __float2bfloat16(s[ni][r]);
#pragma unroll
            for (int ks = 0; ks < 2; ++ks) {
                short8 pa = *(const short8*)(Ps_w + llo * LP + ks * 32 + lhi * 8);
#pragma unroll
                for (int nj = 0; nj < 3; ++nj) {
                    short8 vb = *(const short8*)(Vs_s + (nj * 16 + llo) * LV + ks * 32 + lhi * 8);
                    o[nj] = __builtin_amdgcn_mfma_f32_16x16x32_bf16(pa, vb, o[nj], 0, 0, 0);
                }
            }
        }
        __syncthreads();
    }
    // flash combine: ws=1 publishes partials, ws=0 merges + writes
    if (ws == 1) {
#pragma unroll
        for (int r = 0; r < 4; ++r) {
            int lr = lhi * 4 + r;
            if (llo == 0) { Lm[wq][lr] = mrow[r]; Ll[wq][lr] = lrow[r]; }
#pragma unroll
            for (int nj = 0; nj < 3; ++nj) {
                int d = nj * 16 + llo;
                if (d < DKK) Lo[wq][lr][d] = o[nj][r];
            }
        }
    }
    __syncthreads();
    if (ws == 0) {
#pragma unroll
        for (int r = 0; r < 4; ++r) {
            int lr = lhi * 4 + r;
            float m1 = Lm[wq][lr], l1 = Ll[wq][lr];
            float m = fmaxf(mrow[r], m1);
            float a0 = __expf(mrow[r] - m), a1 = __expf(m1 - m);
            float linv = 1.f / (lrow[r] * a0 + l1 * a1);
            int q = qrow + r;
            if (q < SS) {
#pragma unroll
                for (int nj = 0; nj < 3; ++nj) {
                    int d = nj * 16 + llo;
                    if (d < DKK)
                        AO[((size_t)b * SS + q) * DD + h * DKK + d] =
                            __float2bfloat16((o[nj][r] * a0 + Lo[wq][lr][d] * a1) * linv);
                }
            }
        }
    }
}

// ---------------- row LayerNorm: ln((a + a2? + cb? + add?)) ----------------
__global__ __launch_bounds__(320) void ln_kernel(const float* __restrict__ a,
                                                 const float* __restrict__ a2,
                                                 const float* __restrict__ cb,
                                                 const float* __restrict__ add,
                                                 const float* __restrict__ g,
                                                 const float* __restrict__ bta,
                                                 float* __restrict__ out,
                                                 __hip_bfloat16* __restrict__ outb) {
    const int row = blockIdx.x, i = threadIdx.x;
    __shared__ float red[320];
    __shared__ float s_m, s_v;
    float v = a[row * DD + i];
    if (a2) v += a2[row * DD + i];
    if (cb) v += cb[i];
    if (add) v += add[row * DD + i];
    red[i] = v;
    __syncthreads();
    if (i < 64) red[i] += red[i + 256];
    __syncthreads();
    for (int s = 128; s > 0; s >>= 1) {
        if (i < s) red[i] += red[i + s];
        __syncthreads();
    }
    if (i == 0) s_m = red[0] * (1.0f / DD);
    __syncthreads();
    const float d = v - s_m;
    red[i] = d * d;
    __syncthreads();
    if (i < 64) red[i] += red[i + 256];
    __syncthreads();
    for (int s = 128; s > 0; s >>= 1) {
        if (i < s) red[i] += red[i + s];
        __syncthreads();
    }
    if (i == 0) s_v = red[0] * (1.0f / DD);
    __syncthreads();
    float o = d * rsqrtf(s_v + 1e-5f) * g[i] + bta[i];
    out[row * DD + i] = o;
    outb[row * DD + i] = __float2bfloat16(o);
}

// ---------------- mean stage 1: partial sums over 150-row chunks ----------------
__global__ __launch_bounds__(256) void mpart_kernel(const float* __restrict__ xs,
                                                    float* __restrict__ mp) {
    const int b = blockIdx.y, z = blockIdx.z;
    const int d = blockIdx.x * 64 + (threadIdx.x & 63);
    const int rg = threadIdx.x >> 6;
    float s = 0.f;
    const int t0 = z * 150;
    for (int t = t0 + rg; t < t0 + 150; t += 4) s += xs[((size_t)b * SS + t) * DD + d];
    __shared__ float red[256];
    red[threadIdx.x] = s;
    __syncthreads();
    if (threadIdx.x < 128) red[threadIdx.x] += red[threadIdx.x + 128];
    __syncthreads();
    if (threadIdx.x < 64) mp[((size_t)b * 6 + z) * DD + d] = red[threadIdx.x] + red[threadIdx.x + 64];
}

// ---------------- transform params (reads 6 mean partials) ----------------
__global__ __launch_bounds__(64) void tp_kernel(const float* __restrict__ mp,
                                                const float* __restrict__ wrot, const float* __restrict__ brot,
                                                const float* __restrict__ wrefl, const float* __restrict__ brefl,
                                                const float* __restrict__ wtr, const float* __restrict__ btr,
                                                const float* __restrict__ wsc, const float* __restrict__ bsc,
                                                float* __restrict__ tp) {
    const int b = blockIdx.x, tid = threadIdx.x;
    __shared__ float gs[DD];
    __shared__ float raw[17];
    for (int j = tid; j < DD; j += 64) {
        float s6 = 0.f;
#pragma unroll
        for (int z = 0; z < 6; ++z) s6 += mp[((size_t)b * 6 + z) * DD + j];
        gs[j] = s6 * (1.0f / SS);
    }
    __syncthreads();
    if (tid < 17) {
        float s;
        if (tid < 4) {
            s = brot[tid];
            for (int d = 0; d < DD; ++d) s = fmaf(gs[d], wrot[d * 4 + tid], s);
        } else if (tid < 12) {
            int j = tid - 4;
            s = brefl[j];
            for (int d = 0; d < DD; ++d) s = fmaf(gs[d], wrefl[d * 8 + j], s);
        } else if (tid < 14) {
            int j = tid - 12;
            s = btr[j];
            for (int d = 0; d < DD; ++d) s = fmaf(gs[d], wtr[d * 2 + j], s);
        } else {
            int j = tid - 14;
            s = bsc[j];
            for (int d = 0; d < DD; ++d) s = fmaf(gs[d], wsc[d * 3 + j], s);
        }
        raw[tid] = s;
    }
    __syncthreads();
    if (tid == 0) {
        float mx = -1e30f;
        for (int j = 0; j < 4; ++j) mx = fmaxf(mx, raw[j]);
        float sm = 0.f, e[4];
        for (int j = 0; j < 4; ++j) { e[j] = expf(raw[j] - mx); sm += e[j]; }
        for (int j = 0; j < 4; ++j) tp[b * 17 + j] = e[j] / sm;
    } else if (tid == 1) {
        float mx = -1e30f;
        for (int j = 4; j < 12; ++j) mx = fmaxf(mx, raw[j]);
        float sm = 0.f, e[8];
        for (int j = 0; j < 8; ++j) { e[j] = expf(raw[4 + j] - mx); sm += e[j]; }
        for (int j = 0; j < 8; ++j) tp[b * 17 + 4 + j] = e[j] / sm;
    } else if (tid == 2) {
        tp[b * 17 + 12] = tanhf(raw[12]);
        tp[b * 17 + 13] = tanhf(raw[13]);
    } else if (tid == 3) {
        float mx = -1e30f;
        for (int j = 14; j < 17; ++j) mx = fmaxf(mx, raw[j]);
        float sm = 0.f, e[3];
        for (int j = 0; j < 3; ++j) { e[j] = expf(raw[14 + j] - mx); sm += e[j]; }
        for (int j = 0; j < 3; ++j) tp[b * 17 + 14 + j] = e[j] / sm;
    }
}

// ---------------- concat xs(bf16) + tp -> TIbf [3600, 384] ----------------
__global__ void concat_kernel(const __hip_bfloat16* __restrict__ xb, const float* __restrict__ tp,
                              __hip_bfloat16* __restrict__ ti) {
    int idx = blockIdx.x * 256 + threadIdx.x;
    if (idx >= BS * 384) return;
    int m = idx / 384, j = idx % 384;
    __hip_bfloat16 v;
    if (j < DD) v = xb[m * DD + j];
    else if (j < 337) v = __float2bfloat16(tp[(m / SS) * 17 + (j - DD)]);
    else v = __float2bfloat16(0.f);
    ti[idx] = v;
}

static inline void launch_mgemm(hipStream_t s, const __hip_bfloat16* A, int lda,
                                const __hip_bfloat16* Wt, int ldw, const float* bias,
                                const float* biasB, const float* biasC,
                                const float* res, int ldr, float alpha, float* Cf,
                                __hip_bfloat16* Cb, int ldc, int M, int N, int K, int act) {
    dim3 g((N + 63) / 64, (M + 127) / 128);
    mgemm_kernel<<<g, 256, 0, s>>>(A, lda, Wt, ldw, bias, biasB, biasC, res, ldr, alpha,
                                   Cf, nullptr, Cb, ldc, M, N, K, act);
}

extern "C" void kernel_launch(void* const* d_in, const int* in_sizes, int n_in,
                              void* d_out, int out_size, void* d_ws, size_t ws_size,
                              hipStream_t stream) {
    (void)in_sizes; (void)n_in; (void)out_size; (void)ws_size;
    const int* in_grid = (const int*)d_in[0];
    const float* pe = (const float*)d_in[1];
    const float* iew = (const float*)d_in[2];
    const float* ieb = (const float*)d_in[3];
    const float* wq = (const float*)d_in[4], *bq = (const float*)d_in[5];
    const float* wk = (const float*)d_in[6], *bk = (const float*)d_in[7];
    const float* wv = (const float*)d_in[8], *bv = (const float*)d_in[9];
    const float* wo = (const float*)d_in[10], *bo = (const float*)d_in[11];
    const float* lnag = (const float*)d_in[12], *lnab = (const float*)d_in[13];
    const float* dist_emb = (const float*)d_in[14], *dir_emb = (const float*)d_in[15];
    const float* wrot = (const float*)d_in[16], *brot = (const float*)d_in[17];
    const float* wrefl = (const float*)d_in[18], *brefl = (const float*)d_in[19];
    const float* wtr = (const float*)d_in[20], *btr = (const float*)d_in[21];
    const float* wsc = (const float*)d_in[22], *bsc = (const float*)d_in[23];
    const float* tnw1 = (const float*)d_in[24], *tnb1 = (const float*)d_in[25];
    const float* tnw2 = (const float*)d_in[26], *tnb2 = (const float*)d_in[27];
    const float* tnw3 = (const float*)d_in[28], *tnb3 = (const float*)d_in[29];
    const float* ffw1 = (const float*)d_in[30], *ffb1 = (const float*)d_in[31];
    const float* ffw2 = (const float*)d_in[32], *ffb2 = (const float*)d_in[33];
    const float* ln2g = (const float*)d_in[34], *ln2b = (const float*)d_in[35];
    const float* ck1 = (const float*)d_in[36], *cb1 = (const float*)d_in[37];
    const float* ck3 = (const float*)d_in[38], *cb3 = (const float*)d_in[39];
    const float* ck5 = (const float*)d_in[40], *cb5 = (const float*)d_in[41];
    const float* ck7 = (const float*)d_in[42], *cb7 = (const float*)d_in[43];
    const float* fusw = (const float*)d_in[44], *fusb = (const float*)d_in[45];
    const float* opw1 = (const float*)d_in[46], *opb1 = (const float*)d_in[47];
    const float* opw2 = (const float*)d_in[48], *opb2 = (const float*)d_in[49];
    const float* opw3 = (const float*)d_in[50], *opb3 = (const float*)d_in[51];
    const int* dist_idx = (const int*)d_in[52];
    const int* dir_idx = (const int*)d_in[53];
    float* out = (float*)d_out;

    // ---- workspace arena (byte offsets) ----
    char* base = (char*)d_ws;
    typedef __hip_bfloat16 bf;
    bf* WQKVT = (bf*)(base + 0);          // [4][960][320]
    bf* WOT = (bf*)(base + 2457600);
    bf* TN1T = (bf*)(base + 3276800);
    bf* TN2T = (bf*)(base + 5242880);
    bf* TN3T = (bf*)(base + 6881280);
    bf* FF1T = (bf*)(base + 7700480);
    bf* FF2T = (bf*)(base + 10977280);
    bf* CK1T = (bf*)(base + 14254080);
    bf* CK3T = (bf*)(base + 14458880);
    bf* CK5T = (bf*)(base + 16302080);
    bf* CK7T = (bf*)(base + 21422080);
    bf* FUST = (bf*)(base + 31457280);
    bf* OP1T = (bf*)(base + 32276480);
    float* XS = (float*)(base + 32378880);
    bf* XSbf = (bf*)(base + 36986880);
    bf* QKVbf = (bf*)(base + 39290880);   // [3600][960], ends 46,202,880
    bf* VT = (bf*)(base + 46202880);      // ends 49,152,000
    float* P1f = (float*)(base + 39290880);  // ff2 K-split partial (QKV region, dead post-attn)
    float* R2 = (float*)(base + 53114880);
    float* TP = (float*)(base + 57728000);
    // conv bf16 partials: [7][3600][320] bf16 = 16,128,000 B in dead QKV..R2 region
    bf* CPART = (bf*)(base + 39290880);
    char* BIG = base + 57728512;
    bf* AObf = (bf*)(BIG + 0);
    float* MPart = (float*)(BIG + 0);     // [4][6][320] f32, mean partials (AObf dead; pre-concat)
    bf* BIAS = (bf*)(BIG + 2764800);
    bf* TIbf = (bf*)(BIG + 0);
    bf* T1bf = (bf*)(BIG + 2764800);
    bf* T2bf = (bf*)(BIG + 7372800);
    bf* F1bf = (bf*)(BIG + 0);
    bf* PADbf = (bf*)(BIG + 0);
    bf* FEATSbf = (bf*)(BIG + 3317760);
    float* H1 = (float*)(BIG + 0);
    float* H2 = (float*)(BIG + 2304000);
    bf* R2bf = XSbf;

    dim3 cb(32, 8);
    qkvconvt_kernel<<<dim3(10, 10, 12), cb, 0, stream>>>(wq, wk, wv, WQKVT);
    allconvt_kernel<<<14610, cb, 0, stream>>>(wo, tnw1, tnw2, tnw3, ffw1, ffw2,
                                              ck1, ck3, ck5, ck7, fusw, opw1,
                                              WOT, TN1T, TN2T, TN3T, FF1T, FF2T,
                                              CK1T, CK3T, CK5T, CK7T, FUST, OP1T);

    embed_kernel<<<4500, 256, 0, stream>>>(in_grid, pe, iew, ieb, XS, XSbf);

    for (int l = 0; l < LL; ++l) {
        const int wO = l * DD * DD, bO = l * DD;
        // fused QKV projection: N=960
        launch_mgemm(stream, XSbf, DD, WQKVT + l * 307200, 320, bq + bO, bk + bO, bv + bO,
                     nullptr, 0, 1.f, nullptr, QKVbf, 960, BS, 960, 320, 0);
        attprep_kernel<<<4815, 256, 0, stream>>>(dist_emb + l * 60 * NHH, dir_emb + l * 8 * NHH,
                                                 dist_idx, dir_idx, QKVbf, BIAS, VT);
        mattn_kernel<<<dim3(15, NHH, BB), 512, 0, stream>>>(QKVbf, QKVbf + 320, VT, BIAS, AObf);
        launch_mgemm(stream, AObf, DD, WOT + wO, DD, bo + bO, nullptr, nullptr, XS, DD, 1.f,
                     R2, nullptr, DD, BS, DD, DD, 0);
        ln_kernel<<<BS, 320, 0, stream>>>(R2, nullptr, nullptr, nullptr, lnag + bO, lnab + bO, XS, XSbf);
        mpart_kernel<<<dim3(5, BB, 6), 256, 0, stream>>>(XS, MPart);
        tp_kernel<<<BB, 64, 0, stream>>>(MPart, wrot + l * 1280, brot + l * 4,
                                         wrefl + l * 2560, brefl + l * 8,
                                         wtr + l * 640, btr + l * 2,
                                         wsc + l * 960, bsc + l * 3, TP);
        concat_kernel<<<(BS * 384 + 255) / 256, 256, 0, stream>>>(XSbf, TP, TIbf);
        launch_mgemm(stream, TIbf, 384, TN1T + l * 245760, 384, tnb1 + l * 640, nullptr, nullptr,
                     nullptr, 0, 1.f, nullptr, T1bf, 640, BS, 640, 384, 1);
        launch_mgemm(stream, T1bf, 640, TN2T + l * 204800, 640, tnb2 + bO, nullptr, nullptr,
                     nullptr, 0, 1.f, nullptr, T2bf, DD, BS, DD, 640, 1);
        launch_mgemm(stream, T2bf, DD, TN3T + wO, DD, tnb3 + bO, nullptr, nullptr, XS, DD, 0.3f,
                     XS, XSbf, DD, BS, DD, DD, 0);
        launch_mgemm(stream, XSbf, DD, FF1T + l * 409600, DD, ffb1 + l * FFD, nullptr, nullptr,
                     nullptr, 0, 1.f, nullptr, F1bf, FFD, BS, FFD, DD, 1);
        // ff2 split-K: z=0 -> R2 (K rows 0..639), z=1 -> P1f (rows 640..1279); merged in ln
        {
            dim3 g(5, 29, 2);
            mgemm_kernel<<<g, 256, 0, stream>>>(F1bf, FFD, FF2T + l * 409600, FFD,
                                                nullptr, nullptr, nullptr, nullptr, 0, 1.f,
                                                R2, P1f, nullptr, DD, BS, DD, 640, 0);
        }
        ln_kernel<<<BS, 320, 0, stream>>>(R2, P1f, ffb2 + bO, XS, ln2g + bO, ln2b + bO, XS, XSbf);
    }

    // ---- multiscale convs: per-kh bf16 partials + reduce (XCD-swizzled) ----
    pad_kernel<<<(BB * 36 * 36 * DD + 255) / 256, 256, 0, stream>>>(XSbf, PADbf);
    launch_mgemm(stream, XSbf, DD, CK1T, DD, cb1, nullptr, nullptr, nullptr, 0, 1.f,
                 nullptr, FEATSbf + 0, 1280, BS, DD, DD, 2);
    const int RED = (BS * DD / 8 + 255) / 256;
    mconv_kernel<3><<<dim3(29, 5, 3), 256, 0, stream>>>(PADbf, CK3T, CPART, 1);
    creduce_kernel<<<RED, 256, 0, stream>>>(CPART, 3, cb3, FEATSbf + 320, 1280);
    mconv_kernel<5><<<dim3(29, 5, 5), 256, 0, stream>>>(PADbf, CK5T, CPART, 1);
    creduce_kernel<<<RED, 256, 0, stream>>>(CPART, 5, cb5, FEATSbf + 640, 1280);
    mconv_kernel<7><<<dim3(29, 5, 7), 256, 0, stream>>>(PADbf, CK7T, CPART, 1);
    creduce_kernel<<<RED, 256, 0, stream>>>(CPART, 7, cb7, FEATSbf + 960, 1280);
    launch_mgemm(stream, FEATSbf, 1280, FUST, 1280, fusb, nullptr, nullptr, nullptr, 0, 1.f,
                 nullptr, R2bf, DD, BS, DD, 1280, 0);
    // ---- output head ----
    launch_mgemm(stream, R2bf, DD, OP1T, DD, opb1, nullptr, nullptr, nullptr, 0, 1.f,
                 H1, nullptr, 160, BS, 160, DD, 1);
    gemm_kernel<<<dim3(2, 57), 256, 0, stream>>>(H1, 160, opw2, opb2, H2, 80, BS, 80, 160, 1);
    gemm_kernel<<<dim3(1, 57), 256, 0, stream>>>(H2, 80, opw3, opb3, out, 10, BS, 10, 80, 0);
}

// Round 11
// 1551.552 us; speedup vs baseline: 7.1203x; 1.0055x over previous
//
#include <hip/hip_runtime.h>
#include <hip/hip_bf16.h>

#define BB 4
#define GG_ 30
#define DD 320
#define LL 4
#define NHH 8
#define DKK 40
#define SS 900
#define BS 3600
#define FFD 1280
#define LDK 72   // BK(64) + 8 pad, in bf16 elems -> 144B row stride, 16B aligned

typedef __attribute__((ext_vector_type(8))) short short8;
typedef __attribute__((ext_vector_type(4))) short short4v;
typedef __attribute__((ext_vector_type(4))) float f32x4;

__device__ __forceinline__ float gelu_f(float x) {
    return 0.5f * x * (1.0f + erff(x * 0.70710678118654752f));
}

__device__ __forceinline__ float bfbits2f(short b) {
    return __uint_as_float(((unsigned)(unsigned short)b) << 16);
}

// ---------------- shared convt tile body ----------------
__device__ __forceinline__ void convt_tile(const float* __restrict__ s,
                                           __hip_bfloat16* __restrict__ d,
                                           int K, int N, int Kpad, int kb, int nb) {
    __shared__ float t[32][33];
    const int tx = threadIdx.x, ty = threadIdx.y;   // (32, 8)
#pragma unroll
    for (int i = 0; i < 4; ++i) {
        int k = kb + ty + i * 8, n = nb + tx;
        t[ty + i * 8][tx] = (k < K && n < N) ? s[(size_t)k * N + n] : 0.f;
    }
    __syncthreads();
#pragma unroll
    for (int i = 0; i < 4; ++i) {
        int n = nb + ty + i * 8, k = kb + tx;
        if (n < N && k < Kpad) d[(size_t)n * Kpad + k] = __float2bfloat16(t[tx][ty + i * 8]);
    }
}

// ---------------- ALL weight transposes in one launch (14610 blocks) ----------------
__global__ __launch_bounds__(256) void allconvt_kernel(
    const float* wo, const float* tnw1, const float* tnw2, const float* tnw3,
    const float* ffw1, const float* ffw2, const float* ck1, const float* ck3,
    const float* ck5, const float* ck7, const float* fusw, const float* opw1,
    __hip_bfloat16* WOT, __hip_bfloat16* TN1T, __hip_bfloat16* TN2T, __hip_bfloat16* TN3T,
    __hip_bfloat16* FF1T, __hip_bfloat16* FF2T, __hip_bfloat16* CK1T, __hip_bfloat16* CK3T,
    __hip_bfloat16* CK5T, __hip_bfloat16* CK7T, __hip_bfloat16* FUST, __hip_bfloat16* OP1T) {
    const int bid = blockIdx.x;
    const float* s; __hip_bfloat16* d;
    int K, N, Kpad, gx, per, local, sS, dS;
    if (bid < 400)        { local = bid;         s = wo;   d = WOT;  K = 320;  N = 320;  Kpad = 320;  sS = 102400; dS = 102400; gx = 10;  per = 100; }
    else if (bid < 1360)  { local = bid - 400;   s = tnw1; d = TN1T; K = 337;  N = 640;  Kpad = 384;  sS = 215680; dS = 245760; gx = 12;  per = 240; }
    else if (bid < 2160)  { local = bid - 1360;  s = tnw2; d = TN2T; K = 640;  N = 320;  Kpad = 640;  sS = 204800; dS = 204800; gx = 20;  per = 200; }
    else if (bid < 2560)  { local = bid - 2160;  s = tnw3; d = TN3T; K = 320;  N = 320;  Kpad = 320;  sS = 102400; dS = 102400; gx = 10;  per = 100; }
    else if (bid < 4160)  { local = bid - 2560;  s = ffw1; d = FF1T; K = 320;  N = 1280; Kpad = 320;  sS = 409600; dS = 409600; gx = 10;  per = 400; }
    else if (bid < 5760)  { local = bid - 4160;  s = ffw2; d = FF2T; K = 1280; N = 320;  Kpad = 1280; sS = 409600; dS = 409600; gx = 40;  per = 400; }
    else if (bid < 5860)  { local = bid - 5760;  s = ck1;  d = CK1T; K = 320;  N = 320;  Kpad = 320;  sS = 0; dS = 0; gx = 10;  per = 100; }
    else if (bid < 6760)  { local = bid - 5860;  s = ck3;  d = CK3T; K = 2880; N = 320;  Kpad = 2880; sS = 0; dS = 0; gx = 90;  per = 900; }
    else if (bid < 9260)  { local = bid - 6760;  s = ck5;  d = CK5T; K = 8000; N = 320;  Kpad = 8000; sS = 0; dS = 0; gx = 250; per = 2500; }
    else if (bid < 14160) { local = bid - 9260;  s = ck7;  d = CK7T; K = 15680; N = 320; Kpad = 15680; sS = 0; dS = 0; gx = 490; per = 4900; }
    else if (bid < 14560) { local = bid - 14160; s = fusw; d = FUST; K = 1280; N = 320;  Kpad = 1280; sS = 0; dS = 0; gx = 40;  per = 400; }
    else                  { local = bid - 14560; s = opw1; d = OP1T; K = 320;  N = 160;  Kpad = 320;  sS = 0; dS = 0; gx = 10;  per = 50; }
    const int mat = local / per, rem = local - mat * per;
    const int kb = (rem % gx) * 32, nb = (rem / gx) * 32;
    convt_tile(s + (size_t)mat * sS, d + (size_t)mat * dS, K, N, Kpad, kb, nb);
}

// ---------------- packed QKV weight convert: [L][960][320] bf16 ----------------
__global__ __launch_bounds__(256) void qkvconvt_kernel(const float* __restrict__ wq,
                                                       const float* __restrict__ wk,
                                                       const float* __restrict__ wv,
                                                       __hip_bfloat16* __restrict__ dst) {
    __shared__ float t[32][33];
    const int z = blockIdx.z, l = z / 3, wsel = z % 3;
    const float* s = (wsel == 0 ? wq : wsel == 1 ? wk : wv) + (size_t)l * 102400;
    __hip_bfloat16* d = dst + (size_t)l * 307200 + wsel * 102400;
    const int kb = blockIdx.x * 32, nb = blockIdx.y * 32;
    const int tx = threadIdx.x, ty = threadIdx.y;   // (32, 8)
#pragma unroll
    for (int i = 0; i < 4; ++i) {
        int k = kb + ty + i * 8, n = nb + tx;
        t[ty + i * 8][tx] = s[(size_t)k * 320 + n];
    }
    __syncthreads();
#pragma unroll
    for (int i = 0; i < 4; ++i) {
        int n = nb + ty + i * 8, k = kb + tx;
        d[(size_t)n * 320 + k] = __float2bfloat16(t[tx][ty + i * 8]);
    }
}

// ---------------- embed ----------------
__global__ void embed_kernel(const int* __restrict__ grid, const float* __restrict__ pe,
                             const float* __restrict__ ew, const float* __restrict__ eb,
                             float* __restrict__ x, __hip_bfloat16* __restrict__ xb) {
    int idx = blockIdx.x * 256 + threadIdx.x;   // < 1,152,000
    int m = idx / DD, d = idx % DD;
    int gv = grid[m];
    float v = ew[gv * DD + d] + eb[d] + pe[(m % SS) * DD + d];
    x[idx] = v;
    xb[idx] = __float2bfloat16(v);
}

// ---------------- MFMA bf16 GEMM (proven 128x64 body; 3-way bias; optional K-split z) ----------------
__global__ __launch_bounds__(256) void mgemm_kernel(
    const __hip_bfloat16* __restrict__ A, int lda,
    const __hip_bfloat16* __restrict__ Wt, int ldw,
    const float* __restrict__ bias, const float* __restrict__ biasB, const float* __restrict__ biasC,
    const float* __restrict__ res, int ldr,
    float alpha, float* __restrict__ Cf, float* __restrict__ Cf2,
    __hip_bfloat16* __restrict__ Cb, int ldc,
    int M, int N, int K, int act) {
    __shared__ short As[128 * LDK];
    __shared__ short Bs[64 * LDK];
    const int tid = threadIdx.x;
    const int m0 = blockIdx.y * 128, n0 = blockIdx.x * 64;
    const int kb0 = blockIdx.z * K;                 // K-split offset (z=0 for normal calls)
    float* __restrict__ CfO = (blockIdx.z == 0) ? Cf : Cf2;
    const int lane = tid & 63;
    const int w = tid >> 6, wm = w >> 1, wn = w & 1;
    const int rbase = tid >> 3, q8 = (tid & 7) * 8;
    f32x4 acc[4][2];
    const f32x4 fz = {0.f, 0.f, 0.f, 0.f};
#pragma unroll
    for (int mi = 0; mi < 4; ++mi)
#pragma unroll
        for (int ni = 0; ni < 2; ++ni) acc[mi][ni] = fz;
    const short8 zz = {0, 0, 0, 0, 0, 0, 0, 0};
    for (int k0 = 0; k0 < K; k0 += 64) {
#pragma unroll
        for (int c = 0; c < 4; ++c) {
            int r = c * 32 + rbase, m = m0 + r;
            short8 v = zz;
            if (m < M) v = *(const short8*)((const short*)A + (size_t)m * lda + kb0 + k0 + q8);
            *(short8*)(As + r * LDK + q8) = v;
        }
#pragma unroll
        for (int c = 0; c < 2; ++c) {
            int r = c * 32 + rbase, n = n0 + r;
            short8 v = zz;
            if (n < N) v = *(const short8*)((const short*)Wt + (size_t)n * ldw + kb0 + k0 + q8);
            *(short8*)(Bs + r * LDK + q8) = v;
        }
        __syncthreads();
#pragma unroll
        for (int ks = 0; ks < 64; ks += 32) {
            const int kb = ks + (lane >> 4) * 8;
            short8 af[4], bf[2];
#pragma unroll
            for (int mi = 0; mi < 4; ++mi)
                af[mi] = *(const short8*)(As + (wm * 64 + mi * 16 + (lane & 15)) * LDK + kb);
#pragma unroll
            for (int ni = 0; ni < 2; ++ni)
                bf[ni] = *(const short8*)(Bs + (wn * 32 + ni * 16 + (lane & 15)) * LDK + kb);
#pragma unroll
            for (int mi = 0; mi < 4; ++mi)
#pragma unroll
                for (int ni = 0; ni < 2; ++ni)
                    acc[mi][ni] = __builtin_amdgcn_mfma_f32_16x16x32_bf16(af[mi], bf[ni], acc[mi][ni], 0, 0, 0);
        }
        __syncthreads();
    }
    const int col0 = n0 + wn * 32 + (lane & 15);
    const int rloc = (lane >> 4) * 4;
#pragma unroll
    for (int mi = 0; mi < 4; ++mi) {
#pragma unroll
        for (int ni = 0; ni < 2; ++ni) {
            int col = col0 + ni * 16;
            if (col >= N) continue;
            float bv;
            if (biasC) bv = (col < 320) ? bias[col] : (col < 640) ? biasB[col - 320] : biasC[col - 640];
            else bv = bias ? bias[col] : 0.f;
#pragma unroll
            for (int r = 0; r < 4; ++r) {
                int row = m0 + wm * 64 + mi * 16 + rloc + r;
                if (row >= M) continue;
                float v = acc[mi][ni][r] + bv;
                if (act == 1) v = gelu_f(v);
                else if (act == 2) v = fmaxf(v, 0.f);
                v *= alpha;
                if (res) v += res[(size_t)row * ldr + col];
                if (CfO) CfO[(size_t)row * ldc + col] = v;
                if (Cb) Cb[(size_t)row * ldc + col] = __float2bfloat16(v);
            }
        }
    }
}

// ---------------- MFMA conv: kh-split + XCD swizzle + hoisted im2col addressing ----------------
template <int KS>
__global__ __launch_bounds__(256) void mconv_kernel(
    const __hip_bfloat16* __restrict__ P, const __hip_bfloat16* __restrict__ Wt,
    __hip_bfloat16* __restrict__ part, int kh0step) {
    const int K = KS * KS * DD;
    const int OFF = 3 - KS / 2;
    // --- XCD-aware bijective swizzle (m204): hw id -> work id ---
    const int nwg = 145 * gridDim.z;
    const int ib = blockIdx.x + 29 * (blockIdx.y + 5 * blockIdx.z);
    const int xcd = ib & 7, kk2 = ib >> 3;
    const int qq = nwg >> 3, rr = nwg & 7;
    const int wid = (xcd < rr) ? (xcd * (qq + 1) + kk2) : (rr * (qq + 1) + (xcd - rr) * qq + kk2);
    const int mt = wid % 29, rest = wid / 29;
    const int nt = rest % 5, zt = rest / 5;
    const int kh0 = zt * kh0step;
    const int nkh = (KS - kh0 < kh0step) ? (KS - kh0) : kh0step;
    const int wbase = kh0 * KS * DD;
    __hip_bfloat16* __restrict__ Cp = part + (size_t)zt * BS * DD;
    __shared__ short As[128 * LDK];
    __shared__ short Bs[64 * LDK];
    const int tid = threadIdx.x;
    const int m0 = mt * 128, n0 = nt * 64;
    const int lane = tid & 63;
    const int w = tid >> 6, wm = w >> 1, wn = w & 1;
    const int rbase = tid >> 3, q8 = (tid & 7) * 8;
    f32x4 acc[4][2];
    const f32x4 fz = {0.f, 0.f, 0.f, 0.f};
#pragma unroll
    for (int mi = 0; mi < 4; ++mi)
#pragma unroll
        for (int ni = 0; ni < 2; ++ni) acc[mi][ni] = fz;
    const short8 zz = {0, 0, 0, 0, 0, 0, 0, 0};
    // --- hoisted per-thread bases (loop-invariant) ---
    const short* P0[4];
    bool mval[4];
#pragma unroll
    for (int c = 0; c < 4; ++c) {
        int m = m0 + c * 32 + rbase;
        mval[c] = (m < BS);
        int mm = mval[c] ? m : 0;
        int b = mm / SS, hw = mm % SS, oh = hw / GG_, ow = hw % GG_;
        P0[c] = (const short*)P + (size_t)((b * 36 + oh) * 36 + ow) * DD + q8;
    }
    const short* W0[2];
#pragma unroll
    for (int c = 0; c < 2; ++c) {
        int n = n0 + c * 32 + rbase;
        W0[c] = (const short*)Wt + (size_t)n * K + wbase + q8;
    }
    // --- K loop: taps (kh,kw) outer, channel chunks inner ---
    const int ntap = nkh * KS;
    for (int tap = 0; tap < ntap; ++tap) {
        const int khr = tap / KS, kw = tap - khr * KS;
        const int tapOff = (((kh0 + khr) + OFF) * 36 + (kw + OFF)) * DD;
        const int wOff = tap * DD;
        for (int ci0 = 0; ci0 < DD; ci0 += 64) {
#pragma unroll
            for (int c = 0; c < 4; ++c) {
                int r = c * 32 + rbase;
                short8 v = mval[c] ? *(const short8*)(P0[c] + tapOff + ci0) : zz;
                *(short8*)(As + r * LDK + q8) = v;
            }
#pragma unroll
            for (int c = 0; c < 2; ++c) {
                int r = c * 32 + rbase;
                short8 v = *(const short8*)(W0[c] + wOff + ci0);
                *(short8*)(Bs + r * LDK + q8) = v;
            }
            __syncthreads();
#pragma unroll
            for (int ks = 0; ks < 64; ks += 32) {
                const int kb = ks + (lane >> 4) * 8;
                short8 af[4], bf[2];
#pragma unroll
                for (int mi = 0; mi < 4; ++mi)
                    af[mi] = *(const short8*)(As + (wm * 64 + mi * 16 + (lane & 15)) * LDK + kb);
#pragma unroll
                for (int ni = 0; ni < 2; ++ni)
                    bf[ni] = *(const short8*)(Bs + (wn * 32 + ni * 16 + (lane & 15)) * LDK + kb);
#pragma unroll
                for (int mi = 0; mi < 4; ++mi)
#pragma unroll
                    for (int ni = 0; ni < 2; ++ni)
                        acc[mi][ni] = __builtin_amdgcn_mfma_f32_16x16x32_bf16(af[mi], bf[ni], acc[mi][ni], 0, 0, 0);
            }
            __syncthreads();
        }
    }
    const int col0 = n0 + wn * 32 + (lane & 15);
    const int rloc = (lane >> 4) * 4;
#pragma unroll
    for (int mi = 0; mi < 4; ++mi) {
#pragma unroll
        for (int ni = 0; ni < 2; ++ni) {
            int col = col0 + ni * 16;
#pragma unroll
            for (int r = 0; r < 4; ++r) {
                int row = m0 + wm * 64 + mi * 16 + rloc + r;
                if (row < BS) Cp[(size_t)row * DD + col] = __float2bfloat16(acc[mi][ni][r]);
            }
        }
    }
}

// ---------------- conv partial reduce: relu(sum bf16 parts + bias) -> bf16 @ldc ----------------
__global__ __launch_bounds__(256) void creduce_kernel(const __hip_bfloat16* __restrict__ part,
                                                      int nsplit, const float* __restrict__ bias,
                                                      __hip_bfloat16* __restrict__ outb, int ldc) {
    int idx = blockIdx.x * 256 + threadIdx.x;      // over BS*DD/8 groups of 8 cols
    if (idx >= BS * DD / 8) return;
    int row = idx / (DD / 8), c8 = (idx % (DD / 8)) * 8;
    float s[8] = {};
    for (int p = 0; p < nsplit; ++p) {
        short8 v = *(const short8*)((const short*)part + (size_t)p * BS * DD + (size_t)row * DD + c8);
#pragma unroll
        for (int j = 0; j < 8; ++j) s[j] += bfbits2f(v[j]);
    }
    __hip_bfloat16* o = outb + (size_t)row * ldc + c8;
#pragma unroll
    for (int j = 0; j < 8; ++j) o[j] = __float2bfloat16(fmaxf(s[j] + bias[c8 + j], 0.f));
}

// ---------------- pad bf16 image for convs ----------------
__global__ void pad_kernel(const __hip_bfloat16* __restrict__ xb, __hip_bfloat16* __restrict__ p) {
    int idx = blockIdx.x * 256 + threadIdx.x;   // 4*36*36*320
    if (idx >= BB * 36 * 36 * DD) return;
    int c = idx % DD, t = idx / DD;
    int wp = t % 36, t2 = t / 36, hp = t2 % 36, b = t2 / 36;
    __hip_bfloat16 v = __float2bfloat16(0.f);
    if (hp >= 3 && hp < 33 && wp >= 3 && wp < 33)
        v = xb[((b * SS + (hp - 3) * GG_ + (wp - 3))) * DD + c];
    p[idx] = v;
}

// ---------------- legacy fp32 GEMM (tiny op heads) ----------------
__global__ __launch_bounds__(256) void gemm_kernel(
    const float* __restrict__ A, int lda, const float* __restrict__ W,
    const float* __restrict__ bias, float* __restrict__ C, int ldc,
    int M, int N, int K, int act) {
    __shared__ float As[16][65];
    __shared__ float Ws[16][65];
    const int tid = threadIdx.x;
    const int m0 = blockIdx.y * 64, n0 = blockIdx.x * 64;
    const int tx = tid & 15, ty = tid >> 4;
    float acc[4][4] = {};
    const int kkA = tid & 15, mloc0 = tid >> 4;
    const int nloc = tid & 63, kk0 = tid >> 6;
    for (int k0 = 0; k0 < K; k0 += 16) {
        const int kA = k0 + kkA;
#pragma unroll
        for (int i = 0; i < 4; ++i) {
            int mloc = mloc0 + i * 16, m = m0 + mloc;
            As[kkA][mloc] = (m < M && kA < K) ? A[m * lda + kA] : 0.f;
        }
#pragma unroll
        for (int i = 0; i < 4; ++i) {
            int kk = kk0 + i * 4, k = k0 + kk, n = n0 + nloc;
            Ws[kk][nloc] = (k < K && n < N) ? W[k * N + n] : 0.f;
        }
        __syncthreads();
#pragma unroll
        for (int kk = 0; kk < 16; ++kk) {
            float a[4], b[4];
#pragma unroll
            for (int i = 0; i < 4; ++i) a[i] = As[kk][ty * 4 + i];
#pragma unroll
            for (int j = 0; j < 4; ++j) b[j] = Ws[kk][tx * 4 + j];
#pragma unroll
            for (int i = 0; i < 4; ++i)
#pragma unroll
                for (int j = 0; j < 4; ++j) acc[i][j] = fmaf(a[i], b[j], acc[i][j]);
        }
        __syncthreads();
    }
#pragma unroll
    for (int i = 0; i < 4; ++i) {
        int m = m0 + ty * 4 + i;
        if (m >= M) continue;
#pragma unroll
        for (int j = 0; j < 4; ++j) {
            int n = n0 + tx * 4 + j;
            if (n >= N) continue;
            float v = acc[i][j] + bias[n];
            if (act == 1) v = gelu_f(v);
            C[m * ldc + n] = v;
        }
    }
}

// ---------------- merged attn prep v2: 8-head bias per thread + 4-elem VT ----------------
__global__ __launch_bounds__(256) void attprep_kernel(const float* __restrict__ de,
                                                      const float* __restrict__ dre,
                                                      const int* __restrict__ dist,
                                                      const int* __restrict__ dirn,
                                                      const __hip_bfloat16* __restrict__ QKV,
                                                      __hip_bfloat16* __restrict__ biasOut,
                                                      __hip_bfloat16* __restrict__ VT) {
    const int gid = blockIdx.x;
    const int tid = threadIdx.x;
    if (gid < 3375) {
        int idx = gid * 256 + tid;                 // < 864000
        int sq = idx / 960, t = idx - sq * 960;
        float lut[NHH];
        if (t < SS) {
            int dv = dist[sq * SS + t], rv = dirn[sq * SS + t];
#pragma unroll
            for (int h = 0; h < NHH; ++h) lut[h] = de[dv * NHH + h] + dre[rv * NHH + h];
        } else {
#pragma unroll
            for (int h = 0; h < NHH; ++h) lut[h] = 0.f;
        }
#pragma unroll
        for (int h = 0; h < NHH; ++h)
            biasOut[((size_t)h * SS + sq) * 960 + t] = __float2bfloat16(lut[h]);
    } else {
        int vidx = (gid - 3375) * 256 + tid;       // < 368,640
        int t0 = (vidx % 240) * 4;
        int d = (vidx / 240) % 48;
        int h = (vidx / (240 * 48)) % NHH;
        int b = vidx / (240 * 48 * NHH);
        short4v v = {0, 0, 0, 0};
        if (d < DKK) {
#pragma unroll
            for (int j = 0; j < 4; ++j) {
                int t = t0 + j;
                if (t < SS)
                    v[j] = ((const short*)QKV)[((size_t)b * SS + t) * 960 + 640 + h * DKK + d];
            }
        }
        *(short4v*)((short*)VT + (((size_t)b * NHH + h) * 48 + d) * 960 + t0) = v;
    }
}

// ---------------- MFMA flash attention: 512 thr, in-block KV-split + merge ----------------
#define LQ 72
#define LK 72
#define LV 72
#define LP 72
__global__ __launch_bounds__(512) void mattn_kernel(
    const __hip_bfloat16* __restrict__ Qg, const __hip_bfloat16* __restrict__ Kg,
    const __hip_bfloat16* __restrict__ VTg, const __hip_bfloat16* __restrict__ BIASg,
    __hip_bfloat16* __restrict__ AO) {
    const int qt = blockIdx.x, h = blockIdx.y, b = blockIdx.z;
    const int tid = threadIdx.x, lane = tid & 63, w = tid >> 6;
    const int wq = w & 3, ws = w >> 2;
    const int tid2 = tid & 255;
    const int lhi = lane >> 4, llo = lane & 15;
    __shared__ short Qs[64 * LQ];
    __shared__ short Ks[2][64 * LK];
    __shared__ short Vs[2][48 * LV];
    __shared__ short Ps[8][16 * LP];
    __shared__ float Lm[4][16];
    __shared__ float Ll[4][16];
    __shared__ float Lo[4][16][DKK];
    short* Ps_w = Ps[w];
    short* Ks_s = Ks[ws];
    short* Vs_s = Vs[ws];
    const int q0 = qt * 64;
    const short4v z4 = {0, 0, 0, 0};
    const f32x4 fz = {0.f, 0.f, 0.f, 0.f};
    const float scale = 0.15811388300841898f;  // 1/sqrt(40)

    for (int task = tid; task < 64 * 16; task += 512) {
        int r = task >> 4, d0 = (task & 15) * 4;
        int q = q0 + r;
        short4v v = z4;
        if (q < SS && d0 < DKK)
            v = *(const short4v*)((const short*)Qg + ((size_t)b * SS + q) * 960 + h * DKK + d0);
        *(short4v*)(Qs + r * LQ + d0) = v;
    }
    __syncthreads();
    short8 qa[2];
#pragma unroll
    for (int ks = 0; ks < 2; ++ks)
        qa[ks] = *(const short8*)(Qs + (wq * 16 + llo) * LQ + ks * 32 + lhi * 8);

    float mrow[4] = {-1e30f, -1e30f, -1e30f, -1e30f};
    float lrow[4] = {0.f, 0.f, 0.f, 0.f};
    f32x4 o[3] = {fz, fz, fz};
    const int qrow = q0 + wq * 16 + lhi * 4;

    for (int tt = 0; tt < 8; ++tt) {
        const int t = tt * 2 + ws;
        const int kv0 = t * 64;
        if (t < 15) {
            for (int task = tid2; task < 64 * 16; task += 256) {
                int r = task >> 4, d0 = (task & 15) * 4;
                int kv = kv0 + r;
                short4v v = z4;
                if (kv < SS && d0 < DKK)
                    v = *(const short4v*)((const short*)Kg + ((size_t)b * SS + kv) * 960 + h * DKK + d0);
                *(short4v*)(Ks_s + r * LK + d0) = v;
            }
            for (int task = tid2; task < 48 * 16; task += 256) {
                int r = task >> 4, c4 = (task & 15) * 4;
                short4v v = *(const short4v*)((const short*)VTg +
                             (((size_t)b * NHH + h) * 48 + r) * 960 + kv0 + c4);
                *(short4v*)(Vs_s + r * LV + c4) = v;
            }
        }
        __syncthreads();
        if (t < 15) {
            f32x4 s[4] = {fz, fz, fz, fz};
#pragma unroll
            for (int ks = 0; ks < 2; ++ks) {
#pragma unroll
                for (int ni = 0; ni < 4; ++ni) {
                    short8 kb = *(const short8*)(Ks_s + (ni * 16 + llo) * LK + ks * 32 + lhi * 8);
                    s[ni] = __builtin_amdgcn_mfma_f32_16x16x32_bf16(qa[ks], kb, s[ni], 0, 0, 0);
                }
            }
#pragma unroll
            for (int ni = 0; ni < 4; ++ni) {
                int col = kv0 + ni * 16 + llo;
#pragma unroll
                for (int r = 0; r < 4; ++r) {
                    int qc = qrow + r; if (qc > SS - 1) qc = SS - 1;
                    float v = s[ni][r] * scale +
                              __bfloat162float(BIASg[((size_t)h * SS + qc) * 960 + col]);
                    s[ni][r] = (col < SS) ? v : -1e30f;
                }
            }
            float rmax[4], psum[4], corr[4];
#pragma unroll
            for (int r = 0; r < 4; ++r)
                rmax[r] = fmaxf(fmaxf(s[0][r], s[1][r]), fmaxf(s[2][r], s[3][r]));
#pragma unroll
            for (int off = 1; off < 16; off <<= 1)
#pragma unroll
                for (int r = 0; r < 4; ++r)
                    rmax[r] = fmaxf(rmax[r], __shfl_xor(rmax[r], off));
#pragma unroll
            for (int r = 0; r < 4; ++r) {
                float mnew = fmaxf(mrow[r], rmax[r]);
                corr[r] = __expf(mrow[r] - mnew);
                mrow[r] = mnew;
                float ps = 0.f;
#pragma unroll
                for (int ni = 0; ni < 4; ++ni) {
                    float p = __expf(s[ni][r] - mnew);
                    s[ni][r] = p;
                    ps += p;
                }
                psum[r] = ps;
            }
#pragma unroll
            for (int off = 1; off < 16; off <<= 1)
#pragma unroll
                for (int r = 0; r < 4; ++r) psum[r] += __shfl_xor(psum[r], off);
#pragma unroll
            for (int r = 0; r < 4; ++r) lrow[r] = lrow[r] * corr[r] + psum[r];
#pragma unroll
            for (int nj = 0; nj < 3; ++nj)
#pragma unroll
                for (int r = 0; r < 4; ++r) o[nj][r] *= corr[r];
#pragma unroll
            for (int ni = 0; ni < 4; ++ni)
#pragma unroll
                for (int r = 0; r < 4; ++r)
                    ((__hip_bfloat16*)Ps_w)[(lhi * 4 + r) * LP + ni * 16 + llo] =
                        __float2bfloat16(s[ni][r]);
#pragma unroll
            for (int ks = 0; ks < 2; ++ks) {
                short8 pa = *(const short8*)(Ps_w + llo * LP + ks * 32 + lhi * 8);
#pragma unroll
                for (int nj = 0; nj < 3; ++nj) {
                    short8 vb = *(const short8*)(Vs_s + (nj * 16 + llo) * LV + ks * 32 + lhi * 8);
                    o[nj] = __builtin_amdgcn_mfma_f32_16x16x32_bf16(pa, vb, o[nj], 0, 0, 0);
                }
            }
        }
        __syncthreads();
    }
    if (ws == 1) {
#pragma unroll
        for (int r = 0; r < 4; ++r) {
            int lr = lhi * 4 + r;
            if (llo == 0) { Lm[wq][lr] = mrow[r]; Ll[wq][lr] = lrow[r]; }
#pragma unroll
            for (int nj = 0; nj < 3; ++nj) {
                int d = nj * 16 + llo;
                if (d < DKK) Lo[wq][lr][d] = o[nj][r];
            }
        }
    }
    __syncthreads();
    if (ws == 0) {
#pragma unroll
        for (int r = 0; r < 4; ++r) {
            int lr = lhi * 4 + r;
            float m1 = Lm[wq][lr], l1 = Ll[wq][lr];
            float m = fmaxf(mrow[r], m1);
            float a0 = __expf(mrow[r] - m), a1 = __expf(m1 - m);
            float linv = 1.f / (lrow[r] * a0 + l1 * a1);
            int q = qrow + r;
            if (q < SS) {
#pragma unroll
                for (int nj = 0; nj < 3; ++nj) {
                    int d = nj * 16 + llo;
                    if (d < DKK)
                        AO[((size_t)b * SS + q) * DD + h * DKK + d] =
                            __float2bfloat16((o[nj][r] * a0 + Lo[wq][lr][d] * a1) * linv);
                }
            }
        }
    }
}

// ---------------- row LayerNorm: ln((a + a2? + cb? + add?)) ----------------
__global__ __launch_bounds__(320) void ln_kernel(const float* __restrict__ a,
                                                 const float* __restrict__ a2,
                                                 const float* __restrict__ cb,
                                                 const float* __restrict__ add,
                                                 const float* __restrict__ g,
                                                 const float* __restrict__ bta,
                                                 float* __restrict__ out,
                                                 __hip_bfloat16* __restrict__ outb) {
    const int row = blockIdx.x, i = threadIdx.x;
    __shared__ float red[320];
    __shared__ float s_m, s_v;
    float v = a[row * DD + i];
    if (a2) v += a2[row * DD + i];
    if (cb) v += cb[i];
    if (add) v += add[row * DD + i];
    red[i] = v;
    __syncthreads();
    if (i < 64) red[i] += red[i + 256];
    __syncthreads();
    for (int s = 128; s > 0; s >>= 1) {
        if (i < s) red[i] += red[i + s];
        __syncthreads();
    }
    if (i == 0) s_m = red[0] * (1.0f / DD);
    __syncthreads();
    const float d = v - s_m;
    red[i] = d * d;
    __syncthreads();
    if (i < 64) red[i] += red[i + 256];
    __syncthreads();
    for (int s = 128; s > 0; s >>= 1) {
        if (i < s) red[i] += red[i + s];
        __syncthreads();
    }
    if (i == 0) s_v = red[0] * (1.0f / DD);
    __syncthreads();
    float o = d * rsqrtf(s_v + 1e-5f) * g[i] + bta[i];
    out[row * DD + i] = o;
    outb[row * DD + i] = __float2bfloat16(o);
}

// ---------------- mean stage 1: partial sums over 150-row chunks ----------------
__global__ __launch_bounds__(256) void mpart_kernel(const float* __restrict__ xs,
                                                    float* __restrict__ mp) {
    const int b = blockIdx.y, z = blockIdx.z;
    const int d = blockIdx.x * 64 + (threadIdx.x & 63);
    const int rg = threadIdx.x >> 6;
    float s = 0.f;
    const int t0 = z * 150;
    for (int t = t0 + rg; t < t0 + 150; t += 4) s += xs[((size_t)b * SS + t) * DD + d];
    __shared__ float red[256];
    red[threadIdx.x] = s;
    __syncthreads();
    if (threadIdx.x < 128) red[threadIdx.x] += red[threadIdx.x + 128];
    __syncthreads();
    if (threadIdx.x < 64) mp[((size_t)b * 6 + z) * DD + d] = red[threadIdx.x] + red[threadIdx.x + 64];
}

// ---------------- transform params (reads 6 mean partials) ----------------
__global__ __launch_bounds__(64) void tp_kernel(const float* __restrict__ mp,
                                                const float* __restrict__ wrot, const float* __restrict__ brot,
                                                const float* __restrict__ wrefl, const float* __restrict__ brefl,
                                                const float* __restrict__ wtr, const float* __restrict__ btr,
                                                const float* __restrict__ wsc, const float* __restrict__ bsc,
                                                float* __restrict__ tp) {
    const int b = blockIdx.x, tid = threadIdx.x;
    __shared__ float gs[DD];
    __shared__ float raw[17];
    for (int j = tid; j < DD; j += 64) {
        float s6 = 0.f;
#pragma unroll
        for (int z = 0; z < 6; ++z) s6 += mp[((size_t)b * 6 + z) * DD + j];
        gs[j] = s6 * (1.0f / SS);
    }
    __syncthreads();
    if (tid < 17) {
        float s;
        if (tid < 4) {
            s = brot[tid];
            for (int d = 0; d < DD; ++d) s = fmaf(gs[d], wrot[d * 4 + tid], s);
        } else if (tid < 12) {
            int j = tid - 4;
            s = brefl[j];
            for (int d = 0; d < DD; ++d) s = fmaf(gs[d], wrefl[d * 8 + j], s);
        } else if (tid < 14) {
            int j = tid - 12;
            s = btr[j];
            for (int d = 0; d < DD; ++d) s = fmaf(gs[d], wtr[d * 2 + j], s);
        } else {
            int j = tid - 14;
            s = bsc[j];
            for (int d = 0; d < DD; ++d) s = fmaf(gs[d], wsc[d * 3 + j], s);
        }
        raw[tid] = s;
    }
    __syncthreads();
    if (tid == 0) {
        float mx = -1e30f;
        for (int j = 0; j < 4; ++j) mx = fmaxf(mx, raw[j]);
        float sm = 0.f, e[4];
        for (int j = 0; j < 4; ++j) { e[j] = expf(raw[j] - mx); sm += e[j]; }
        for (int j = 0; j < 4; ++j) tp[b * 17 + j] = e[j] / sm;
    } else if (tid == 1) {
        float mx = -1e30f;
        for (int j = 4; j < 12; ++j) mx = fmaxf(mx, raw[j]);
        float sm = 0.f, e[8];
        for (int j = 0; j < 8; ++j) { e[j] = expf(raw[4 + j] - mx); sm += e[j]; }
        for (int j = 0; j < 8; ++j) tp[b * 17 + 4 + j] = e[j] / sm;
    } else if (tid == 2) {
        tp[b * 17 + 12] = tanhf(raw[12]);
        tp[b * 17 + 13] = tanhf(raw[13]);
    } else if (tid == 3) {
        float mx = -1e30f;
        for (int j = 14; j < 17; ++j) mx = fmaxf(mx, raw[j]);
        float sm = 0.f, e[3];
        for (int j = 0; j < 3; ++j) { e[j] = expf(raw[14 + j] - mx); sm += e[j]; }
        for (int j = 0; j < 3; ++j) tp[b * 17 + 14 + j] = e[j] / sm;
    }
}

// ---------------- concat xs(bf16) + tp -> TIbf [3600, 384] ----------------
__global__ void concat_kernel(const __hip_bfloat16* __restrict__ xb, const float* __restrict__ tp,
                              __hip_bfloat16* __restrict__ ti) {
    int idx = blockIdx.x * 256 + threadIdx.x;
    if (idx >= BS * 384) return;
    int m = idx / 384, j = idx % 384;
    __hip_bfloat16 v;
    if (j < DD) v = xb[m * DD + j];
    else if (j < 337) v = __float2bfloat16(tp[(m / SS) * 17 + (j - DD)]);
    else v = __float2bfloat16(0.f);
    ti[idx] = v;
}

static inline void launch_mgemm(hipStream_t s, const __hip_bfloat16* A, int lda,
                                const __hip_bfloat16* Wt, int ldw, const float* bias,
                                const float* biasB, const float* biasC,
                                const float* res, int ldr, float alpha, float* Cf,
                                __hip_bfloat16* Cb, int ldc, int M, int N, int K, int act) {
    dim3 g((N + 63) / 64, (M + 127) / 128);
    mgemm_kernel<<<g, 256, 0, s>>>(A, lda, Wt, ldw, bias, biasB, biasC, res, ldr, alpha,
                                   Cf, nullptr, Cb, ldc, M, N, K, act);
}

extern "C" void kernel_launch(void* const* d_in, const int* in_sizes, int n_in,
                              void* d_out, int out_size, void* d_ws, size_t ws_size,
                              hipStream_t stream) {
    (void)in_sizes; (void)n_in; (void)out_size; (void)ws_size;
    const int* in_grid = (const int*)d_in[0];
    const float* pe = (const float*)d_in[1];
    const float* iew = (const float*)d_in[2];
    const float* ieb = (const float*)d_in[3];
    const float* wq = (const float*)d_in[4], *bq = (const float*)d_in[5];
    const float* wk = (const float*)d_in[6], *bk = (const float*)d_in[7];
    const float* wv = (const float*)d_in[8], *bv = (const float*)d_in[9];
    const float* wo = (const float*)d_in[10], *bo = (const float*)d_in[11];
    const float* lnag = (const float*)d_in[12], *lnab = (const float*)d_in[13];
    const float* dist_emb = (const float*)d_in[14], *dir_emb = (const float*)d_in[15];
    const float* wrot = (const float*)d_in[16], *brot = (const float*)d_in[17];
    const float* wrefl = (const float*)d_in[18], *brefl = (const float*)d_in[19];
    const float* wtr = (const float*)d_in[20], *btr = (const float*)d_in[21];
    const float* wsc = (const float*)d_in[22], *bsc = (const float*)d_in[23];
    const float* tnw1 = (const float*)d_in[24], *tnb1 = (const float*)d_in[25];
    const float* tnw2 = (const float*)d_in[26], *tnb2 = (const float*)d_in[27];
    const float* tnw3 = (const float*)d_in[28], *tnb3 = (const float*)d_in[29];
    const float* ffw1 = (const float*)d_in[30], *ffb1 = (const float*)d_in[31];
    const float* ffw2 = (const float*)d_in[32], *ffb2 = (const float*)d_in[33];
    const float* ln2g = (const float*)d_in[34], *ln2b = (const float*)d_in[35];
    const float* ck1 = (const float*)d_in[36], *cb1 = (const float*)d_in[37];
    const float* ck3 = (const float*)d_in[38], *cb3 = (const float*)d_in[39];
    const float* ck5 = (const float*)d_in[40], *cb5 = (const float*)d_in[41];
    const float* ck7 = (const float*)d_in[42], *cb7 = (const float*)d_in[43];
    const float* fusw = (const float*)d_in[44], *fusb = (const float*)d_in[45];
    const float* opw1 = (const float*)d_in[46], *opb1 = (const float*)d_in[47];
    const float* opw2 = (const float*)d_in[48], *opb2 = (const float*)d_in[49];
    const float* opw3 = (const float*)d_in[50], *opb3 = (const float*)d_in[51];
    const int* dist_idx = (const int*)d_in[52];
    const int* dir_idx = (const int*)d_in[53];
    float* out = (float*)d_out;

    // ---- workspace arena (byte offsets) ----
    char* base = (char*)d_ws;
    typedef __hip_bfloat16 bf;
    bf* WQKVT = (bf*)(base + 0);          // [4][960][320]
    bf* WOT = (bf*)(base + 2457600);
    bf* TN1T = (bf*)(base + 3276800);
    bf* TN2T = (bf*)(base + 5242880);
    bf* TN3T = (bf*)(base + 6881280);
    bf* FF1T = (bf*)(base + 7700480);
    bf* FF2T = (bf*)(base + 10977280);
    bf* CK1T = (bf*)(base + 14254080);
    bf* CK3T = (bf*)(base + 14458880);
    bf* CK5T = (bf*)(base + 16302080);
    bf* CK7T = (bf*)(base + 21422080);
    bf* FUST = (bf*)(base + 31457280);
    bf* OP1T = (bf*)(base + 32276480);
    float* XS = (float*)(base + 32378880);
    bf* XSbf = (bf*)(base + 36986880);
    bf* QKVbf = (bf*)(base + 39290880);   // [3600][960], ends 46,202,880
    bf* VT = (bf*)(base + 46202880);      // ends 49,152,000
    float* P1f = (float*)(base + 39290880);  // ff2 K-split partial (QKV region, dead post-attn)
    float* R2 = (float*)(base + 53114880);
    float* TP = (float*)(base + 57728000);
    // conv bf16 partials: [7][3600][320] bf16 = 16,128,000 B in dead QKV..R2 region
    bf* CPART = (bf*)(base + 39290880);
    char* BIG = base + 57728512;
    bf* AObf = (bf*)(BIG + 0);
    float* MPart = (float*)(BIG + 0);     // [4][6][320] f32, mean partials (AObf dead; pre-concat)
    bf* BIAS = (bf*)(BIG + 2764800);
    bf* TIbf = (bf*)(BIG + 0);
    bf* T1bf = (bf*)(BIG + 2764800);
    bf* T2bf = (bf*)(BIG + 7372800);
    bf* F1bf = (bf*)(BIG + 0);
    bf* PADbf = (bf*)(BIG + 0);
    bf* FEATSbf = (bf*)(BIG + 3317760);
    float* H1 = (float*)(BIG + 0);
    float* H2 = (float*)(BIG + 2304000);
    bf* R2bf = XSbf;

    dim3 cb(32, 8);
    qkvconvt_kernel<<<dim3(10, 10, 12), cb, 0, stream>>>(wq, wk, wv, WQKVT);
    allconvt_kernel<<<14610, cb, 0, stream>>>(wo, tnw1, tnw2, tnw3, ffw1, ffw2,
                                              ck1, ck3, ck5, ck7, fusw, opw1,
                                              WOT, TN1T, TN2T, TN3T, FF1T, FF2T,
                                              CK1T, CK3T, CK5T, CK7T, FUST, OP1T);

    embed_kernel<<<4500, 256, 0, stream>>>(in_grid, pe, iew, ieb, XS, XSbf);

    for (int l = 0; l < LL; ++l) {
        const int wO = l * DD * DD, bO = l * DD;
        launch_mgemm(stream, XSbf, DD, WQKVT + l * 307200, 320, bq + bO, bk + bO, bv + bO,
                     nullptr, 0, 1.f, nullptr, QKVbf, 960, BS, 960, 320, 0);
        attprep_kernel<<<4815, 256, 0, stream>>>(dist_emb + l * 60 * NHH, dir_emb + l * 8 * NHH,
                                                 dist_idx, dir_idx, QKVbf, BIAS, VT);
        mattn_kernel<<<dim3(15, NHH, BB), 512, 0, stream>>>(QKVbf, QKVbf + 320, VT, BIAS, AObf);
        launch_mgemm(stream, AObf, DD, WOT + wO, DD, bo + bO, nullptr, nullptr, XS, DD, 1.f,
                     R2, nullptr, DD, BS, DD, DD, 0);
        ln_kernel<<<BS, 320, 0, stream>>>(R2, nullptr, nullptr, nullptr, lnag + bO, lnab + bO, XS, XSbf);
        mpart_kernel<<<dim3(5, BB, 6), 256, 0, stream>>>(XS, MPart);
        tp_kernel<<<BB, 64, 0, stream>>>(MPart, wrot + l * 1280, brot + l * 4,
                                         wrefl + l * 2560, brefl + l * 8,
                                         wtr + l * 640, btr + l * 2,
                                         wsc + l * 960, bsc + l * 3, TP);
        concat_kernel<<<(BS * 384 + 255) / 256, 256, 0, stream>>>(XSbf, TP, TIbf);
        launch_mgemm(stream, TIbf, 384, TN1T + l * 245760, 384, tnb1 + l * 640, nullptr, nullptr,
                     nullptr, 0, 1.f, nullptr, T1bf, 640, BS, 640, 384, 1);
        launch_mgemm(stream, T1bf, 640, TN2T + l * 204800, 640, tnb2 + bO, nullptr, nullptr,
                     nullptr, 0, 1.f, nullptr, T2bf, DD, BS, DD, 640, 1);
        launch_mgemm(stream, T2bf, DD, TN3T + wO, DD, tnb3 + bO, nullptr, nullptr, XS, DD, 0.3f,
                     XS, XSbf, DD, BS, DD, DD, 0);
        launch_mgemm(stream, XSbf, DD, FF1T + l * 409600, DD, ffb1 + l * FFD, nullptr, nullptr,
                     nullptr, 0, 1.f, nullptr, F1bf, FFD, BS, FFD, DD, 1);
        {
            dim3 g(5, 29, 2);
            mgemm_kernel<<<g, 256, 0, stream>>>(F1bf, FFD, FF2T + l * 409600, FFD,
                                                nullptr, nullptr, nullptr, nullptr, 0, 1.f,
                                                R2, P1f, nullptr, DD, BS, DD, 640, 0);
        }
        ln_kernel<<<BS, 320, 0, stream>>>(R2, P1f, ffb2 + bO, XS, ln2g + bO, ln2b + bO, XS, XSbf);
    }

    // ---- multiscale convs: per-kh bf16 partials + reduce (XCD-swizzled, hoisted addr) ----
    pad_kernel<<<(BB * 36 * 36 * DD + 255) / 256, 256, 0, stream>>>(XSbf, PADbf);
    launch_mgemm(stream, XSbf, DD, CK1T, DD, cb1, nullptr, nullptr, nullptr, 0, 1.f,
                 nullptr, FEATSbf + 0, 1280, BS, DD, DD, 2);
    const int RED = (BS * DD / 8 + 255) / 256;
    mconv_kernel<3><<<dim3(29, 5, 3), 256, 0, stream>>>(PADbf, CK3T, CPART, 1);
    creduce_kernel<<<RED, 256, 0, stream>>>(CPART, 3, cb3, FEATSbf + 320, 1280);
    mconv_kernel<5><<<dim3(29, 5, 5), 256, 0, stream>>>(PADbf, CK5T, CPART, 1);
    creduce_kernel<<<RED, 256, 0, stream>>>(CPART, 5, cb5, FEATSbf + 640, 1280);
    mconv_kernel<7><<<dim3(29, 5, 7), 256, 0, stream>>>(PADbf, CK7T, CPART, 1);
    creduce_kernel<<<RED, 256, 0, stream>>>(CPART, 7, cb7, FEATSbf + 960, 1280);
    launch_mgemm(stream, FEATSbf, 1280, FUST, 1280, fusb, nullptr, nullptr, nullptr, 0, 1.f,
                 nullptr, R2bf, DD, BS, DD, 1280, 0);
    // ---- output head ----
    launch_mgemm(stream, R2bf, DD, OP1T, DD, opb1, nullptr, nullptr, nullptr, 0, 1.f,
                 H1, nullptr, 160, BS, 160, DD, 1);
    gemm_kernel<<<dim3(2, 57), 256, 0, stream>>>(H1, 160, opw2, opb2, H2, 80, BS, 80, 160, 1);
    gemm_kernel<<<dim3(1, 57), 256, 0, stream>>>(H2, 80, opw3, opb3, out, 10, BS, 10, 80, 0);
}